// Round 1
// baseline (974.293 us; speedup 1.0000x reference)
//
#include <hip/hip_runtime.h>

// ---------------------------------------------------------------------------
// GNNStack — dead-code-eliminated pipeline (edge-update MLPs don't affect y).
// Live work: deg/CSR build, 3x (mean-aggr + fused SAGE matmul), post-MLP,
// fused predict MLP. All fp32 vector math (no fp32 MFMA on CDNA4).
// ---------------------------------------------------------------------------

__global__ void k_count(const int* __restrict__ dst, int* __restrict__ cnt, int E) {
  int i = blockIdx.x * blockDim.x + threadIdx.x;
  if (i < E) atomicAdd(&cnt[dst[i]], 1);
}

// single-block scan: exclusive prefix of counts -> row_start & cursor, deg float
__global__ void k_scan(const int* __restrict__ cnt, int* __restrict__ rs,
                       int* __restrict__ cursor, float* __restrict__ degf, int n) {
  __shared__ int wsum[16];
  __shared__ int wpre[16];
  __shared__ int s_run;
  const int tid = threadIdx.x;
  const int lane = tid & 63;
  const int wv = tid >> 6;
  if (tid == 0) s_run = 0;
  __syncthreads();
  for (int base = 0; base < n; base += 1024) {
    int i = base + tid;
    int v = (i < n) ? cnt[i] : 0;
    int s = v;
#pragma unroll
    for (int off = 1; off < 64; off <<= 1) {
      int t = __shfl_up(s, off);
      if (lane >= off) s += t;
    }
    if (lane == 63) wsum[wv] = s;
    __syncthreads();
    if (tid < 16) {
      int t = wsum[tid];
      int ss = t;
#pragma unroll
      for (int off = 1; off < 16; off <<= 1) {
        int u = __shfl_up(ss, off);
        if (tid >= off) ss += u;
      }
      wpre[tid] = ss - t;  // exclusive prefix over wave sums
    }
    __syncthreads();
    int incl = s + wpre[wv];
    int run = s_run;
    if (i < n) {
      int excl = run + incl - v;
      rs[i] = excl;
      cursor[i] = excl;
      degf[i] = (float)(v > 0 ? v : 1);
    }
    __syncthreads();
    if (tid == 1023) s_run = run + wpre[15] + wsum[15];
    __syncthreads();
  }
  if (tid == 0) rs[n] = s_run;
}

__global__ void k_scatter(const int* __restrict__ src, const int* __restrict__ dst,
                          int* __restrict__ cursor, int* __restrict__ csr, int E) {
  int i = blockIdx.x * blockDim.x + threadIdx.x;
  if (i < E) {
    int p = atomicAdd(&cursor[dst[i]], 1);
    csr[p] = src[i];
  }
}

// mean-aggregate: one 64-lane wave per dst node, lane holds 2 feature dims
__global__ void k_aggr(const float* __restrict__ x, const int* __restrict__ csr,
                       const int* __restrict__ rs, const float* __restrict__ degf,
                       float* __restrict__ aggr, int n) {
  int gid = blockIdx.x * blockDim.x + threadIdx.x;
  int wid = gid >> 6, lane = gid & 63;
  if (wid >= n) return;
  int s = rs[wid], e = rs[wid + 1];
  float ax = 0.f, ay = 0.f;
  for (int j = s; j < e; ++j) {
    int sv = csr[j];
    float2 v = *(const float2*)(x + (size_t)sv * 128 + lane * 2);
    ax += v.x;
    ay += v.y;
  }
  float inv = 1.0f / degf[wid];
  float2 o;
  o.x = ax * inv;
  o.y = ay * inv;
  *(float2*)(aggr + (size_t)wid * 128 + lane * 2) = o;
}

// ---------------------------------------------------------------------------
// Generic tiled matmul: OUT[r, 0:128] = epi( sum_phases A_p[row] @ W_p + bias )
//   NPHASE: 1 or 2 (K = 128 * NPHASE); per-phase source + optional gather idx
//   EPI: 0 = relu+store[128], 1 = store[128], 2 = predict (relu, dot qW2, +qb2)
// 64 rows/block, 256 threads, thread tile = 4 rows x (4+4 cols). No LDS:
// W rows are hot in L1/L2 (broadcast within wave), A rows coalesce per 16 lanes.
// ---------------------------------------------------------------------------
template <int NPHASE, int EPI>
__global__ __launch_bounds__(256) void k_mm(
    const float* __restrict__ srcA, const float* __restrict__ srcB,
    const int* __restrict__ idxA, const int* __restrict__ idxB,
    const float* __restrict__ W0, const float* __restrict__ W1,
    const float* __restrict__ bias,
    const float* __restrict__ qW2, const float* __restrict__ qb2,
    float* __restrict__ out, int nrows) {
  const int tid = threadIdx.x;
  const int c = tid & 15;   // col group: cols [4c..4c+3] and [64+4c..64+4c+3]
  const int rg = tid >> 4;  // row group: rows base..base+3
  const long base = (long)blockIdx.x * 64 + (long)rg * 4;

  float acc[4][8];
#pragma unroll
  for (int i = 0; i < 4; ++i)
#pragma unroll
    for (int j = 0; j < 8; ++j) acc[i][j] = 0.f;

#pragma unroll
  for (int p = 0; p < NPHASE; ++p) {
    const float* S = (p == 0) ? srcA : srcB;
    const int* I = (p == 0) ? idxA : idxB;
    const float* W = (p == 0) ? W0 : W1;
    const float* ar[4];
#pragma unroll
    for (int i = 0; i < 4; ++i) {
      long r = base + i;
      long rr = (r < nrows) ? r : (long)(nrows - 1);  // clamped rows: result discarded
      long a = I ? (long)I[rr] : rr;
      ar[i] = S + a * 128;
    }
    for (int k0 = 0; k0 < 128; k0 += 4) {
      float a_[4][4];
#pragma unroll
      for (int i = 0; i < 4; ++i) {
        float4 t = *(const float4*)(ar[i] + k0);
        a_[i][0] = t.x; a_[i][1] = t.y; a_[i][2] = t.z; a_[i][3] = t.w;
      }
#pragma unroll
      for (int kk = 0; kk < 4; ++kk) {
        float4 w0 = *(const float4*)(W + (k0 + kk) * 128 + 4 * c);
        float4 w1 = *(const float4*)(W + (k0 + kk) * 128 + 64 + 4 * c);
#pragma unroll
        for (int i = 0; i < 4; ++i) {
          float av = a_[i][kk];
          acc[i][0] = fmaf(av, w0.x, acc[i][0]);
          acc[i][1] = fmaf(av, w0.y, acc[i][1]);
          acc[i][2] = fmaf(av, w0.z, acc[i][2]);
          acc[i][3] = fmaf(av, w0.w, acc[i][3]);
          acc[i][4] = fmaf(av, w1.x, acc[i][4]);
          acc[i][5] = fmaf(av, w1.y, acc[i][5]);
          acc[i][6] = fmaf(av, w1.z, acc[i][6]);
          acc[i][7] = fmaf(av, w1.w, acc[i][7]);
        }
      }
    }
  }

  float4 b0 = *(const float4*)(bias + 4 * c);
  float4 b1 = *(const float4*)(bias + 64 + 4 * c);

  if (EPI == 2) {
    float4 q0 = *(const float4*)(qW2 + 4 * c);
    float4 q1 = *(const float4*)(qW2 + 64 + 4 * c);
    float qb = qb2[0];
#pragma unroll
    for (int i = 0; i < 4; ++i) {
      float part = fmaxf(acc[i][0] + b0.x, 0.f) * q0.x;
      part = fmaf(fmaxf(acc[i][1] + b0.y, 0.f), q0.y, part);
      part = fmaf(fmaxf(acc[i][2] + b0.z, 0.f), q0.z, part);
      part = fmaf(fmaxf(acc[i][3] + b0.w, 0.f), q0.w, part);
      part = fmaf(fmaxf(acc[i][4] + b1.x, 0.f), q1.x, part);
      part = fmaf(fmaxf(acc[i][5] + b1.y, 0.f), q1.y, part);
      part = fmaf(fmaxf(acc[i][6] + b1.z, 0.f), q1.z, part);
      part = fmaf(fmaxf(acc[i][7] + b1.w, 0.f), q1.w, part);
#pragma unroll
      for (int m = 1; m < 16; m <<= 1) part += __shfl_xor(part, m);
      long r = base + i;
      if (c == 0 && r < nrows) out[r] = part + qb;
    }
  } else {
#pragma unroll
    for (int i = 0; i < 4; ++i) {
      long r = base + i;
      if (r >= nrows) continue;
      float4 o0, o1;
      o0.x = acc[i][0] + b0.x; o0.y = acc[i][1] + b0.y;
      o0.z = acc[i][2] + b0.z; o0.w = acc[i][3] + b0.w;
      o1.x = acc[i][4] + b1.x; o1.y = acc[i][5] + b1.y;
      o1.z = acc[i][6] + b1.z; o1.w = acc[i][7] + b1.w;
      if (EPI == 0) {
        o0.x = fmaxf(o0.x, 0.f); o0.y = fmaxf(o0.y, 0.f);
        o0.z = fmaxf(o0.z, 0.f); o0.w = fmaxf(o0.w, 0.f);
        o1.x = fmaxf(o1.x, 0.f); o1.y = fmaxf(o1.y, 0.f);
        o1.z = fmaxf(o1.z, 0.f); o1.w = fmaxf(o1.w, 0.f);
      }
      *(float4*)(out + r * 128 + 4 * c) = o0;
      *(float4*)(out + r * 128 + 64 + 4 * c) = o1;
    }
  }
}

extern "C" void kernel_launch(void* const* d_in, const int* in_sizes, int n_in,
                              void* d_out, int out_size, void* d_ws, size_t ws_size,
                              hipStream_t stream) {
  const float* x_in = (const float*)d_in[0];
  // d_in[1] edge_attr: dead (edge-update branch never reaches the output)
  const int* ei = (const int*)d_in[2];
  const int* pe = (const int*)d_in[3];
  const float* Wl = (const float*)d_in[4];
  const float* bl = (const float*)d_in[5];
  const float* Wr = (const float*)d_in[6];
  // d_in[7..10] edge-update weights: dead
  const float* pW1 = (const float*)d_in[11];
  const float* pb1 = (const float*)d_in[12];
  const float* pW2 = (const float*)d_in[13];
  const float* pb2 = (const float*)d_in[14];
  const float* qW1 = (const float*)d_in[15];
  const float* qb1 = (const float*)d_in[16];
  const float* qW2 = (const float*)d_in[17];
  const float* qb2 = (const float*)d_in[18];

  const int N = in_sizes[0] / 128;
  const int E = in_sizes[2] / 2;
  const int EP = in_sizes[3] / 2;
  const int* e_src = ei;
  const int* e_dst = ei + E;
  const int* p_src = pe;
  const int* p_dst = pe + EP;

  char* ws = (char*)d_ws;
  size_t off = 0;
  auto alloc = [&](size_t bytes) {
    void* p = ws + off;
    off += (bytes + 511) & ~(size_t)511;
    return p;
  };
  float* x_buf = (float*)alloc((size_t)N * 128 * 4);  // 25.6 MB
  float* aggr = (float*)alloc((size_t)N * 128 * 4);   // 25.6 MB
  int* deg_i = (int*)alloc((size_t)N * 4);
  int* rs = (int*)alloc((size_t)(N + 1) * 4);
  int* cursor = (int*)alloc((size_t)N * 4);
  float* degf = (float*)alloc((size_t)N * 4);
  int* csr = (int*)alloc((size_t)E * 4);              // 2.4 MB

  hipMemsetAsync(deg_i, 0, (size_t)N * 4, stream);
  k_count<<<(E + 255) / 256, 256, 0, stream>>>(e_dst, deg_i, E);
  k_scan<<<1, 1024, 0, stream>>>(deg_i, rs, cursor, degf, N);
  k_scatter<<<(E + 255) / 256, 256, 0, stream>>>(e_src, e_dst, cursor, csr, E);

  const int mmblocks = (N + 63) / 64;
  for (int l = 0; l < 3; ++l) {
    const float* xin = (l == 0) ? x_in : x_buf;
    k_aggr<<<(N + 3) / 4, 256, 0, stream>>>(xin, csr, rs, degf, aggr, N);
    // x_new = relu(aggr @ Wl[l] + x @ Wr[l] + bl[l])  (in-place safe: row owned
    // by the 16 lanes of one wave; reads precede that wave's writes)
    k_mm<2, 0><<<mmblocks, 256, 0, stream>>>(
        aggr, xin, nullptr, nullptr, Wl + (size_t)l * 128 * 128,
        Wr + (size_t)l * 128 * 128, bl + (size_t)l * 128, nullptr, nullptr,
        x_buf, N);
  }
  // post MLP: h1 = relu(x@pW1+pb1) -> aggr ; x_final = h1@pW2+pb2 -> x_buf
  k_mm<1, 0><<<mmblocks, 256, 0, stream>>>(x_buf, nullptr, nullptr, nullptr, pW1,
                                           nullptr, pb1, nullptr, nullptr, aggr, N);
  k_mm<1, 1><<<mmblocks, 256, 0, stream>>>(aggr, nullptr, nullptr, nullptr, pW2,
                                           nullptr, pb2, nullptr, nullptr, x_buf, N);
  // predict: y = relu([x_i | x_j] @ qW1 + qb1) @ qW2 + qb2  (fused second layer)
  k_mm<2, 2><<<(EP + 63) / 64, 256, 0, stream>>>(
      x_buf, x_buf, p_src, p_dst, qW1, qW1 + 128 * 128, qb1, qW2, qb2,
      (float*)d_out, EP);
}

// Round 2
// 747.367 us; speedup vs baseline: 1.3036x; 1.3036x over previous
//
#include <hip/hip_runtime.h>

// ---------------------------------------------------------------------------
// GNNStack — dead-code-eliminated pipeline (edge-update MLPs don't affect y).
// Live work: deg/CSR build, 3x (mean-aggr + fused SAGE matmul), post-MLP,
// factorized predict MLP (per-node u/v then streaming pair kernel).
// All fp32 vector math (no fp32 MFMA on CDNA4).
// ---------------------------------------------------------------------------

__global__ void k_count(const int* __restrict__ dst, int* __restrict__ cnt, int E) {
  int i = blockIdx.x * blockDim.x + threadIdx.x;
  if (i < E) atomicAdd(&cnt[dst[i]], 1);
}

// single-block scan: exclusive prefix of counts -> row_start & cursor, deg float
__global__ void k_scan(const int* __restrict__ cnt, int* __restrict__ rs,
                       int* __restrict__ cursor, float* __restrict__ degf, int n) {
  __shared__ int wsum[16];
  __shared__ int wpre[16];
  __shared__ int s_run;
  const int tid = threadIdx.x;
  const int lane = tid & 63;
  const int wv = tid >> 6;
  if (tid == 0) s_run = 0;
  __syncthreads();
  for (int base = 0; base < n; base += 1024) {
    int i = base + tid;
    int v = (i < n) ? cnt[i] : 0;
    int s = v;
#pragma unroll
    for (int off = 1; off < 64; off <<= 1) {
      int t = __shfl_up(s, off);
      if (lane >= off) s += t;
    }
    if (lane == 63) wsum[wv] = s;
    __syncthreads();
    if (tid < 16) {
      int t = wsum[tid];
      int ss = t;
#pragma unroll
      for (int off = 1; off < 16; off <<= 1) {
        int u = __shfl_up(ss, off);
        if (tid >= off) ss += u;
      }
      wpre[tid] = ss - t;  // exclusive prefix over wave sums
    }
    __syncthreads();
    int incl = s + wpre[wv];
    int run = s_run;
    if (i < n) {
      int excl = run + incl - v;
      rs[i] = excl;
      cursor[i] = excl;
      degf[i] = (float)(v > 0 ? v : 1);
    }
    __syncthreads();
    if (tid == 1023) s_run = run + wpre[15] + wsum[15];
    __syncthreads();
  }
  if (tid == 0) rs[n] = s_run;
}

__global__ void k_scatter(const int* __restrict__ src, const int* __restrict__ dst,
                          int* __restrict__ cursor, int* __restrict__ csr, int E) {
  int i = blockIdx.x * blockDim.x + threadIdx.x;
  if (i < E) {
    int p = atomicAdd(&cursor[dst[i]], 1);
    csr[p] = src[i];
  }
}

// mean-aggregate: one 64-lane wave per dst node, lane holds 2 feature dims.
// 4-wide neighbor unroll keeps 4 independent 512B gathers in flight.
__global__ void k_aggr(const float* __restrict__ x, const int* __restrict__ csr,
                       const int* __restrict__ rs, const float* __restrict__ degf,
                       float* __restrict__ aggr, int n) {
  int gid = blockIdx.x * blockDim.x + threadIdx.x;
  int wid = gid >> 6, lane = gid & 63;
  if (wid >= n) return;
  int s = rs[wid], e = rs[wid + 1];
  float ax = 0.f, ay = 0.f;
  int j = s;
  for (; j + 3 < e; j += 4) {
    int s0 = csr[j], s1 = csr[j + 1], s2 = csr[j + 2], s3 = csr[j + 3];
    float2 v0 = *(const float2*)(x + (size_t)s0 * 128 + lane * 2);
    float2 v1 = *(const float2*)(x + (size_t)s1 * 128 + lane * 2);
    float2 v2 = *(const float2*)(x + (size_t)s2 * 128 + lane * 2);
    float2 v3 = *(const float2*)(x + (size_t)s3 * 128 + lane * 2);
    ax += (v0.x + v1.x) + (v2.x + v3.x);
    ay += (v0.y + v1.y) + (v2.y + v3.y);
  }
  for (; j < e; ++j) {
    int sv = csr[j];
    float2 v = *(const float2*)(x + (size_t)sv * 128 + lane * 2);
    ax += v.x;
    ay += v.y;
  }
  float inv = 1.0f / degf[wid];
  float2 o;
  o.x = ax * inv;
  o.y = ay * inv;
  *(float2*)(aggr + (size_t)wid * 128 + lane * 2) = o;
}

// ---------------------------------------------------------------------------
// Generic tiled matmul: OUT[r, 0:128] = epi( sum_phases A_p[row] @ W_p + bias )
//   NPHASE: 1 or 2 (K = 128 * NPHASE); per-phase source + optional gather idx
//   EPI: 0 = relu+store[128], 1 = store[128]
// 64 rows/block, 256 threads, thread tile = 4 rows x (4+4 cols). No LDS:
// W rows hot in L2 (broadcast within wave). k-loop unrolled 8-wide so ~24
// loads are in flight per 512 VALU-issue cycles.
// ---------------------------------------------------------------------------
template <int NPHASE, int EPI>
__global__ __launch_bounds__(256) void k_mm(
    const float* __restrict__ srcA, const float* __restrict__ srcB,
    const float* __restrict__ W0, const float* __restrict__ W1,
    const float* __restrict__ bias, float* __restrict__ out, int nrows) {
  const int tid = threadIdx.x;
  const int c = tid & 15;   // col group: cols [4c..4c+3] and [64+4c..64+4c+3]
  const int rg = tid >> 4;  // row group: rows base..base+3
  const long base = (long)blockIdx.x * 64 + (long)rg * 4;

  float acc[4][8];
#pragma unroll
  for (int i = 0; i < 4; ++i)
#pragma unroll
    for (int j = 0; j < 8; ++j) acc[i][j] = 0.f;

#pragma unroll
  for (int p = 0; p < NPHASE; ++p) {
    const float* S = (p == 0) ? srcA : srcB;
    const float* W = (p == 0) ? W0 : W1;
    const float* ar[4];
#pragma unroll
    for (int i = 0; i < 4; ++i) {
      long r = base + i;
      long rr = (r < nrows) ? r : (long)(nrows - 1);  // clamped rows: discarded
      ar[i] = S + rr * 128;
    }
    for (int k0 = 0; k0 < 128; k0 += 8) {
      float4 a0[4], a1[4];
#pragma unroll
      for (int i = 0; i < 4; ++i) {
        a0[i] = *(const float4*)(ar[i] + k0);
        a1[i] = *(const float4*)(ar[i] + k0 + 4);
      }
#pragma unroll
      for (int kk = 0; kk < 8; ++kk) {
        float4 w0 = *(const float4*)(W + (k0 + kk) * 128 + 4 * c);
        float4 w1 = *(const float4*)(W + (k0 + kk) * 128 + 64 + 4 * c);
#pragma unroll
        for (int i = 0; i < 4; ++i) {
          float av;
          if (kk == 0) av = a0[i].x;
          else if (kk == 1) av = a0[i].y;
          else if (kk == 2) av = a0[i].z;
          else if (kk == 3) av = a0[i].w;
          else if (kk == 4) av = a1[i].x;
          else if (kk == 5) av = a1[i].y;
          else if (kk == 6) av = a1[i].z;
          else av = a1[i].w;
          acc[i][0] = fmaf(av, w0.x, acc[i][0]);
          acc[i][1] = fmaf(av, w0.y, acc[i][1]);
          acc[i][2] = fmaf(av, w0.z, acc[i][2]);
          acc[i][3] = fmaf(av, w0.w, acc[i][3]);
          acc[i][4] = fmaf(av, w1.x, acc[i][4]);
          acc[i][5] = fmaf(av, w1.y, acc[i][5]);
          acc[i][6] = fmaf(av, w1.z, acc[i][6]);
          acc[i][7] = fmaf(av, w1.w, acc[i][7]);
        }
      }
    }
  }

  float4 b0 = *(const float4*)(bias + 4 * c);
  float4 b1 = *(const float4*)(bias + 64 + 4 * c);
#pragma unroll
  for (int i = 0; i < 4; ++i) {
    long r = base + i;
    if (r >= nrows) continue;
    float4 o0, o1;
    o0.x = acc[i][0] + b0.x; o0.y = acc[i][1] + b0.y;
    o0.z = acc[i][2] + b0.z; o0.w = acc[i][3] + b0.w;
    o1.x = acc[i][4] + b1.x; o1.y = acc[i][5] + b1.y;
    o1.z = acc[i][6] + b1.z; o1.w = acc[i][7] + b1.w;
    if (EPI == 0) {
      o0.x = fmaxf(o0.x, 0.f); o0.y = fmaxf(o0.y, 0.f);
      o0.z = fmaxf(o0.z, 0.f); o0.w = fmaxf(o0.w, 0.f);
      o1.x = fmaxf(o1.x, 0.f); o1.y = fmaxf(o1.y, 0.f);
      o1.z = fmaxf(o1.z, 0.f); o1.w = fmaxf(o1.w, 0.f);
    }
    *(float4*)(out + r * 128 + 4 * c) = o0;
    *(float4*)(out + r * 128 + 64 + 4 * c) = o1;
  }
}

// predict pair kernel: y = relu(u[i] + v[j]) . qW2 + qb2  (qb1 folded into u)
// one wave per 4 pairs; lane holds 2 dims; 8 independent 512B gathers in flight.
__global__ __launch_bounds__(256) void k_pair(
    const float* __restrict__ u, const float* __restrict__ v,
    const int* __restrict__ ps, const int* __restrict__ pd,
    const float* __restrict__ qW2, const float* __restrict__ qb2,
    float* __restrict__ out, int EP) {
  int gid = blockIdx.x * blockDim.x + threadIdx.x;
  int wid = gid >> 6, lane = gid & 63;
  int base = wid * 4;
  if (base >= EP) return;
  float2 q = *(const float2*)(qW2 + lane * 2);
  float qb = qb2[0];
  int n = EP - base;
  n = n < 4 ? n : 4;
  float2 a[4], b[4];
#pragma unroll
  for (int p = 0; p < 4; ++p) {
    int pp = (p < n) ? base + p : base;
    int i = ps[pp], j = pd[pp];
    a[p] = *(const float2*)(u + (size_t)i * 128 + lane * 2);
    b[p] = *(const float2*)(v + (size_t)j * 128 + lane * 2);
  }
#pragma unroll
  for (int p = 0; p < 4; ++p) {
    float hx = fmaxf(a[p].x + b[p].x, 0.f);
    float hy = fmaxf(a[p].y + b[p].y, 0.f);
    float part = fmaf(hy, q.y, hx * q.x);
#pragma unroll
    for (int m = 1; m < 64; m <<= 1) part += __shfl_xor(part, m);
    if (lane == 0 && p < n) out[base + p] = part + qb;
  }
}

extern "C" void kernel_launch(void* const* d_in, const int* in_sizes, int n_in,
                              void* d_out, int out_size, void* d_ws, size_t ws_size,
                              hipStream_t stream) {
  const float* x_in = (const float*)d_in[0];
  // d_in[1] edge_attr: dead (edge-update branch never reaches the output)
  const int* ei = (const int*)d_in[2];
  const int* pe = (const int*)d_in[3];
  const float* Wl = (const float*)d_in[4];
  const float* bl = (const float*)d_in[5];
  const float* Wr = (const float*)d_in[6];
  // d_in[7..10] edge-update weights: dead
  const float* pW1 = (const float*)d_in[11];
  const float* pb1 = (const float*)d_in[12];
  const float* pW2 = (const float*)d_in[13];
  const float* pb2 = (const float*)d_in[14];
  const float* qW1 = (const float*)d_in[15];
  const float* qb1 = (const float*)d_in[16];
  const float* qW2 = (const float*)d_in[17];
  const float* qb2 = (const float*)d_in[18];

  const int N = in_sizes[0] / 128;
  const int E = in_sizes[2] / 2;
  const int EP = in_sizes[3] / 2;
  const int* e_src = ei;
  const int* e_dst = ei + E;
  const int* p_src = pe;
  const int* p_dst = pe + EP;

  char* ws = (char*)d_ws;
  size_t off = 0;
  auto alloc = [&](size_t bytes) {
    void* p = ws + off;
    off += (bytes + 511) & ~(size_t)511;
    return p;
  };
  float* x_buf = (float*)alloc((size_t)N * 128 * 4);  // 25.6 MB
  float* aggr = (float*)alloc((size_t)N * 128 * 4);   // 25.6 MB
  int* deg_i = (int*)alloc((size_t)N * 4);
  int* rs = (int*)alloc((size_t)(N + 1) * 4);
  int* cursor = (int*)alloc((size_t)N * 4);
  float* degf = (float*)alloc((size_t)N * 4);
  int* csr = (int*)alloc((size_t)E * 4);              // 2.4 MB
  float* zerob = (float*)alloc(128 * 4);

  hipMemsetAsync(deg_i, 0, (size_t)N * 4, stream);
  hipMemsetAsync(zerob, 0, 128 * 4, stream);
  k_count<<<(E + 255) / 256, 256, 0, stream>>>(e_dst, deg_i, E);
  k_scan<<<1, 1024, 0, stream>>>(deg_i, rs, cursor, degf, N);
  k_scatter<<<(E + 255) / 256, 256, 0, stream>>>(e_src, e_dst, cursor, csr, E);

  const int mmblocks = (N + 63) / 64;
  for (int l = 0; l < 3; ++l) {
    const float* xin = (l == 0) ? x_in : x_buf;
    k_aggr<<<(N + 3) / 4, 256, 0, stream>>>(xin, csr, rs, degf, aggr, N);
    // x_new = relu(aggr @ Wl[l] + x @ Wr[l] + bl[l])  (in-place safe: rows are
    // wave-exclusive; all k-loop reads precede that wave's epilogue stores)
    k_mm<2, 0><<<mmblocks, 256, 0, stream>>>(
        aggr, xin, Wl + (size_t)l * 128 * 128, Wr + (size_t)l * 128 * 128,
        bl + (size_t)l * 128, x_buf, N);
  }
  // post MLP: h1 = relu(x@pW1+pb1) -> aggr ; x_final = h1@pW2+pb2 -> x_buf
  k_mm<1, 0><<<mmblocks, 256, 0, stream>>>(x_buf, nullptr, pW1, nullptr, pb1,
                                           aggr, N);
  k_mm<1, 1><<<mmblocks, 256, 0, stream>>>(aggr, nullptr, pW2, nullptr, pb2,
                                           x_buf, N);
  // factorized predict: u = x@qW1_top + qb1 -> aggr ; v = x@qW1_bot -> x_buf
  // (in-place, wave-exclusive rows)
  k_mm<1, 1><<<mmblocks, 256, 0, stream>>>(x_buf, nullptr, qW1, nullptr, qb1,
                                           aggr, N);
  k_mm<1, 1><<<mmblocks, 256, 0, stream>>>(x_buf, nullptr, qW1 + 128 * 128,
                                           nullptr, zerob, x_buf, N);
  // y[p] = relu(u[i]+v[j]) . qW2 + qb2
  k_pair<<<(EP + 15) / 16, 256, 0, stream>>>(aggr, x_buf, p_src, p_dst, qW2, qb2,
                                             (float*)d_out, EP);
}

// Round 3
// 506.339 us; speedup vs baseline: 1.9242x; 1.4760x over previous
//
#include <hip/hip_runtime.h>

// ---------------------------------------------------------------------------
// GNNStack — dead-code-eliminated (edge-update MLPs never reach the output).
// All matmuls on MFMA bf16 with hi/lo split precision (fp32-equivalent):
//   C = Ahi*Bhi + Alo*Bhi + Ahi*Blo   (AloBlo ~ 1.6e-5 relative, dropped)
// Node features stored as bf16 hi/lo row-major; weights pre-packed into
// per-lane MFMA fragment order (verified gfx950 16x16x32 layout).
// ---------------------------------------------------------------------------

typedef __attribute__((ext_vector_type(8))) short bf16x8;
typedef __attribute__((ext_vector_type(4))) float f32x4;

__device__ __forceinline__ unsigned short f2bf(float x) {
  unsigned u = __float_as_uint(x);
  u += 0x7fffu + ((u >> 16) & 1u);
  return (unsigned short)(u >> 16);
}
__device__ __forceinline__ float bf2f(unsigned short h) {
  return __uint_as_float(((unsigned)h) << 16);
}
__device__ __forceinline__ float lo16f(unsigned u) { return __uint_as_float(u << 16); }
__device__ __forceinline__ float hi16f(unsigned u) { return __uint_as_float(u & 0xffff0000u); }

// ---------------- CSR build ----------------
__global__ void k_count(const int* __restrict__ dst, int* __restrict__ cnt, int E) {
  int i = blockIdx.x * blockDim.x + threadIdx.x;
  if (i < E) atomicAdd(&cnt[dst[i]], 1);
}

__global__ void k_scan(const int* __restrict__ cnt, int* __restrict__ rs,
                       int* __restrict__ cursor, float* __restrict__ degf, int n) {
  __shared__ int wsum[16];
  __shared__ int wpre[16];
  __shared__ int s_run;
  const int tid = threadIdx.x;
  const int lane = tid & 63;
  const int wv = tid >> 6;
  if (tid == 0) s_run = 0;
  __syncthreads();
  for (int base = 0; base < n; base += 1024) {
    int i = base + tid;
    int v = (i < n) ? cnt[i] : 0;
    int s = v;
#pragma unroll
    for (int off = 1; off < 64; off <<= 1) {
      int t = __shfl_up(s, off);
      if (lane >= off) s += t;
    }
    if (lane == 63) wsum[wv] = s;
    __syncthreads();
    if (tid < 16) {
      int t = wsum[tid];
      int ss = t;
#pragma unroll
      for (int off = 1; off < 16; off <<= 1) {
        int u = __shfl_up(ss, off);
        if (tid >= off) ss += u;
      }
      wpre[tid] = ss - t;
    }
    __syncthreads();
    int incl = s + wpre[wv];
    int run = s_run;
    if (i < n) {
      int excl = run + incl - v;
      rs[i] = excl;
      cursor[i] = excl;
      degf[i] = (float)(v > 0 ? v : 1);
    }
    __syncthreads();
    if (tid == 1023) s_run = run + wpre[15] + wsum[15];
    __syncthreads();
  }
  if (tid == 0) rs[n] = s_run;
}

__global__ void k_scatter(const int* __restrict__ src, const int* __restrict__ dst,
                          int* __restrict__ cursor, int* __restrict__ csr, int E) {
  int i = blockIdx.x * blockDim.x + threadIdx.x;
  if (i < E) {
    int p = atomicAdd(&cursor[dst[i]], 1);
    csr[p] = src[i];
  }
}

// ---------------- fp32 -> bf16 hi/lo split of x ----------------
__global__ void k_split(const float* __restrict__ x, unsigned short* __restrict__ hi,
                        unsigned short* __restrict__ lo, long n2) {
  long g = (long)blockIdx.x * blockDim.x + threadIdx.x;
  if (g >= n2) return;
  float2 v = ((const float2*)x)[g];
  unsigned short hx = f2bf(v.x), hy = f2bf(v.y);
  unsigned short lx = f2bf(v.x - bf2f(hx)), ly = f2bf(v.y - bf2f(hy));
  ((unsigned*)hi)[g] = (unsigned)hx | ((unsigned)hy << 16);
  ((unsigned*)lo)[g] = (unsigned)lx | ((unsigned)ly << 16);
}

// ---------------- weight pack: fp32 [K=128][N=128] -> frag-order bf16 hi/lo --
// frag f = nt*4 + ks; lane l supplies B[k0 + 8*(l>>4) + r][nt*16 + (l&15)]
__global__ void k_packW(const float* __restrict__ W, unsigned short* __restrict__ hi,
                        unsigned short* __restrict__ lo, int nmat) {
  int gid = blockIdx.x * blockDim.x + threadIdx.x;
  if (gid >= nmat * 2048) return;
  int lane = gid & 63;
  int f = (gid >> 6) & 31;
  int mat = gid >> 11;
  int nt = f >> 2, ks = f & 3;
  int n = nt * 16 + (lane & 15);
  int k0 = ks * 32 + 8 * (lane >> 4);
  const float* Wm = W + (size_t)mat * 16384;
  size_t dst = (size_t)gid * 8;
#pragma unroll
  for (int r = 0; r < 8; ++r) {
    float w = Wm[(size_t)(k0 + r) * 128 + n];
    unsigned short h = f2bf(w);
    hi[dst + r] = h;
    lo[dst + r] = f2bf(w - bf2f(h));
  }
}

// ---------------- mean aggregation over bf16 hi/lo features ----------------
__global__ void k_aggr(const unsigned short* __restrict__ xh,
                       const unsigned short* __restrict__ xl,
                       const int* __restrict__ csr, const int* __restrict__ rs,
                       const float* __restrict__ degf,
                       unsigned short* __restrict__ ah, unsigned short* __restrict__ al,
                       int n) {
  int gid = blockIdx.x * blockDim.x + threadIdx.x;
  int wid = gid >> 6, lane = gid & 63;
  if (wid >= n) return;
  int s = rs[wid], e = rs[wid + 1];
  float ax = 0.f, ay = 0.f;
  int j = s;
  for (; j + 3 < e; j += 4) {
    int s0 = csr[j], s1 = csr[j + 1], s2 = csr[j + 2], s3 = csr[j + 3];
    unsigned h0 = *(const unsigned*)(xh + (size_t)s0 * 128 + lane * 2);
    unsigned l0 = *(const unsigned*)(xl + (size_t)s0 * 128 + lane * 2);
    unsigned h1 = *(const unsigned*)(xh + (size_t)s1 * 128 + lane * 2);
    unsigned l1 = *(const unsigned*)(xl + (size_t)s1 * 128 + lane * 2);
    unsigned h2 = *(const unsigned*)(xh + (size_t)s2 * 128 + lane * 2);
    unsigned l2 = *(const unsigned*)(xl + (size_t)s2 * 128 + lane * 2);
    unsigned h3 = *(const unsigned*)(xh + (size_t)s3 * 128 + lane * 2);
    unsigned l3 = *(const unsigned*)(xl + (size_t)s3 * 128 + lane * 2);
    ax += (lo16f(h0) + lo16f(l0)) + (lo16f(h1) + lo16f(l1)) +
          (lo16f(h2) + lo16f(l2)) + (lo16f(h3) + lo16f(l3));
    ay += (hi16f(h0) + hi16f(l0)) + (hi16f(h1) + hi16f(l1)) +
          (hi16f(h2) + hi16f(l2)) + (hi16f(h3) + hi16f(l3));
  }
  for (; j < e; ++j) {
    int sv = csr[j];
    unsigned h = *(const unsigned*)(xh + (size_t)sv * 128 + lane * 2);
    unsigned l = *(const unsigned*)(xl + (size_t)sv * 128 + lane * 2);
    ax += lo16f(h) + lo16f(l);
    ay += hi16f(h) + hi16f(l);
  }
  float inv = 1.0f / degf[wid];
  float mx = ax * inv, my = ay * inv;
  unsigned short hx = f2bf(mx), hy = f2bf(my);
  unsigned short lx = f2bf(mx - bf2f(hx)), ly = f2bf(my - bf2f(hy));
  *(unsigned*)(ah + (size_t)wid * 128 + lane * 2) = (unsigned)hx | ((unsigned)hy << 16);
  *(unsigned*)(al + (size_t)wid * 128 + lane * 2) = (unsigned)lx | ((unsigned)ly << 16);
}

// ---------------- MFMA GEMM: OUT = epi( sum_p A_p @ W_p + bias ) ------------
// Block = 64 rows (4 waves x 16 rows), NT output 16-col tiles.
// EPI: 0 = relu + split-out hi/lo; 1 = split-out hi/lo; 2 = bf16 u|v out.
template <int NPHASE, int NT, int EPI>
__global__ __launch_bounds__(256) void k_gemm(
    const unsigned short* __restrict__ A0h, const unsigned short* __restrict__ A0l,
    const unsigned short* __restrict__ A1h, const unsigned short* __restrict__ A1l,
    const unsigned short* __restrict__ W0h, const unsigned short* __restrict__ W0l,
    const unsigned short* __restrict__ W1h, const unsigned short* __restrict__ W1l,
    const float* __restrict__ bias,
    unsigned short* __restrict__ O0, unsigned short* __restrict__ O1, int nrows) {
  const int lane = threadIdx.x & 63;
  const int wv = threadIdx.x >> 6;
  const int rowbase = blockIdx.x * 64 + wv * 16;
  const int arow0 = rowbase + (lane & 15);
  const long arow = (arow0 < nrows) ? arow0 : (long)(nrows - 1);
  const int kgrp = (lane >> 4) * 8;

  f32x4 zero = {0.f, 0.f, 0.f, 0.f};
  f32x4 acc[NT];
#pragma unroll
  for (int t = 0; t < NT; ++t) acc[t] = zero;

#pragma unroll
  for (int p = 0; p < NPHASE; ++p) {
    const unsigned short* Ah = p ? A1h : A0h;
    const unsigned short* Al = p ? A1l : A0l;
    const unsigned short* Wh = p ? W1h : W0h;
    const unsigned short* Wl_ = p ? W1l : W0l;
#pragma unroll
    for (int ks = 0; ks < 4; ++ks) {
      bf16x8 a_h = *(const bf16x8*)(Ah + arow * 128 + ks * 32 + kgrp);
      bf16x8 a_l = *(const bf16x8*)(Al + arow * 128 + ks * 32 + kgrp);
#pragma unroll
      for (int nt = 0; nt < NT; ++nt) {
        const long fo = (((long)(nt * 4 + ks)) * 64 + lane) * 8;
        bf16x8 b_h = *(const bf16x8*)(Wh + fo);
        bf16x8 b_l = *(const bf16x8*)(Wl_ + fo);
        acc[nt] = __builtin_amdgcn_mfma_f32_16x16x32_bf16(a_h, b_h, acc[nt], 0, 0, 0);
        acc[nt] = __builtin_amdgcn_mfma_f32_16x16x32_bf16(a_l, b_h, acc[nt], 0, 0, 0);
        acc[nt] = __builtin_amdgcn_mfma_f32_16x16x32_bf16(a_h, b_l, acc[nt], 0, 0, 0);
      }
    }
  }

  const int c = lane & 15;
  const int rbase = rowbase + (lane >> 4) * 4;
#pragma unroll
  for (int nt = 0; nt < NT; ++nt) {
    int col = nt * 16 + c;
    float bv = bias[col];
#pragma unroll
    for (int j = 0; j < 4; ++j) {
      int row = rbase + j;
      if (row >= nrows) continue;
      float val = acc[nt][j] + bv;
      if (EPI == 0) val = fmaxf(val, 0.f);
      if (EPI == 2) {
        unsigned short h = f2bf(val);
        if (nt < 8) O0[(long)row * 128 + col] = h;
        else O1[(long)row * 128 + (col - 128)] = h;
      } else {
        unsigned short h = f2bf(val);
        unsigned short l = f2bf(val - bf2f(h));
        O0[(long)row * 128 + col] = h;
        O1[(long)row * 128 + col] = l;
      }
    }
  }
}

// ---------------- predict pair: y = relu(u[i]+v[j]) . qW2 + qb2 -------------
__global__ __launch_bounds__(256) void k_pair(
    const unsigned short* __restrict__ u, const unsigned short* __restrict__ v,
    const int* __restrict__ ps, const int* __restrict__ pd,
    const float* __restrict__ qW2, const float* __restrict__ qb2,
    float* __restrict__ out, int EP) {
  int gid = blockIdx.x * blockDim.x + threadIdx.x;
  int wid = gid >> 6, lane = gid & 63;
  int base = wid * 4;
  if (base >= EP) return;
  float2 q = *(const float2*)(qW2 + lane * 2);
  float qb = qb2[0];
  int n = EP - base;
  n = n < 4 ? n : 4;
  unsigned a[4], b[4];
#pragma unroll
  for (int p = 0; p < 4; ++p) {
    int pp = (p < n) ? base + p : base;
    int i = ps[pp], j = pd[pp];
    a[p] = *(const unsigned*)(u + (size_t)i * 128 + lane * 2);
    b[p] = *(const unsigned*)(v + (size_t)j * 128 + lane * 2);
  }
#pragma unroll
  for (int p = 0; p < 4; ++p) {
    float hx = fmaxf(lo16f(a[p]) + lo16f(b[p]), 0.f);
    float hy = fmaxf(hi16f(a[p]) + hi16f(b[p]), 0.f);
    float part = fmaf(hy, q.y, hx * q.x);
#pragma unroll
    for (int m = 1; m < 64; m <<= 1) part += __shfl_xor(part, m);
    if (lane == 0 && p < n) out[base + p] = part + qb;
  }
}

extern "C" void kernel_launch(void* const* d_in, const int* in_sizes, int n_in,
                              void* d_out, int out_size, void* d_ws, size_t ws_size,
                              hipStream_t stream) {
  const float* x_in = (const float*)d_in[0];
  // d_in[1] edge_attr: dead
  const int* ei = (const int*)d_in[2];
  const int* pe = (const int*)d_in[3];
  const float* Wl = (const float*)d_in[4];
  const float* bl = (const float*)d_in[5];
  const float* Wr = (const float*)d_in[6];
  // d_in[7..10] edge-update weights: dead
  const float* pW1 = (const float*)d_in[11];
  const float* pb1 = (const float*)d_in[12];
  const float* pW2 = (const float*)d_in[13];
  const float* pb2 = (const float*)d_in[14];
  const float* qW1 = (const float*)d_in[15];
  const float* qb1 = (const float*)d_in[16];
  const float* qW2 = (const float*)d_in[17];
  const float* qb2 = (const float*)d_in[18];

  const int N = in_sizes[0] / 128;
  const int E = in_sizes[2] / 2;
  const int EP = in_sizes[3] / 2;
  const int* e_src = ei;
  const int* e_dst = ei + E;
  const int* p_src = pe;
  const int* p_dst = pe + EP;

  char* ws = (char*)d_ws;
  size_t off = 0;
  auto alloc = [&](size_t bytes) {
    void* p = ws + off;
    off += (bytes + 511) & ~(size_t)511;
    return p;
  };
  unsigned short* xhi = (unsigned short*)alloc((size_t)N * 128 * 2);  // 12.8 MB
  unsigned short* xlo = (unsigned short*)alloc((size_t)N * 128 * 2);
  unsigned short* ahi = (unsigned short*)alloc((size_t)N * 128 * 2);
  unsigned short* alo = (unsigned short*)alloc((size_t)N * 128 * 2);
  int* deg_i = (int*)alloc((size_t)N * 4);
  int* rs = (int*)alloc((size_t)(N + 1) * 4);
  int* cursor = (int*)alloc((size_t)N * 4);
  float* degf = (float*)alloc((size_t)N * 4);
  int* csr = (int*)alloc((size_t)E * 4);
  // packed weights: 10 mats x 16384 ushorts (Wl0-2, Wr0-2, pW1, pW2, qW1t, qW1b)
  unsigned short* Whi = (unsigned short*)alloc((size_t)10 * 16384 * 2);
  unsigned short* Wlo = (unsigned short*)alloc((size_t)10 * 16384 * 2);
  float* biasuv = (float*)alloc(256 * 4);

  const size_t MS = 16384;  // mat stride in ushorts

  hipMemsetAsync(deg_i, 0, (size_t)N * 4, stream);
  hipMemcpyAsync(biasuv, qb1, 128 * 4, hipMemcpyDeviceToDevice, stream);
  hipMemsetAsync(biasuv + 128, 0, 128 * 4, stream);

  // pack weights (frag order, hi/lo split)
  k_packW<<<(3 * 2048 + 255) / 256, 256, 0, stream>>>(Wl, Whi + 0 * MS, Wlo + 0 * MS, 3);
  k_packW<<<(3 * 2048 + 255) / 256, 256, 0, stream>>>(Wr, Whi + 3 * MS, Wlo + 3 * MS, 3);
  k_packW<<<(2048 + 255) / 256, 256, 0, stream>>>(pW1, Whi + 6 * MS, Wlo + 6 * MS, 1);
  k_packW<<<(2048 + 255) / 256, 256, 0, stream>>>(pW2, Whi + 7 * MS, Wlo + 7 * MS, 1);
  k_packW<<<(2 * 2048 + 255) / 256, 256, 0, stream>>>(qW1, Whi + 8 * MS, Wlo + 8 * MS, 2);

  // x -> bf16 hi/lo
  long n2 = (long)N * 64;
  k_split<<<(int)((n2 + 255) / 256), 256, 0, stream>>>(x_in, xhi, xlo, n2);

  // CSR
  k_count<<<(E + 255) / 256, 256, 0, stream>>>(e_dst, deg_i, E);
  k_scan<<<1, 1024, 0, stream>>>(deg_i, rs, cursor, degf, N);
  k_scatter<<<(E + 255) / 256, 256, 0, stream>>>(e_src, e_dst, cursor, csr, E);

  const int mmblocks = (N + 63) / 64;
  const int agblocks = (N + 3) / 4;
  for (int l = 0; l < 3; ++l) {
    k_aggr<<<agblocks, 256, 0, stream>>>(xhi, xlo, csr, rs, degf, ahi, alo, N);
    // x = relu(aggr@Wl + x@Wr + bl); in-place safe (rows wave-owned)
    k_gemm<2, 8, 0><<<mmblocks, 256, 0, stream>>>(
        ahi, alo, xhi, xlo, Whi + (size_t)l * MS, Wlo + (size_t)l * MS,
        Whi + (size_t)(3 + l) * MS, Wlo + (size_t)(3 + l) * MS,
        bl + (size_t)l * 128, xhi, xlo, N);
  }
  // h = relu(x@pW1+pb1) -> ahi/alo
  k_gemm<1, 8, 0><<<mmblocks, 256, 0, stream>>>(
      xhi, xlo, nullptr, nullptr, Whi + 6 * MS, Wlo + 6 * MS, nullptr, nullptr,
      pb1, ahi, alo, N);
  // x2 = h@pW2+pb2 -> xhi/xlo
  k_gemm<1, 8, 1><<<mmblocks, 256, 0, stream>>>(
      ahi, alo, nullptr, nullptr, Whi + 7 * MS, Wlo + 7 * MS, nullptr, nullptr,
      pb2, xhi, xlo, N);
  // u = x2@qW1t + qb1 -> ahi (bf16) ; v = x2@qW1b -> alo (bf16)
  k_gemm<1, 16, 2><<<mmblocks, 256, 0, stream>>>(
      xhi, xlo, nullptr, nullptr, Whi + 8 * MS, Wlo + 8 * MS, nullptr, nullptr,
      biasuv, ahi, alo, N);
  // y = relu(u[i]+v[j]) . qW2 + qb2
  k_pair<<<(EP + 15) / 16, 256, 0, stream>>>(ahi, alo, p_src, p_dst, qW2, qb2,
                                             (float*)d_out, EP);
}

// Round 4
// 460.397 us; speedup vs baseline: 2.1162x; 1.0998x over previous
//
#include <hip/hip_runtime.h>

// ---------------------------------------------------------------------------
// GNNStack — dead-code-eliminated (edge-update MLPs never reach the output).
// All matmuls on MFMA bf16 with hi/lo split precision (fp32-equivalent):
//   C = Ahi*Bhi + Alo*Bhi + Ahi*Blo   (AloBlo ~ 1.6e-5 relative, dropped)
// Node features stored as bf16 hi/lo row-major; weights pre-packed into
// per-lane MFMA fragment order (verified gfx950 16x16x32 layout).
// Scan is hierarchical (49-block local + 1-wave block-sum + offset add).
// ---------------------------------------------------------------------------

typedef __attribute__((ext_vector_type(8))) short bf16x8;
typedef __attribute__((ext_vector_type(4))) float f32x4;

__device__ __forceinline__ unsigned short f2bf(float x) {
  unsigned u = __float_as_uint(x);
  u += 0x7fffu + ((u >> 16) & 1u);
  return (unsigned short)(u >> 16);
}
__device__ __forceinline__ float bf2f(unsigned short h) {
  return __uint_as_float(((unsigned)h) << 16);
}
__device__ __forceinline__ float lo16f(unsigned u) { return __uint_as_float(u << 16); }
__device__ __forceinline__ float hi16f(unsigned u) { return __uint_as_float(u & 0xffff0000u); }

// ---------------- CSR build ----------------
__global__ void k_count(const int* __restrict__ dst, int* __restrict__ cnt, int E) {
  int i = blockIdx.x * blockDim.x + threadIdx.x;
  if (i < E) atomicAdd(&cnt[dst[i]], 1);
}

// pass 1: per-block (1024 elems) exclusive scan -> rs (local), block total -> bsum
__global__ void k_scan1(const int* __restrict__ cnt, int* __restrict__ rs,
                        float* __restrict__ degf, int* __restrict__ bsum, int n) {
  __shared__ int wsum[16];
  __shared__ int wpre[16];
  const int tid = threadIdx.x;
  const int lane = tid & 63;
  const int wv = tid >> 6;
  int i = blockIdx.x * 1024 + tid;
  int v = (i < n) ? cnt[i] : 0;
  int s = v;
#pragma unroll
  for (int off = 1; off < 64; off <<= 1) {
    int t = __shfl_up(s, off);
    if (lane >= off) s += t;
  }
  if (lane == 63) wsum[wv] = s;
  __syncthreads();
  if (tid < 16) {
    int t = wsum[tid];
    int ss = t;
#pragma unroll
    for (int off = 1; off < 16; off <<= 1) {
      int u = __shfl_up(ss, off);
      if (tid >= off) ss += u;
    }
    wpre[tid] = ss - t;
  }
  __syncthreads();
  if (i < n) {
    rs[i] = s - v + wpre[wv];  // local exclusive
    degf[i] = (float)(v > 0 ? v : 1);
  }
  if (tid == 1023) bsum[blockIdx.x] = wpre[15] + wsum[15];
}

// pass 2: single wave scans block sums (nb <= 64) -> exclusive boff; rs[n]=total
__global__ void k_scan2(const int* __restrict__ bsum, int* __restrict__ boff,
                        int* __restrict__ rs_n, int nb) {
  int tid = threadIdx.x;  // 64 threads
  int v = (tid < nb) ? bsum[tid] : 0;
  int s = v;
#pragma unroll
  for (int off = 1; off < 64; off <<= 1) {
    int t = __shfl_up(s, off);
    if (tid >= off) s += t;
  }
  if (tid < nb) boff[tid] = s - v;
  if (tid == 63) rs_n[0] = s;
}

// pass 3: add block offsets; init cursor
__global__ void k_scan3(int* __restrict__ rs, const int* __restrict__ boff,
                        int* __restrict__ cursor, int n) {
  int i = blockIdx.x * blockDim.x + threadIdx.x;
  if (i < n) {
    int r = rs[i] + boff[i >> 10];
    rs[i] = r;
    cursor[i] = r;
  }
}

__global__ void k_scatter(const int* __restrict__ src, const int* __restrict__ dst,
                          int* __restrict__ cursor, int* __restrict__ csr, int E) {
  int i = blockIdx.x * blockDim.x + threadIdx.x;
  if (i < E) {
    int p = atomicAdd(&cursor[dst[i]], 1);
    csr[p] = src[i];
  }
}

// ---------------- fp32 -> bf16 hi/lo split of x ----------------
__global__ void k_split(const float* __restrict__ x, unsigned short* __restrict__ hi,
                        unsigned short* __restrict__ lo, long n2) {
  long g = (long)blockIdx.x * blockDim.x + threadIdx.x;
  if (g >= n2) return;
  float2 v = ((const float2*)x)[g];
  unsigned short hx = f2bf(v.x), hy = f2bf(v.y);
  unsigned short lx = f2bf(v.x - bf2f(hx)), ly = f2bf(v.y - bf2f(hy));
  ((unsigned*)hi)[g] = (unsigned)hx | ((unsigned)hy << 16);
  ((unsigned*)lo)[g] = (unsigned)lx | ((unsigned)ly << 16);
}

// ---------------- weight pack: fp32 [K=128][N=128] -> frag-order bf16 hi/lo --
// frag f = nt*4 + ks; lane l supplies B[k0 + 8*(l>>4) + r][nt*16 + (l&15)]
__global__ void k_packW(const float* __restrict__ W, unsigned short* __restrict__ hi,
                        unsigned short* __restrict__ lo, int nmat) {
  int gid = blockIdx.x * blockDim.x + threadIdx.x;
  if (gid >= nmat * 2048) return;
  int lane = gid & 63;
  int f = (gid >> 6) & 31;
  int mat = gid >> 11;
  int nt = f >> 2, ks = f & 3;
  int n = nt * 16 + (lane & 15);
  int k0 = ks * 32 + 8 * (lane >> 4);
  const float* Wm = W + (size_t)mat * 16384;
  size_t dst = (size_t)gid * 8;
#pragma unroll
  for (int r = 0; r < 8; ++r) {
    float w = Wm[(size_t)(k0 + r) * 128 + n];
    unsigned short h = f2bf(w);
    hi[dst + r] = h;
    lo[dst + r] = f2bf(w - bf2f(h));
  }
}

// ---------------- mean aggregation over bf16 hi/lo features ----------------
// One wave per dst node. Lane covers 4 dims (8B loads); the two 32-lane
// halves process 2 neighbors concurrently; combined via shfl_xor(·,32).
__global__ void k_aggr(const unsigned short* __restrict__ xh,
                       const unsigned short* __restrict__ xl,
                       const int* __restrict__ csr, const int* __restrict__ rs,
                       const float* __restrict__ degf,
                       unsigned short* __restrict__ ah, unsigned short* __restrict__ al,
                       int n) {
  int gid = blockIdx.x * blockDim.x + threadIdx.x;
  int wid = gid >> 6, lane = gid & 63;
  if (wid >= n) return;
  int s = rs[wid], e = rs[wid + 1];
  const int h = lane >> 5;         // neighbor slot (0/1)
  const int dq = (lane & 31) * 4;  // dim-quad base
  float a0 = 0.f, a1 = 0.f, a2 = 0.f, a3 = 0.f;
  int j = s;
  for (; j + 3 < e; j += 4) {
    int n0 = csr[j + h];
    int n1 = csr[j + 2 + h];
    uint2 h0 = *(const uint2*)(xh + (size_t)n0 * 128 + dq);
    uint2 l0 = *(const uint2*)(xl + (size_t)n0 * 128 + dq);
    uint2 h1 = *(const uint2*)(xh + (size_t)n1 * 128 + dq);
    uint2 l1 = *(const uint2*)(xl + (size_t)n1 * 128 + dq);
    a0 += (lo16f(h0.x) + lo16f(l0.x)) + (lo16f(h1.x) + lo16f(l1.x));
    a1 += (hi16f(h0.x) + hi16f(l0.x)) + (hi16f(h1.x) + hi16f(l1.x));
    a2 += (lo16f(h0.y) + lo16f(l0.y)) + (lo16f(h1.y) + lo16f(l1.y));
    a3 += (hi16f(h0.y) + hi16f(l0.y)) + (hi16f(h1.y) + hi16f(l1.y));
  }
  for (; j < e; j += 2) {  // tail: up to 3 neighbors, 2 per step
    int idx = j + h;
    bool ok = idx < e;
    int nn = ok ? csr[idx] : 0;
    uint2 hh = *(const uint2*)(xh + (size_t)nn * 128 + dq);
    uint2 ll = *(const uint2*)(xl + (size_t)nn * 128 + dq);
    float m = ok ? 1.f : 0.f;
    a0 += m * (lo16f(hh.x) + lo16f(ll.x));
    a1 += m * (hi16f(hh.x) + hi16f(ll.x));
    a2 += m * (lo16f(hh.y) + lo16f(ll.y));
    a3 += m * (hi16f(hh.y) + hi16f(ll.y));
  }
  a0 += __shfl_xor(a0, 32);
  a1 += __shfl_xor(a1, 32);
  a2 += __shfl_xor(a2, 32);
  a3 += __shfl_xor(a3, 32);
  if (lane < 32) {
    float inv = 1.0f / degf[wid];
    float m0 = a0 * inv, m1 = a1 * inv, m2 = a2 * inv, m3 = a3 * inv;
    unsigned short h0_ = f2bf(m0), h1_ = f2bf(m1), h2_ = f2bf(m2), h3_ = f2bf(m3);
    uint2 oh, ol;
    oh.x = (unsigned)h0_ | ((unsigned)h1_ << 16);
    oh.y = (unsigned)h2_ | ((unsigned)h3_ << 16);
    ol.x = (unsigned)f2bf(m0 - bf2f(h0_)) | ((unsigned)f2bf(m1 - bf2f(h1_)) << 16);
    ol.y = (unsigned)f2bf(m2 - bf2f(h2_)) | ((unsigned)f2bf(m3 - bf2f(h3_)) << 16);
    *(uint2*)(ah + (size_t)wid * 128 + dq) = oh;
    *(uint2*)(al + (size_t)wid * 128 + dq) = ol;
  }
}

// ---------------- MFMA GEMM: OUT = epi( sum_p A_p @ W_p + bias ) ------------
// Block = 64 rows (4 waves x 16 rows), NT output 16-col tiles.
// EPI: 0 = relu + split-out hi/lo; 1 = split-out hi/lo; 2 = bf16 u|v out.
template <int NPHASE, int NT, int EPI>
__global__ __launch_bounds__(256) void k_gemm(
    const unsigned short* __restrict__ A0h, const unsigned short* __restrict__ A0l,
    const unsigned short* __restrict__ A1h, const unsigned short* __restrict__ A1l,
    const unsigned short* __restrict__ W0h, const unsigned short* __restrict__ W0l,
    const unsigned short* __restrict__ W1h, const unsigned short* __restrict__ W1l,
    const float* __restrict__ bias,
    unsigned short* __restrict__ O0, unsigned short* __restrict__ O1, int nrows) {
  const int lane = threadIdx.x & 63;
  const int wv = threadIdx.x >> 6;
  const int rowbase = blockIdx.x * 64 + wv * 16;
  const int arow0 = rowbase + (lane & 15);
  const long arow = (arow0 < nrows) ? arow0 : (long)(nrows - 1);
  const int kgrp = (lane >> 4) * 8;

  f32x4 zero = {0.f, 0.f, 0.f, 0.f};
  f32x4 acc[NT];
#pragma unroll
  for (int t = 0; t < NT; ++t) acc[t] = zero;

#pragma unroll
  for (int p = 0; p < NPHASE; ++p) {
    const unsigned short* Ah = p ? A1h : A0h;
    const unsigned short* Al = p ? A1l : A0l;
    const unsigned short* Wh = p ? W1h : W0h;
    const unsigned short* Wl_ = p ? W1l : W0l;
#pragma unroll
    for (int ks = 0; ks < 4; ++ks) {
      bf16x8 a_h = *(const bf16x8*)(Ah + arow * 128 + ks * 32 + kgrp);
      bf16x8 a_l = *(const bf16x8*)(Al + arow * 128 + ks * 32 + kgrp);
#pragma unroll
      for (int nt = 0; nt < NT; ++nt) {
        const long fo = (((long)(nt * 4 + ks)) * 64 + lane) * 8;
        bf16x8 b_h = *(const bf16x8*)(Wh + fo);
        bf16x8 b_l = *(const bf16x8*)(Wl_ + fo);
        acc[nt] = __builtin_amdgcn_mfma_f32_16x16x32_bf16(a_h, b_h, acc[nt], 0, 0, 0);
        acc[nt] = __builtin_amdgcn_mfma_f32_16x16x32_bf16(a_l, b_h, acc[nt], 0, 0, 0);
        acc[nt] = __builtin_amdgcn_mfma_f32_16x16x32_bf16(a_h, b_l, acc[nt], 0, 0, 0);
      }
    }
  }

  const int c = lane & 15;
  const int rbase = rowbase + (lane >> 4) * 4;
#pragma unroll
  for (int nt = 0; nt < NT; ++nt) {
    int col = nt * 16 + c;
    float bv = bias[col];
#pragma unroll
    for (int j = 0; j < 4; ++j) {
      int row = rbase + j;
      if (row >= nrows) continue;
      float val = acc[nt][j] + bv;
      if (EPI == 0) val = fmaxf(val, 0.f);
      if (EPI == 2) {
        unsigned short h = f2bf(val);
        if (nt < 8) O0[(long)row * 128 + col] = h;
        else O1[(long)row * 128 + (col - 128)] = h;
      } else {
        unsigned short h = f2bf(val);
        unsigned short l = f2bf(val - bf2f(h));
        O0[(long)row * 128 + col] = h;
        O1[(long)row * 128 + col] = l;
      }
    }
  }
}

// ---------------- predict pair: y = relu(u[i]+v[j]) . qW2 + qb2 -------------
// 16-lane groups; lane covers 8 dims (16B loads); 8 pairs per wave.
__global__ __launch_bounds__(256) void k_pair(
    const unsigned short* __restrict__ u, const unsigned short* __restrict__ v,
    const int* __restrict__ ps, const int* __restrict__ pd,
    const float* __restrict__ qW2, const float* __restrict__ qb2,
    float* __restrict__ out, int EP) {
  int gid = blockIdx.x * blockDim.x + threadIdx.x;
  long wid = gid >> 6;
  int lane = gid & 63;
  int sub = lane & 15, g = lane >> 4;
  long base = wid * 8;
  if (base >= EP) return;
  float4 q0 = *(const float4*)(qW2 + sub * 8);
  float4 q1 = *(const float4*)(qW2 + sub * 8 + 4);
  float qb = qb2[0];

  long p0 = base + g;
  long p1 = base + 4 + g;
  long c0 = (p0 < EP) ? p0 : (EP - 1);
  long c1 = (p1 < EP) ? p1 : (EP - 1);
  int i0 = ps[c0], j0 = pd[c0];
  int i1 = ps[c1], j1 = pd[c1];
  uint4 a0 = *(const uint4*)(u + (size_t)i0 * 128 + sub * 8);
  uint4 b0 = *(const uint4*)(v + (size_t)j0 * 128 + sub * 8);
  uint4 a1 = *(const uint4*)(u + (size_t)i1 * 128 + sub * 8);
  uint4 b1 = *(const uint4*)(v + (size_t)j1 * 128 + sub * 8);

  float s0, s1;
  {
    float t;
    t = fmaxf(lo16f(a0.x) + lo16f(b0.x), 0.f) * q0.x;
    t = fmaf(fmaxf(hi16f(a0.x) + hi16f(b0.x), 0.f), q0.y, t);
    t = fmaf(fmaxf(lo16f(a0.y) + lo16f(b0.y), 0.f), q0.z, t);
    t = fmaf(fmaxf(hi16f(a0.y) + hi16f(b0.y), 0.f), q0.w, t);
    t = fmaf(fmaxf(lo16f(a0.z) + lo16f(b0.z), 0.f), q1.x, t);
    t = fmaf(fmaxf(hi16f(a0.z) + hi16f(b0.z), 0.f), q1.y, t);
    t = fmaf(fmaxf(lo16f(a0.w) + lo16f(b0.w), 0.f), q1.z, t);
    t = fmaf(fmaxf(hi16f(a0.w) + hi16f(b0.w), 0.f), q1.w, t);
    s0 = t;
    t = fmaxf(lo16f(a1.x) + lo16f(b1.x), 0.f) * q0.x;
    t = fmaf(fmaxf(hi16f(a1.x) + hi16f(b1.x), 0.f), q0.y, t);
    t = fmaf(fmaxf(lo16f(a1.y) + lo16f(b1.y), 0.f), q0.z, t);
    t = fmaf(fmaxf(hi16f(a1.y) + hi16f(b1.y), 0.f), q0.w, t);
    t = fmaf(fmaxf(lo16f(a1.z) + lo16f(b1.z), 0.f), q1.x, t);
    t = fmaf(fmaxf(hi16f(a1.z) + hi16f(b1.z), 0.f), q1.y, t);
    t = fmaf(fmaxf(lo16f(a1.w) + lo16f(b1.w), 0.f), q1.z, t);
    t = fmaf(fmaxf(hi16f(a1.w) + hi16f(b1.w), 0.f), q1.w, t);
    s1 = t;
  }
#pragma unroll
  for (int m = 1; m < 16; m <<= 1) {
    s0 += __shfl_xor(s0, m);
    s1 += __shfl_xor(s1, m);
  }
  if (sub == 0) {
    if (p0 < EP) out[p0] = s0 + qb;
    if (p1 < EP) out[p1] = s1 + qb;
  }
}

extern "C" void kernel_launch(void* const* d_in, const int* in_sizes, int n_in,
                              void* d_out, int out_size, void* d_ws, size_t ws_size,
                              hipStream_t stream) {
  const float* x_in = (const float*)d_in[0];
  // d_in[1] edge_attr: dead
  const int* ei = (const int*)d_in[2];
  const int* pe = (const int*)d_in[3];
  const float* Wl = (const float*)d_in[4];
  const float* bl = (const float*)d_in[5];
  const float* Wr = (const float*)d_in[6];
  // d_in[7..10] edge-update weights: dead
  const float* pW1 = (const float*)d_in[11];
  const float* pb1 = (const float*)d_in[12];
  const float* pW2 = (const float*)d_in[13];
  const float* pb2 = (const float*)d_in[14];
  const float* qW1 = (const float*)d_in[15];
  const float* qb1 = (const float*)d_in[16];
  const float* qW2 = (const float*)d_in[17];
  const float* qb2 = (const float*)d_in[18];

  const int N = in_sizes[0] / 128;
  const int E = in_sizes[2] / 2;
  const int EP = in_sizes[3] / 2;
  const int* e_src = ei;
  const int* e_dst = ei + E;
  const int* p_src = pe;
  const int* p_dst = pe + EP;

  char* ws = (char*)d_ws;
  size_t off = 0;
  auto alloc = [&](size_t bytes) {
    void* p = ws + off;
    off += (bytes + 511) & ~(size_t)511;
    return p;
  };
  unsigned short* xhi = (unsigned short*)alloc((size_t)N * 128 * 2);  // 12.8 MB
  unsigned short* xlo = (unsigned short*)alloc((size_t)N * 128 * 2);
  unsigned short* ahi = (unsigned short*)alloc((size_t)N * 128 * 2);
  unsigned short* alo = (unsigned short*)alloc((size_t)N * 128 * 2);
  int* deg_i = (int*)alloc((size_t)N * 4);
  int* rs = (int*)alloc((size_t)(N + 1) * 4);
  int* cursor = (int*)alloc((size_t)N * 4);
  float* degf = (float*)alloc((size_t)N * 4);
  int* csr = (int*)alloc((size_t)E * 4);
  int* bsum = (int*)alloc(64 * 4);
  int* boff = (int*)alloc(64 * 4);
  unsigned short* Whi = (unsigned short*)alloc((size_t)10 * 16384 * 2);
  unsigned short* Wlo = (unsigned short*)alloc((size_t)10 * 16384 * 2);
  float* biasuv = (float*)alloc(256 * 4);

  const size_t MS = 16384;  // mat stride in ushorts
  const int nb = (N + 1023) / 1024;

  hipMemsetAsync(deg_i, 0, (size_t)N * 4, stream);
  hipMemcpyAsync(biasuv, qb1, 128 * 4, hipMemcpyDeviceToDevice, stream);
  hipMemsetAsync(biasuv + 128, 0, 128 * 4, stream);

  // pack weights (frag order, hi/lo split)
  k_packW<<<(3 * 2048 + 255) / 256, 256, 0, stream>>>(Wl, Whi + 0 * MS, Wlo + 0 * MS, 3);
  k_packW<<<(3 * 2048 + 255) / 256, 256, 0, stream>>>(Wr, Whi + 3 * MS, Wlo + 3 * MS, 3);
  k_packW<<<(2048 + 255) / 256, 256, 0, stream>>>(pW1, Whi + 6 * MS, Wlo + 6 * MS, 1);
  k_packW<<<(2048 + 255) / 256, 256, 0, stream>>>(pW2, Whi + 7 * MS, Wlo + 7 * MS, 1);
  k_packW<<<(2 * 2048 + 255) / 256, 256, 0, stream>>>(qW1, Whi + 8 * MS, Wlo + 8 * MS, 2);

  // x -> bf16 hi/lo
  long n2 = (long)N * 64;
  k_split<<<(int)((n2 + 255) / 256), 256, 0, stream>>>(x_in, xhi, xlo, n2);

  // CSR (hierarchical scan)
  k_count<<<(E + 255) / 256, 256, 0, stream>>>(e_dst, deg_i, E);
  k_scan1<<<nb, 1024, 0, stream>>>(deg_i, rs, degf, bsum, N);
  k_scan2<<<1, 64, 0, stream>>>(bsum, boff, rs + N, nb);
  k_scan3<<<(N + 255) / 256, 256, 0, stream>>>(rs, boff, cursor, N);
  k_scatter<<<(E + 255) / 256, 256, 0, stream>>>(e_src, e_dst, cursor, csr, E);

  const int mmblocks = (N + 63) / 64;
  const int agblocks = (N + 3) / 4;
  for (int l = 0; l < 3; ++l) {
    k_aggr<<<agblocks, 256, 0, stream>>>(xhi, xlo, csr, rs, degf, ahi, alo, N);
    // x = relu(aggr@Wl + x@Wr + bl); in-place safe (rows wave-owned)
    k_gemm<2, 8, 0><<<mmblocks, 256, 0, stream>>>(
        ahi, alo, xhi, xlo, Whi + (size_t)l * MS, Wlo + (size_t)l * MS,
        Whi + (size_t)(3 + l) * MS, Wlo + (size_t)(3 + l) * MS,
        bl + (size_t)l * 128, xhi, xlo, N);
  }
  // h = relu(x@pW1+pb1) -> ahi/alo
  k_gemm<1, 8, 0><<<mmblocks, 256, 0, stream>>>(
      xhi, xlo, nullptr, nullptr, Whi + 6 * MS, Wlo + 6 * MS, nullptr, nullptr,
      pb1, ahi, alo, N);
  // x2 = h@pW2+pb2 -> xhi/xlo
  k_gemm<1, 8, 1><<<mmblocks, 256, 0, stream>>>(
      ahi, alo, nullptr, nullptr, Whi + 7 * MS, Wlo + 7 * MS, nullptr, nullptr,
      pb2, xhi, xlo, N);
  // u = x2@qW1t + qb1 -> ahi (bf16) ; v = x2@qW1b -> alo (bf16)
  k_gemm<1, 16, 2><<<mmblocks, 256, 0, stream>>>(
      xhi, xlo, nullptr, nullptr, Whi + 8 * MS, Wlo + 8 * MS, nullptr, nullptr,
      biasuv, ahi, alo, N);
  // y = relu(u[i]+v[j]) . qW2 + qb2
  k_pair<<<(EP + 31) / 32, 256, 0, stream>>>(ahi, alo, p_src, p_dst, qW2, qb2,
                                             (float*)d_out, EP);
}

// Round 5
// 387.726 us; speedup vs baseline: 2.5128x; 1.1874x over previous
//
#include <hip/hip_runtime.h>

// ---------------------------------------------------------------------------
// GNNStack — dead-code-eliminated (edge-update MLPs never reach the output).
// All matmuls on MFMA bf16 with hi/lo split precision (fp32-equivalent):
//   C = Ahi*Bhi + Alo*Bhi + Ahi*Blo   (AloBlo ~ 1.6e-5 relative, dropped)
// GEMM: 8-wave blocks, weights LDS-staged per phase (64 KiB), 32 rows/wave
// so each ds_read_b128 pair feeds 6 MFMAs. Weights pre-packed to fragment
// order (verified gfx950 16x16x32 layout). Hierarchical scan for CSR.
// ---------------------------------------------------------------------------

typedef __attribute__((ext_vector_type(8))) short bf16x8;
typedef __attribute__((ext_vector_type(4))) float f32x4;

__device__ __forceinline__ unsigned short f2bf(float x) {
  unsigned u = __float_as_uint(x);
  u += 0x7fffu + ((u >> 16) & 1u);
  return (unsigned short)(u >> 16);
}
__device__ __forceinline__ float bf2f(unsigned short h) {
  return __uint_as_float(((unsigned)h) << 16);
}
__device__ __forceinline__ float lo16f(unsigned u) { return __uint_as_float(u << 16); }
__device__ __forceinline__ float hi16f(unsigned u) { return __uint_as_float(u & 0xffff0000u); }

// ---------------- CSR build ----------------
__global__ void k_count(const int* __restrict__ dst, int* __restrict__ cnt, int E) {
  int i = blockIdx.x * blockDim.x + threadIdx.x;
  if (i < E) atomicAdd(&cnt[dst[i]], 1);
}

__global__ void k_scan1(const int* __restrict__ cnt, int* __restrict__ rs,
                        float* __restrict__ degf, int* __restrict__ bsum, int n) {
  __shared__ int wsum[16];
  __shared__ int wpre[16];
  const int tid = threadIdx.x;
  const int lane = tid & 63;
  const int wv = tid >> 6;
  int i = blockIdx.x * 1024 + tid;
  int v = (i < n) ? cnt[i] : 0;
  int s = v;
#pragma unroll
  for (int off = 1; off < 64; off <<= 1) {
    int t = __shfl_up(s, off);
    if (lane >= off) s += t;
  }
  if (lane == 63) wsum[wv] = s;
  __syncthreads();
  if (tid < 16) {
    int t = wsum[tid];
    int ss = t;
#pragma unroll
    for (int off = 1; off < 16; off <<= 1) {
      int u = __shfl_up(ss, off);
      if (tid >= off) ss += u;
    }
    wpre[tid] = ss - t;
  }
  __syncthreads();
  if (i < n) {
    rs[i] = s - v + wpre[wv];
    degf[i] = (float)(v > 0 ? v : 1);
  }
  if (tid == 1023) bsum[blockIdx.x] = wpre[15] + wsum[15];
}

__global__ void k_scan2(const int* __restrict__ bsum, int* __restrict__ boff,
                        int* __restrict__ rs_n, int nb) {
  int tid = threadIdx.x;
  int v = (tid < nb) ? bsum[tid] : 0;
  int s = v;
#pragma unroll
  for (int off = 1; off < 64; off <<= 1) {
    int t = __shfl_up(s, off);
    if (tid >= off) s += t;
  }
  if (tid < nb) boff[tid] = s - v;
  if (tid == 63) rs_n[0] = s;
}

__global__ void k_scan3(int* __restrict__ rs, const int* __restrict__ boff,
                        int* __restrict__ cursor, int n) {
  int i = blockIdx.x * blockDim.x + threadIdx.x;
  if (i < n) {
    int r = rs[i] + boff[i >> 10];
    rs[i] = r;
    cursor[i] = r;
  }
}

__global__ void k_scatter(const int* __restrict__ src, const int* __restrict__ dst,
                          int* __restrict__ cursor, int* __restrict__ csr, int E) {
  int i = blockIdx.x * blockDim.x + threadIdx.x;
  if (i < E) {
    int p = atomicAdd(&cursor[dst[i]], 1);
    csr[p] = src[i];
  }
}

// ---------------- fp32 -> bf16 hi/lo split of x ----------------
__global__ void k_split(const float* __restrict__ x, unsigned short* __restrict__ hi,
                        unsigned short* __restrict__ lo, long n2) {
  long g = (long)blockIdx.x * blockDim.x + threadIdx.x;
  if (g >= n2) return;
  float2 v = ((const float2*)x)[g];
  unsigned short hx = f2bf(v.x), hy = f2bf(v.y);
  unsigned short lx = f2bf(v.x - bf2f(hx)), ly = f2bf(v.y - bf2f(hy));
  ((unsigned*)hi)[g] = (unsigned)hx | ((unsigned)hy << 16);
  ((unsigned*)lo)[g] = (unsigned)lx | ((unsigned)ly << 16);
}

// ---------------- weight pack: fp32 [K=128][N=128] -> frag-order bf16 hi/lo --
// frag f = nt*4 + ks; lane l supplies B[k0 + 8*(l>>4) + r][nt*16 + (l&15)]
__global__ void k_packW(const float* __restrict__ W, unsigned short* __restrict__ hi,
                        unsigned short* __restrict__ lo, int nmat) {
  int gid = blockIdx.x * blockDim.x + threadIdx.x;
  if (gid >= nmat * 2048) return;
  int lane = gid & 63;
  int f = (gid >> 6) & 31;
  int mat = gid >> 11;
  int nt = f >> 2, ks = f & 3;
  int n = nt * 16 + (lane & 15);
  int k0 = ks * 32 + 8 * (lane >> 4);
  const float* Wm = W + (size_t)mat * 16384;
  size_t dst = (size_t)gid * 8;
#pragma unroll
  for (int r = 0; r < 8; ++r) {
    float w = Wm[(size_t)(k0 + r) * 128 + n];
    unsigned short h = f2bf(w);
    hi[dst + r] = h;
    lo[dst + r] = f2bf(w - bf2f(h));
  }
}

// ---------------- mean aggregation over bf16 hi/lo features ----------------
__global__ void k_aggr(const unsigned short* __restrict__ xh,
                       const unsigned short* __restrict__ xl,
                       const int* __restrict__ csr, const int* __restrict__ rs,
                       const float* __restrict__ degf,
                       unsigned short* __restrict__ ah, unsigned short* __restrict__ al,
                       int n) {
  int gid = blockIdx.x * blockDim.x + threadIdx.x;
  int wid = gid >> 6, lane = gid & 63;
  if (wid >= n) return;
  int s = rs[wid], e = rs[wid + 1];
  const int h = lane >> 5;         // neighbor slot (0/1)
  const int dq = (lane & 31) * 4;  // dim-quad base
  float a0 = 0.f, a1 = 0.f, a2 = 0.f, a3 = 0.f;
  int j = s;
  for (; j + 3 < e; j += 4) {
    int n0 = csr[j + h];
    int n1 = csr[j + 2 + h];
    uint2 h0 = *(const uint2*)(xh + (size_t)n0 * 128 + dq);
    uint2 l0 = *(const uint2*)(xl + (size_t)n0 * 128 + dq);
    uint2 h1 = *(const uint2*)(xh + (size_t)n1 * 128 + dq);
    uint2 l1 = *(const uint2*)(xl + (size_t)n1 * 128 + dq);
    a0 += (lo16f(h0.x) + lo16f(l0.x)) + (lo16f(h1.x) + lo16f(l1.x));
    a1 += (hi16f(h0.x) + hi16f(l0.x)) + (hi16f(h1.x) + hi16f(l1.x));
    a2 += (lo16f(h0.y) + lo16f(l0.y)) + (lo16f(h1.y) + lo16f(l1.y));
    a3 += (hi16f(h0.y) + hi16f(l0.y)) + (hi16f(h1.y) + hi16f(l1.y));
  }
  for (; j < e; j += 2) {
    int idx = j + h;
    bool ok = idx < e;
    int nn = ok ? csr[idx] : 0;
    uint2 hh = *(const uint2*)(xh + (size_t)nn * 128 + dq);
    uint2 ll = *(const uint2*)(xl + (size_t)nn * 128 + dq);
    float m = ok ? 1.f : 0.f;
    a0 += m * (lo16f(hh.x) + lo16f(ll.x));
    a1 += m * (hi16f(hh.x) + hi16f(ll.x));
    a2 += m * (lo16f(hh.y) + lo16f(ll.y));
    a3 += m * (hi16f(hh.y) + hi16f(ll.y));
  }
  a0 += __shfl_xor(a0, 32);
  a1 += __shfl_xor(a1, 32);
  a2 += __shfl_xor(a2, 32);
  a3 += __shfl_xor(a3, 32);
  if (lane < 32) {
    float inv = 1.0f / degf[wid];
    float m0 = a0 * inv, m1 = a1 * inv, m2 = a2 * inv, m3 = a3 * inv;
    unsigned short h0_ = f2bf(m0), h1_ = f2bf(m1), h2_ = f2bf(m2), h3_ = f2bf(m3);
    uint2 oh, ol;
    oh.x = (unsigned)h0_ | ((unsigned)h1_ << 16);
    oh.y = (unsigned)h2_ | ((unsigned)h3_ << 16);
    ol.x = (unsigned)f2bf(m0 - bf2f(h0_)) | ((unsigned)f2bf(m1 - bf2f(h1_)) << 16);
    ol.y = (unsigned)f2bf(m2 - bf2f(h2_)) | ((unsigned)f2bf(m3 - bf2f(h3_)) << 16);
    *(uint2*)(ah + (size_t)wid * 128 + dq) = oh;
    *(uint2*)(al + (size_t)wid * 128 + dq) = ol;
  }
}

// ---------------- MFMA GEMM, LDS-staged weights ------------------------------
// 512 threads = 8 waves; each wave owns a 32-row tile (RS=2 row-sets of 16).
// Per phase: stage hi+lo frag-packed weights (64 KiB) to LDS, barrier, then
// 4 ks x NT { 2 ds_read_b128 -> 3*RS MFMA }. acc persists across phases.
// EPI: 0 = relu + hi/lo split out; 1 = hi/lo split out; 2 = bf16 out (O0).
template <int NPHASE, int NT, int EPI, int RS>
__global__ __launch_bounds__(512, 2) void k_gemm(
    const unsigned short* __restrict__ A0h, const unsigned short* __restrict__ A0l,
    const unsigned short* __restrict__ A1h, const unsigned short* __restrict__ A1l,
    const unsigned short* __restrict__ W0h, const unsigned short* __restrict__ W0l,
    const unsigned short* __restrict__ W1h, const unsigned short* __restrict__ W1l,
    const float* __restrict__ bias,
    unsigned short* __restrict__ O0, unsigned short* __restrict__ O1, int nrows) {
  __shared__ unsigned short smem[NT * 4096];  // hi: NT*2048, lo: NT*2048 ushorts
  unsigned short* smh = smem;
  unsigned short* sml = smem + NT * 2048;

  const int tid = threadIdx.x;
  const int lane = tid & 63;
  const int wv = tid >> 6;
  const long tile = (long)blockIdx.x * 8 + wv;
  const long row0 = tile * (16 * RS);
  const bool active = row0 < nrows;
  const int kgrp = (lane >> 4) * 8;

  long arow[RS];
#pragma unroll
  for (int rs = 0; rs < RS; ++rs) {
    long r = row0 + rs * 16 + (lane & 15);
    arow[rs] = (r < nrows) ? r : (long)(nrows - 1);
  }

  f32x4 zero = {0.f, 0.f, 0.f, 0.f};
  f32x4 acc[RS][NT];
#pragma unroll
  for (int rs = 0; rs < RS; ++rs)
#pragma unroll
    for (int t = 0; t < NT; ++t) acc[rs][t] = zero;

#pragma unroll
  for (int p = 0; p < NPHASE; ++p) {
    const unsigned short* Ah = p ? A1h : A0h;
    const unsigned short* Al = p ? A1l : A0l;
    const unsigned short* Wh = p ? W1h : W0h;
    const unsigned short* Wl_ = p ? W1l : W0l;
    if (p) __syncthreads();  // protect previous phase's LDS reads
    for (int t = tid; t < NT * 256; t += 512) {  // NT*256 16B chunks per region
      ((uint4*)smh)[t] = ((const uint4*)Wh)[t];
      ((uint4*)sml)[t] = ((const uint4*)Wl_)[t];
    }
    __syncthreads();
    if (active) {
#pragma unroll
      for (int ks = 0; ks < 4; ++ks) {
        bf16x8 a_h[RS], a_l[RS];
#pragma unroll
        for (int rs = 0; rs < RS; ++rs) {
          a_h[rs] = *(const bf16x8*)(Ah + arow[rs] * 128 + ks * 32 + kgrp);
          a_l[rs] = *(const bf16x8*)(Al + arow[rs] * 128 + ks * 32 + kgrp);
        }
#pragma unroll
        for (int nt = 0; nt < NT; ++nt) {
          const bf16x8 b_h = *(const bf16x8*)(smh + (nt * 4 + ks) * 512 + lane * 8);
          const bf16x8 b_l = *(const bf16x8*)(sml + (nt * 4 + ks) * 512 + lane * 8);
#pragma unroll
          for (int rs = 0; rs < RS; ++rs) {
            acc[rs][nt] = __builtin_amdgcn_mfma_f32_16x16x32_bf16(a_h[rs], b_h, acc[rs][nt], 0, 0, 0);
            acc[rs][nt] = __builtin_amdgcn_mfma_f32_16x16x32_bf16(a_l[rs], b_h, acc[rs][nt], 0, 0, 0);
            acc[rs][nt] = __builtin_amdgcn_mfma_f32_16x16x32_bf16(a_h[rs], b_l, acc[rs][nt], 0, 0, 0);
          }
        }
      }
    }
  }
  if (!active) return;

  const int c = lane & 15;
#pragma unroll
  for (int rs = 0; rs < RS; ++rs) {
    const long rbase = row0 + rs * 16 + (lane >> 4) * 4;
#pragma unroll
    for (int nt = 0; nt < NT; ++nt) {
      int col = nt * 16 + c;
      float bv = bias[col];
#pragma unroll
      for (int j = 0; j < 4; ++j) {
        long row = rbase + j;
        if (row >= nrows) continue;
        float val = acc[rs][nt][j] + bv;
        if (EPI == 0) val = fmaxf(val, 0.f);
        unsigned short h = f2bf(val);
        if (EPI == 2) {
          O0[row * 128 + col] = h;
        } else {
          O0[row * 128 + col] = h;
          O1[row * 128 + col] = f2bf(val - bf2f(h));
        }
      }
    }
  }
}

// ---------------- predict pair: y = relu(u[i]+v[j]) . qW2 + qb2 -------------
__global__ __launch_bounds__(256) void k_pair(
    const unsigned short* __restrict__ u, const unsigned short* __restrict__ v,
    const int* __restrict__ ps, const int* __restrict__ pd,
    const float* __restrict__ qW2, const float* __restrict__ qb2,
    float* __restrict__ out, int EP) {
  int gid = blockIdx.x * blockDim.x + threadIdx.x;
  long wid = gid >> 6;
  int lane = gid & 63;
  int sub = lane & 15, g = lane >> 4;
  long base = wid * 8;
  if (base >= EP) return;
  float4 q0 = *(const float4*)(qW2 + sub * 8);
  float4 q1 = *(const float4*)(qW2 + sub * 8 + 4);
  float qb = qb2[0];

  long p0 = base + g;
  long p1 = base + 4 + g;
  long c0 = (p0 < EP) ? p0 : (EP - 1);
  long c1 = (p1 < EP) ? p1 : (EP - 1);
  int i0 = ps[c0], j0 = pd[c0];
  int i1 = ps[c1], j1 = pd[c1];
  uint4 a0 = *(const uint4*)(u + (size_t)i0 * 128 + sub * 8);
  uint4 b0 = *(const uint4*)(v + (size_t)j0 * 128 + sub * 8);
  uint4 a1 = *(const uint4*)(u + (size_t)i1 * 128 + sub * 8);
  uint4 b1 = *(const uint4*)(v + (size_t)j1 * 128 + sub * 8);

  float s0, s1;
  {
    float t;
    t = fmaxf(lo16f(a0.x) + lo16f(b0.x), 0.f) * q0.x;
    t = fmaf(fmaxf(hi16f(a0.x) + hi16f(b0.x), 0.f), q0.y, t);
    t = fmaf(fmaxf(lo16f(a0.y) + lo16f(b0.y), 0.f), q0.z, t);
    t = fmaf(fmaxf(hi16f(a0.y) + hi16f(b0.y), 0.f), q0.w, t);
    t = fmaf(fmaxf(lo16f(a0.z) + lo16f(b0.z), 0.f), q1.x, t);
    t = fmaf(fmaxf(hi16f(a0.z) + hi16f(b0.z), 0.f), q1.y, t);
    t = fmaf(fmaxf(lo16f(a0.w) + lo16f(b0.w), 0.f), q1.z, t);
    t = fmaf(fmaxf(hi16f(a0.w) + hi16f(b0.w), 0.f), q1.w, t);
    s0 = t;
    t = fmaxf(lo16f(a1.x) + lo16f(b1.x), 0.f) * q0.x;
    t = fmaf(fmaxf(hi16f(a1.x) + hi16f(b1.x), 0.f), q0.y, t);
    t = fmaf(fmaxf(lo16f(a1.y) + lo16f(b1.y), 0.f), q0.z, t);
    t = fmaf(fmaxf(hi16f(a1.y) + hi16f(b1.y), 0.f), q0.w, t);
    t = fmaf(fmaxf(lo16f(a1.z) + lo16f(b1.z), 0.f), q1.x, t);
    t = fmaf(fmaxf(hi16f(a1.z) + hi16f(b1.z), 0.f), q1.y, t);
    t = fmaf(fmaxf(lo16f(a1.w) + lo16f(b1.w), 0.f), q1.z, t);
    t = fmaf(fmaxf(hi16f(a1.w) + hi16f(b1.w), 0.f), q1.w, t);
    s1 = t;
  }
#pragma unroll
  for (int m = 1; m < 16; m <<= 1) {
    s0 += __shfl_xor(s0, m);
    s1 += __shfl_xor(s1, m);
  }
  if (sub == 0) {
    if (p0 < EP) out[p0] = s0 + qb;
    if (p1 < EP) out[p1] = s1 + qb;
  }
}

extern "C" void kernel_launch(void* const* d_in, const int* in_sizes, int n_in,
                              void* d_out, int out_size, void* d_ws, size_t ws_size,
                              hipStream_t stream) {
  const float* x_in = (const float*)d_in[0];
  // d_in[1] edge_attr: dead
  const int* ei = (const int*)d_in[2];
  const int* pe = (const int*)d_in[3];
  const float* Wl = (const float*)d_in[4];
  const float* bl = (const float*)d_in[5];
  const float* Wr = (const float*)d_in[6];
  // d_in[7..10] edge-update weights: dead
  const float* pW1 = (const float*)d_in[11];
  const float* pb1 = (const float*)d_in[12];
  const float* pW2 = (const float*)d_in[13];
  const float* pb2 = (const float*)d_in[14];
  const float* qW1 = (const float*)d_in[15];
  const float* qb1 = (const float*)d_in[16];
  const float* qW2 = (const float*)d_in[17];
  const float* qb2 = (const float*)d_in[18];

  const int N = in_sizes[0] / 128;
  const int E = in_sizes[2] / 2;
  const int EP = in_sizes[3] / 2;
  const int* e_src = ei;
  const int* e_dst = ei + E;
  const int* p_src = pe;
  const int* p_dst = pe + EP;

  char* ws = (char*)d_ws;
  size_t off = 0;
  auto alloc = [&](size_t bytes) {
    void* p = ws + off;
    off += (bytes + 511) & ~(size_t)511;
    return p;
  };
  unsigned short* xhi = (unsigned short*)alloc((size_t)N * 128 * 2);
  unsigned short* xlo = (unsigned short*)alloc((size_t)N * 128 * 2);
  unsigned short* ahi = (unsigned short*)alloc((size_t)N * 128 * 2);
  unsigned short* alo = (unsigned short*)alloc((size_t)N * 128 * 2);
  int* deg_i = (int*)alloc((size_t)N * 4);
  int* rs = (int*)alloc((size_t)(N + 1) * 4);
  int* cursor = (int*)alloc((size_t)N * 4);
  float* degf = (float*)alloc((size_t)N * 4);
  int* csr = (int*)alloc((size_t)E * 4);
  int* bsum = (int*)alloc(64 * 4);
  int* boff = (int*)alloc(64 * 4);
  unsigned short* Whi = (unsigned short*)alloc((size_t)10 * 16384 * 2);
  unsigned short* Wlo = (unsigned short*)alloc((size_t)10 * 16384 * 2);
  float* biasuv = (float*)alloc(256 * 4);

  const size_t MS = 16384;  // mat stride in ushorts
  const int nb = (N + 1023) / 1024;

  hipMemsetAsync(deg_i, 0, (size_t)N * 4, stream);
  hipMemcpyAsync(biasuv, qb1, 128 * 4, hipMemcpyDeviceToDevice, stream);
  hipMemsetAsync(biasuv + 128, 0, 128 * 4, stream);

  // pack weights (frag order, hi/lo split); mats 8,9 = qW1 top/bottom
  k_packW<<<(3 * 2048 + 255) / 256, 256, 0, stream>>>(Wl, Whi + 0 * MS, Wlo + 0 * MS, 3);
  k_packW<<<(3 * 2048 + 255) / 256, 256, 0, stream>>>(Wr, Whi + 3 * MS, Wlo + 3 * MS, 3);
  k_packW<<<(2048 + 255) / 256, 256, 0, stream>>>(pW1, Whi + 6 * MS, Wlo + 6 * MS, 1);
  k_packW<<<(2048 + 255) / 256, 256, 0, stream>>>(pW2, Whi + 7 * MS, Wlo + 7 * MS, 1);
  k_packW<<<(2 * 2048 + 255) / 256, 256, 0, stream>>>(qW1, Whi + 8 * MS, Wlo + 8 * MS, 2);

  // x -> bf16 hi/lo
  long n2 = (long)N * 64;
  k_split<<<(int)((n2 + 255) / 256), 256, 0, stream>>>(x_in, xhi, xlo, n2);

  // CSR (hierarchical scan)
  k_count<<<(E + 255) / 256, 256, 0, stream>>>(e_dst, deg_i, E);
  k_scan1<<<nb, 1024, 0, stream>>>(deg_i, rs, degf, bsum, N);
  k_scan2<<<1, 64, 0, stream>>>(bsum, boff, rs + N, nb);
  k_scan3<<<(N + 255) / 256, 256, 0, stream>>>(rs, boff, cursor, N);
  k_scatter<<<(E + 255) / 256, 256, 0, stream>>>(e_src, e_dst, cursor, csr, E);

  // gemm grid: 32 rows/wave, 8 waves/block
  const int gmm = ((N + 31) / 32 + 7) / 8;
  const int agblocks = (N + 3) / 4;
  for (int l = 0; l < 3; ++l) {
    k_aggr<<<agblocks, 256, 0, stream>>>(xhi, xlo, csr, rs, degf, ahi, alo, N);
    // x = relu(aggr@Wl + x@Wr + bl); in-place safe (rows wave-owned; all
    // phase reads precede that wave's epilogue stores)
    k_gemm<2, 8, 0, 2><<<gmm, 512, 0, stream>>>(
        ahi, alo, xhi, xlo, Whi + (size_t)l * MS, Wlo + (size_t)l * MS,
        Whi + (size_t)(3 + l) * MS, Wlo + (size_t)(3 + l) * MS,
        bl + (size_t)l * 128, xhi, xlo, N);
  }
  // h = relu(x@pW1+pb1) -> ahi/alo
  k_gemm<1, 8, 0, 2><<<gmm, 512, 0, stream>>>(
      xhi, xlo, nullptr, nullptr, Whi + 6 * MS, Wlo + 6 * MS, nullptr, nullptr,
      pb1, ahi, alo, N);
  // x2 = h@pW2+pb2 -> xhi/xlo
  k_gemm<1, 8, 1, 2><<<gmm, 512, 0, stream>>>(
      ahi, alo, nullptr, nullptr, Whi + 7 * MS, Wlo + 7 * MS, nullptr, nullptr,
      pb2, xhi, xlo, N);
  // u = x2@qW1t + qb1 -> ahi (bf16) ; v = x2@qW1b -> alo (bf16)
  k_gemm<1, 8, 2, 2><<<gmm, 512, 0, stream>>>(
      xhi, xlo, nullptr, nullptr, Whi + 8 * MS, Wlo + 8 * MS, nullptr, nullptr,
      biasuv, ahi, nullptr, N);
  k_gemm<1, 8, 2, 2><<<gmm, 512, 0, stream>>>(
      xhi, xlo, nullptr, nullptr, Whi + 9 * MS, Wlo + 9 * MS, nullptr, nullptr,
      biasuv + 128, alo, nullptr, N);
  // y = relu(u[i]+v[j]) . qW2 + qb2
  k_pair<<<(EP + 31) / 32, 256, 0, stream>>>(ahi, alo, p_src, p_dst, qW2, qb2,
                                             (float*)d_out, EP);
}

// Round 6
// 382.967 us; speedup vs baseline: 2.5441x; 1.0124x over previous
//
#include <hip/hip_runtime.h>

// ---------------------------------------------------------------------------
// GNNStack — dead-code-eliminated (edge-update MLPs never reach the output).
// All matmuls on MFMA bf16 with hi/lo split precision (fp32-equivalent):
//   C = Ahi*Bhi + Alo*Bhi + Ahi*Blo   (AloBlo ~ 1.6e-5 relative, dropped)
// Node features stored INTERLEAVED: [node][hi 128 bf16 | lo 128 bf16] (512 B
// row) so the aggregation gather is one uint4/lane = 2 neighbors per load
// instruction, 8-edge unrolled (4 KB in flight per wave).
// GEMM: 8-wave blocks, weights LDS-staged per phase (64 KiB), 32 rows/wave.
// ---------------------------------------------------------------------------

typedef __attribute__((ext_vector_type(8))) short bf16x8;
typedef __attribute__((ext_vector_type(4))) float f32x4;

__device__ __forceinline__ unsigned short f2bf(float x) {
  unsigned u = __float_as_uint(x);
  u += 0x7fffu + ((u >> 16) & 1u);
  return (unsigned short)(u >> 16);
}
__device__ __forceinline__ float bf2f(unsigned short h) {
  return __uint_as_float(((unsigned)h) << 16);
}
__device__ __forceinline__ float lo16f(unsigned u) { return __uint_as_float(u << 16); }
__device__ __forceinline__ float hi16f(unsigned u) { return __uint_as_float(u & 0xffff0000u); }

// ---------------- CSR build ----------------
__global__ void k_count(const int* __restrict__ dst, int* __restrict__ cnt, int E) {
  int i = blockIdx.x * blockDim.x + threadIdx.x;
  if (i < E) atomicAdd(&cnt[dst[i]], 1);
}

__global__ void k_scan1(const int* __restrict__ cnt, int* __restrict__ rs,
                        float* __restrict__ degf, int* __restrict__ bsum, int n) {
  __shared__ int wsum[16];
  __shared__ int wpre[16];
  const int tid = threadIdx.x;
  const int lane = tid & 63;
  const int wv = tid >> 6;
  int i = blockIdx.x * 1024 + tid;
  int v = (i < n) ? cnt[i] : 0;
  int s = v;
#pragma unroll
  for (int off = 1; off < 64; off <<= 1) {
    int t = __shfl_up(s, off);
    if (lane >= off) s += t;
  }
  if (lane == 63) wsum[wv] = s;
  __syncthreads();
  if (tid < 16) {
    int t = wsum[tid];
    int ss = t;
#pragma unroll
    for (int off = 1; off < 16; off <<= 1) {
      int u = __shfl_up(ss, off);
      if (tid >= off) ss += u;
    }
    wpre[tid] = ss - t;
  }
  __syncthreads();
  if (i < n) {
    rs[i] = s - v + wpre[wv];
    degf[i] = (float)(v > 0 ? v : 1);
  }
  if (tid == 1023) bsum[blockIdx.x] = wpre[15] + wsum[15];
}

__global__ void k_scan2(const int* __restrict__ bsum, int* __restrict__ boff,
                        int* __restrict__ rs_n, int nb) {
  int tid = threadIdx.x;
  int v = (tid < nb) ? bsum[tid] : 0;
  int s = v;
#pragma unroll
  for (int off = 1; off < 64; off <<= 1) {
    int t = __shfl_up(s, off);
    if (tid >= off) s += t;
  }
  if (tid < nb) boff[tid] = s - v;
  if (tid == 63) rs_n[0] = s;
}

__global__ void k_scan3(int* __restrict__ rs, const int* __restrict__ boff,
                        int* __restrict__ cursor, int n) {
  int i = blockIdx.x * blockDim.x + threadIdx.x;
  if (i < n) {
    int r = rs[i] + boff[i >> 10];
    rs[i] = r;
    cursor[i] = r;
  }
}

__global__ void k_scatter(const int* __restrict__ src, const int* __restrict__ dst,
                          int* __restrict__ cursor, int* __restrict__ csr, int E) {
  int i = blockIdx.x * blockDim.x + threadIdx.x;
  if (i < E) {
    int p = atomicAdd(&cursor[dst[i]], 1);
    csr[p] = src[i];
  }
}

// ---------------- fp32 -> interleaved hi|lo bf16 row ----------------
// X row layout (u32 view, 128 words): [0..63]=hi pairs, [64..127]=lo pairs
__global__ void k_split(const float* __restrict__ x, unsigned* __restrict__ X,
                        long n2) {
  long g = (long)blockIdx.x * blockDim.x + threadIdx.x;
  if (g >= n2) return;
  float2 v = ((const float2*)x)[g];
  unsigned short hx = f2bf(v.x), hy = f2bf(v.y);
  unsigned short lx = f2bf(v.x - bf2f(hx)), ly = f2bf(v.y - bf2f(hy));
  long row = g >> 6, p = g & 63;
  X[row * 128 + p] = (unsigned)hx | ((unsigned)hy << 16);
  X[row * 128 + 64 + p] = (unsigned)lx | ((unsigned)ly << 16);
}

// ---------------- weight pack: fp32 [K=128][N=128] -> frag-order bf16 hi/lo --
// frag f = nt*4 + ks; lane l supplies B[k0 + 8*(l>>4) + r][nt*16 + (l&15)]
__global__ void k_packW(const float* __restrict__ W, unsigned short* __restrict__ hi,
                        unsigned short* __restrict__ lo, int nmat) {
  int gid = blockIdx.x * blockDim.x + threadIdx.x;
  if (gid >= nmat * 2048) return;
  int lane = gid & 63;
  int f = (gid >> 6) & 31;
  int mat = gid >> 11;
  int nt = f >> 2, ks = f & 3;
  int n = nt * 16 + (lane & 15);
  int k0 = ks * 32 + 8 * (lane >> 4);
  const float* Wm = W + (size_t)mat * 16384;
  size_t dst = (size_t)gid * 8;
#pragma unroll
  for (int r = 0; r < 8; ++r) {
    float w = Wm[(size_t)(k0 + r) * 128 + n];
    unsigned short h = f2bf(w);
    hi[dst + r] = h;
    lo[dst + r] = f2bf(w - bf2f(h));
  }
}

// ---------------- mean aggregation over interleaved hi|lo rows --------------
// One wave per dst node. Lane L: neighbor half h=L>>5, 16 B chunk (L&31)*16
// of the 512 B row (lanes 0-15: hi dims, 16-31: lo dims, per neighbor).
// 8-edge main loop = 4 uint4 gathers (4 KB) in flight per wave.
__global__ void k_aggr(const unsigned short* __restrict__ X,
                       const int* __restrict__ csr, const int* __restrict__ rs,
                       const float* __restrict__ degf,
                       unsigned short* __restrict__ A, int n) {
  int gid = blockIdx.x * blockDim.x + threadIdx.x;
  int wid = gid >> 6, lane = gid & 63;
  if (wid >= n) return;
  int s = rs[wid], e = rs[wid + 1];
  const int h = lane >> 5;          // neighbor slot (0/1)
  const int o16 = (lane & 31) * 8;  // ushort offset within 512 B row
  float a0 = 0.f, a1 = 0.f, a2 = 0.f, a3 = 0.f;
  float a4 = 0.f, a5 = 0.f, a6 = 0.f, a7 = 0.f;
  int j = s;
  for (; j + 7 < e; j += 8) {
    int n0 = csr[j + h];
    int n1 = csr[j + 2 + h];
    int n2 = csr[j + 4 + h];
    int n3 = csr[j + 6 + h];
    uint4 v0 = *(const uint4*)(X + (size_t)n0 * 256 + o16);
    uint4 v1 = *(const uint4*)(X + (size_t)n1 * 256 + o16);
    uint4 v2 = *(const uint4*)(X + (size_t)n2 * 256 + o16);
    uint4 v3 = *(const uint4*)(X + (size_t)n3 * 256 + o16);
    a0 += (lo16f(v0.x) + lo16f(v1.x)) + (lo16f(v2.x) + lo16f(v3.x));
    a1 += (hi16f(v0.x) + hi16f(v1.x)) + (hi16f(v2.x) + hi16f(v3.x));
    a2 += (lo16f(v0.y) + lo16f(v1.y)) + (lo16f(v2.y) + lo16f(v3.y));
    a3 += (hi16f(v0.y) + hi16f(v1.y)) + (hi16f(v2.y) + hi16f(v3.y));
    a4 += (lo16f(v0.z) + lo16f(v1.z)) + (lo16f(v2.z) + lo16f(v3.z));
    a5 += (hi16f(v0.z) + hi16f(v1.z)) + (hi16f(v2.z) + hi16f(v3.z));
    a6 += (lo16f(v0.w) + lo16f(v1.w)) + (lo16f(v2.w) + lo16f(v3.w));
    a7 += (hi16f(v0.w) + hi16f(v1.w)) + (hi16f(v2.w) + hi16f(v3.w));
  }
  for (; j < e; j += 2) {
    int idx = j + h;
    bool ok = idx < e;
    int nn = ok ? csr[idx] : 0;
    uint4 v = *(const uint4*)(X + (size_t)nn * 256 + o16);
    float m = ok ? 1.f : 0.f;
    a0 += m * lo16f(v.x); a1 += m * hi16f(v.x);
    a2 += m * lo16f(v.y); a3 += m * hi16f(v.y);
    a4 += m * lo16f(v.z); a5 += m * hi16f(v.z);
    a6 += m * lo16f(v.w); a7 += m * hi16f(v.w);
  }
  // combine hi-lanes with lo-lanes (xor 16), then the two neighbor halves
  a0 += __shfl_xor(a0, 16); a1 += __shfl_xor(a1, 16);
  a2 += __shfl_xor(a2, 16); a3 += __shfl_xor(a3, 16);
  a4 += __shfl_xor(a4, 16); a5 += __shfl_xor(a5, 16);
  a6 += __shfl_xor(a6, 16); a7 += __shfl_xor(a7, 16);
  a0 += __shfl_xor(a0, 32); a1 += __shfl_xor(a1, 32);
  a2 += __shfl_xor(a2, 32); a3 += __shfl_xor(a3, 32);
  a4 += __shfl_xor(a4, 32); a5 += __shfl_xor(a5, 32);
  a6 += __shfl_xor(a6, 32); a7 += __shfl_xor(a7, 32);
  if (lane < 32) {
    float inv = 1.0f / degf[wid];
    int r = (lane >> 4) & 1;  // 0: write hi part, 1: write lo part
    float m0 = a0 * inv, m1 = a1 * inv, m2 = a2 * inv, m3 = a3 * inv;
    float m4 = a4 * inv, m5 = a5 * inv, m6 = a6 * inv, m7 = a7 * inv;
    unsigned short h0 = f2bf(m0), h1 = f2bf(m1), h2 = f2bf(m2), h3 = f2bf(m3);
    unsigned short h4 = f2bf(m4), h5 = f2bf(m5), h6 = f2bf(m6), h7 = f2bf(m7);
    unsigned short o0 = r ? f2bf(m0 - bf2f(h0)) : h0;
    unsigned short o1 = r ? f2bf(m1 - bf2f(h1)) : h1;
    unsigned short o2 = r ? f2bf(m2 - bf2f(h2)) : h2;
    unsigned short o3 = r ? f2bf(m3 - bf2f(h3)) : h3;
    unsigned short o4 = r ? f2bf(m4 - bf2f(h4)) : h4;
    unsigned short o5 = r ? f2bf(m5 - bf2f(h5)) : h5;
    unsigned short o6 = r ? f2bf(m6 - bf2f(h6)) : h6;
    unsigned short o7 = r ? f2bf(m7 - bf2f(h7)) : h7;
    uint4 o;
    o.x = (unsigned)o0 | ((unsigned)o1 << 16);
    o.y = (unsigned)o2 | ((unsigned)o3 << 16);
    o.z = (unsigned)o4 | ((unsigned)o5 << 16);
    o.w = (unsigned)o6 | ((unsigned)o7 << 16);
    *(uint4*)(A + (size_t)wid * 256 + lane * 8) = o;
  }
}

// ---------------- MFMA GEMM, LDS-staged weights ------------------------------
// A inputs interleaved (stride 256 ushorts; lo at +128). 512 threads = 8
// waves; each wave owns 32 rows (2 row-sets of 16). Per phase: stage hi+lo
// frag-packed weights (64 KiB) to LDS, then 4 ks x 8 nt { 2 ds_read_b128 ->
// 6 MFMA }. EPI: 0 = relu + interleaved out; 1 = interleaved out; 2 = dense
// bf16 out (stride 128).
template <int NPHASE, int EPI>
__global__ __launch_bounds__(512, 2) void k_gemm(
    const unsigned short* __restrict__ A0, const unsigned short* __restrict__ A1,
    const unsigned short* __restrict__ W0h, const unsigned short* __restrict__ W0l,
    const unsigned short* __restrict__ W1h, const unsigned short* __restrict__ W1l,
    const float* __restrict__ bias, unsigned short* __restrict__ O, int nrows) {
  __shared__ unsigned short smem[8 * 4096];  // hi: 16384, lo: 16384 ushorts
  unsigned short* smh = smem;
  unsigned short* sml = smem + 8 * 2048;

  const int tid = threadIdx.x;
  const int lane = tid & 63;
  const int wv = tid >> 6;
  const long row0 = ((long)blockIdx.x * 8 + wv) * 32;
  const bool active = row0 < nrows;
  const int kgrp = (lane >> 4) * 8;

  long arow[2];
#pragma unroll
  for (int rs = 0; rs < 2; ++rs) {
    long r = row0 + rs * 16 + (lane & 15);
    arow[rs] = (r < nrows) ? r : (long)(nrows - 1);
  }

  f32x4 zero = {0.f, 0.f, 0.f, 0.f};
  f32x4 acc[2][8];
#pragma unroll
  for (int rs = 0; rs < 2; ++rs)
#pragma unroll
    for (int t = 0; t < 8; ++t) acc[rs][t] = zero;

#pragma unroll
  for (int p = 0; p < NPHASE; ++p) {
    const unsigned short* A = p ? A1 : A0;
    const unsigned short* Wh = p ? W1h : W0h;
    const unsigned short* Wl_ = p ? W1l : W0l;
    if (p) __syncthreads();
    for (int t = tid; t < 8 * 256; t += 512) {
      ((uint4*)smh)[t] = ((const uint4*)Wh)[t];
      ((uint4*)sml)[t] = ((const uint4*)Wl_)[t];
    }
    __syncthreads();
    if (active) {
#pragma unroll
      for (int ks = 0; ks < 4; ++ks) {
        bf16x8 a_h[2], a_l[2];
#pragma unroll
        for (int rs = 0; rs < 2; ++rs) {
          a_h[rs] = *(const bf16x8*)(A + arow[rs] * 256 + ks * 32 + kgrp);
          a_l[rs] = *(const bf16x8*)(A + arow[rs] * 256 + 128 + ks * 32 + kgrp);
        }
#pragma unroll
        for (int nt = 0; nt < 8; ++nt) {
          const bf16x8 b_h = *(const bf16x8*)(smh + (nt * 4 + ks) * 512 + lane * 8);
          const bf16x8 b_l = *(const bf16x8*)(sml + (nt * 4 + ks) * 512 + lane * 8);
#pragma unroll
          for (int rs = 0; rs < 2; ++rs) {
            acc[rs][nt] = __builtin_amdgcn_mfma_f32_16x16x32_bf16(a_h[rs], b_h, acc[rs][nt], 0, 0, 0);
            acc[rs][nt] = __builtin_amdgcn_mfma_f32_16x16x32_bf16(a_l[rs], b_h, acc[rs][nt], 0, 0, 0);
            acc[rs][nt] = __builtin_amdgcn_mfma_f32_16x16x32_bf16(a_h[rs], b_l, acc[rs][nt], 0, 0, 0);
          }
        }
      }
    }
  }
  if (!active) return;

  const int c = lane & 15;
#pragma unroll
  for (int rs = 0; rs < 2; ++rs) {
    const long rbase = row0 + rs * 16 + (lane >> 4) * 4;
#pragma unroll
    for (int nt = 0; nt < 8; ++nt) {
      int col = nt * 16 + c;
      float bv = bias[col];
#pragma unroll
      for (int j = 0; j < 4; ++j) {
        long row = rbase + j;
        if (row >= nrows) continue;
        float val = acc[rs][nt][j] + bv;
        if (EPI == 0) val = fmaxf(val, 0.f);
        unsigned short h = f2bf(val);
        if (EPI == 2) {
          O[row * 128 + col] = h;
        } else {
          O[row * 256 + col] = h;
          O[row * 256 + 128 + col] = f2bf(val - bf2f(h));
        }
      }
    }
  }
}

// ---------------- predict pair: y = relu(u[i]+v[j]) . qW2 + qb2 -------------
__global__ __launch_bounds__(256) void k_pair(
    const unsigned short* __restrict__ u, const unsigned short* __restrict__ v,
    const int* __restrict__ ps, const int* __restrict__ pd,
    const float* __restrict__ qW2, const float* __restrict__ qb2,
    float* __restrict__ out, int EP) {
  int gid = blockIdx.x * blockDim.x + threadIdx.x;
  long wid = gid >> 6;
  int lane = gid & 63;
  int sub = lane & 15, g = lane >> 4;
  long base = wid * 8;
  if (base >= EP) return;
  float4 q0 = *(const float4*)(qW2 + sub * 8);
  float4 q1 = *(const float4*)(qW2 + sub * 8 + 4);
  float qb = qb2[0];

  long p0 = base + g;
  long p1 = base + 4 + g;
  long c0 = (p0 < EP) ? p0 : (EP - 1);
  long c1 = (p1 < EP) ? p1 : (EP - 1);
  int i0 = ps[c0], j0 = pd[c0];
  int i1 = ps[c1], j1 = pd[c1];
  uint4 a0 = *(const uint4*)(u + (size_t)i0 * 128 + sub * 8);
  uint4 b0 = *(const uint4*)(v + (size_t)j0 * 128 + sub * 8);
  uint4 a1 = *(const uint4*)(u + (size_t)i1 * 128 + sub * 8);
  uint4 b1 = *(const uint4*)(v + (size_t)j1 * 128 + sub * 8);

  float s0, s1;
  {
    float t;
    t = fmaxf(lo16f(a0.x) + lo16f(b0.x), 0.f) * q0.x;
    t = fmaf(fmaxf(hi16f(a0.x) + hi16f(b0.x), 0.f), q0.y, t);
    t = fmaf(fmaxf(lo16f(a0.y) + lo16f(b0.y), 0.f), q0.z, t);
    t = fmaf(fmaxf(hi16f(a0.y) + hi16f(b0.y), 0.f), q0.w, t);
    t = fmaf(fmaxf(lo16f(a0.z) + lo16f(b0.z), 0.f), q1.x, t);
    t = fmaf(fmaxf(hi16f(a0.z) + hi16f(b0.z), 0.f), q1.y, t);
    t = fmaf(fmaxf(lo16f(a0.w) + lo16f(b0.w), 0.f), q1.z, t);
    t = fmaf(fmaxf(hi16f(a0.w) + hi16f(b0.w), 0.f), q1.w, t);
    s0 = t;
    t = fmaxf(lo16f(a1.x) + lo16f(b1.x), 0.f) * q0.x;
    t = fmaf(fmaxf(hi16f(a1.x) + hi16f(b1.x), 0.f), q0.y, t);
    t = fmaf(fmaxf(lo16f(a1.y) + lo16f(b1.y), 0.f), q0.z, t);
    t = fmaf(fmaxf(hi16f(a1.y) + hi16f(b1.y), 0.f), q0.w, t);
    t = fmaf(fmaxf(lo16f(a1.z) + lo16f(b1.z), 0.f), q1.x, t);
    t = fmaf(fmaxf(hi16f(a1.z) + hi16f(b1.z), 0.f), q1.y, t);
    t = fmaf(fmaxf(lo16f(a1.w) + lo16f(b1.w), 0.f), q1.z, t);
    t = fmaf(fmaxf(hi16f(a1.w) + hi16f(b1.w), 0.f), q1.w, t);
    s1 = t;
  }
#pragma unroll
  for (int m = 1; m < 16; m <<= 1) {
    s0 += __shfl_xor(s0, m);
    s1 += __shfl_xor(s1, m);
  }
  if (sub == 0) {
    if (p0 < EP) out[p0] = s0 + qb;
    if (p1 < EP) out[p1] = s1 + qb;
  }
}

extern "C" void kernel_launch(void* const* d_in, const int* in_sizes, int n_in,
                              void* d_out, int out_size, void* d_ws, size_t ws_size,
                              hipStream_t stream) {
  const float* x_in = (const float*)d_in[0];
  // d_in[1] edge_attr: dead
  const int* ei = (const int*)d_in[2];
  const int* pe = (const int*)d_in[3];
  const float* Wl = (const float*)d_in[4];
  const float* bl = (const float*)d_in[5];
  const float* Wr = (const float*)d_in[6];
  // d_in[7..10] edge-update weights: dead
  const float* pW1 = (const float*)d_in[11];
  const float* pb1 = (const float*)d_in[12];
  const float* pW2 = (const float*)d_in[13];
  const float* pb2 = (const float*)d_in[14];
  const float* qW1 = (const float*)d_in[15];
  const float* qb1 = (const float*)d_in[16];
  const float* qW2 = (const float*)d_in[17];
  const float* qb2 = (const float*)d_in[18];

  const int N = in_sizes[0] / 128;
  const int E = in_sizes[2] / 2;
  const int EP = in_sizes[3] / 2;
  const int* e_src = ei;
  const int* e_dst = ei + E;
  const int* p_src = pe;
  const int* p_dst = pe + EP;

  char* ws = (char*)d_ws;
  size_t off = 0;
  auto alloc = [&](size_t bytes) {
    void* p = ws + off;
    off += (bytes + 511) & ~(size_t)511;
    return p;
  };
  // interleaved feature buffers: [node][hi 128 | lo 128] bf16 (512 B rows)
  unsigned short* X = (unsigned short*)alloc((size_t)N * 256 * 2);  // 25.6 MB
  unsigned short* A = (unsigned short*)alloc((size_t)N * 256 * 2);  // 25.6 MB
  int* deg_i = (int*)alloc((size_t)N * 4);
  int* rs = (int*)alloc((size_t)(N + 1) * 4);
  int* cursor = (int*)alloc((size_t)N * 4);
  float* degf = (float*)alloc((size_t)N * 4);
  int* csr = (int*)alloc((size_t)E * 4);
  int* bsum = (int*)alloc(64 * 4);
  int* boff = (int*)alloc(64 * 4);
  unsigned short* Whi = (unsigned short*)alloc((size_t)10 * 16384 * 2);
  unsigned short* Wlo = (unsigned short*)alloc((size_t)10 * 16384 * 2);
  float* biasuv = (float*)alloc(256 * 4);

  const size_t MS = 16384;  // mat stride in ushorts
  const int nb = (N + 1023) / 1024;

  hipMemsetAsync(deg_i, 0, (size_t)N * 4, stream);
  hipMemcpyAsync(biasuv, qb1, 128 * 4, hipMemcpyDeviceToDevice, stream);
  hipMemsetAsync(biasuv + 128, 0, 128 * 4, stream);

  // pack weights (frag order, hi/lo split); mats 8,9 = qW1 top/bottom
  k_packW<<<(3 * 2048 + 255) / 256, 256, 0, stream>>>(Wl, Whi + 0 * MS, Wlo + 0 * MS, 3);
  k_packW<<<(3 * 2048 + 255) / 256, 256, 0, stream>>>(Wr, Whi + 3 * MS, Wlo + 3 * MS, 3);
  k_packW<<<(2048 + 255) / 256, 256, 0, stream>>>(pW1, Whi + 6 * MS, Wlo + 6 * MS, 1);
  k_packW<<<(2048 + 255) / 256, 256, 0, stream>>>(pW2, Whi + 7 * MS, Wlo + 7 * MS, 1);
  k_packW<<<(2 * 2048 + 255) / 256, 256, 0, stream>>>(qW1, Whi + 8 * MS, Wlo + 8 * MS, 2);

  // x -> interleaved hi|lo
  long n2 = (long)N * 64;
  k_split<<<(int)((n2 + 255) / 256), 256, 0, stream>>>(x_in, (unsigned*)X, n2);

  // CSR (hierarchical scan)
  k_count<<<(E + 255) / 256, 256, 0, stream>>>(e_dst, deg_i, E);
  k_scan1<<<nb, 1024, 0, stream>>>(deg_i, rs, degf, bsum, N);
  k_scan2<<<1, 64, 0, stream>>>(bsum, boff, rs + N, nb);
  k_scan3<<<(N + 255) / 256, 256, 0, stream>>>(rs, boff, cursor, N);
  k_scatter<<<(E + 255) / 256, 256, 0, stream>>>(e_src, e_dst, cursor, csr, E);

  const int gmm = ((N + 31) / 32 + 7) / 8;  // 32 rows/wave, 8 waves/block
  const int agblocks = (N + 3) / 4;
  for (int l = 0; l < 3; ++l) {
    k_aggr<<<agblocks, 256, 0, stream>>>(X, csr, rs, degf, A, N);
    // x = relu(aggr@Wl + x@Wr + bl); in-place safe (rows wave-owned; all
    // phase reads precede that wave's epilogue stores)
    k_gemm<2, 0><<<gmm, 512, 0, stream>>>(
        A, X, Whi + (size_t)l * MS, Wlo + (size_t)l * MS,
        Whi + (size_t)(3 + l) * MS, Wlo + (size_t)(3 + l) * MS,
        bl + (size_t)l * 128, X, N);
  }
  // h1 = relu(x@pW1+pb1) -> A
  k_gemm<1, 0><<<gmm, 512, 0, stream>>>(
      X, nullptr, Whi + 6 * MS, Wlo + 6 * MS, nullptr, nullptr, pb1, A, N);
  // x2 = h1@pW2+pb2 -> X (in-place over x; A is the source)
  k_gemm<1, 1><<<gmm, 512, 0, stream>>>(
      A, nullptr, Whi + 7 * MS, Wlo + 7 * MS, nullptr, nullptr, pb2, X, N);
  // u = x2@qW1t + qb1 ; v = x2@qW1b   (dense bf16, carved out of A's space)
  unsigned short* u = A;
  unsigned short* v = A + (size_t)N * 128;
  k_gemm<1, 2><<<gmm, 512, 0, stream>>>(
      X, nullptr, Whi + 8 * MS, Wlo + 8 * MS, nullptr, nullptr, biasuv, u, N);
  k_gemm<1, 2><<<gmm, 512, 0, stream>>>(
      X, nullptr, Whi + 9 * MS, Wlo + 9 * MS, nullptr, nullptr, biasuv + 128, v, N);
  // y = relu(u[i]+v[j]) . qW2 + qb2
  k_pair<<<(EP + 31) / 32, 256, 0, stream>>>(u, v, p_src, p_dst, qW2, qb2,
                                             (float*)d_out, EP);
}

// Round 7
// 345.920 us; speedup vs baseline: 2.8165x; 1.1071x over previous
//
#include <hip/hip_runtime.h>

// ---------------------------------------------------------------------------
// GNNStack — dead-code-eliminated (edge-update MLPs never reach the output).
// All matmuls on MFMA bf16 with hi/lo split precision (fp32-equivalent):
//   C = Ahi*Bhi + Alo*Bhi + Ahi*Blo   (AloBlo ~ 1.6e-5 relative, dropped)
// Node features: X interleaved [node][hi 128 | lo 128] bf16 (512 B row) for
// GEMM A-operands; Xh dense bf16-hi copy (256 B row) is the AGGREGATION
// gather table — halves gather traffic (precision cost ~2e-3/layer, only on
// the aggr@Wl path). One uint4/lane = 4 neighbors per gather instruction.
// GEMM: 8-wave blocks, weights LDS-staged per phase (64 KiB), 32 rows/wave.
// ---------------------------------------------------------------------------

typedef __attribute__((ext_vector_type(8))) short bf16x8;
typedef __attribute__((ext_vector_type(4))) float f32x4;

__device__ __forceinline__ unsigned short f2bf(float x) {
  unsigned u = __float_as_uint(x);
  u += 0x7fffu + ((u >> 16) & 1u);
  return (unsigned short)(u >> 16);
}
__device__ __forceinline__ float bf2f(unsigned short h) {
  return __uint_as_float(((unsigned)h) << 16);
}
__device__ __forceinline__ float lo16f(unsigned u) { return __uint_as_float(u << 16); }
__device__ __forceinline__ float hi16f(unsigned u) { return __uint_as_float(u & 0xffff0000u); }

// ---------------- CSR build ----------------
__global__ void k_count(const int* __restrict__ dst, int* __restrict__ cnt, int E) {
  int i = blockIdx.x * blockDim.x + threadIdx.x;
  if (i < E) atomicAdd(&cnt[dst[i]], 1);
}

__global__ void k_scan1(const int* __restrict__ cnt, int* __restrict__ rs,
                        float* __restrict__ degf, int* __restrict__ bsum, int n) {
  __shared__ int wsum[16];
  __shared__ int wpre[16];
  const int tid = threadIdx.x;
  const int lane = tid & 63;
  const int wv = tid >> 6;
  int i = blockIdx.x * 1024 + tid;
  int v = (i < n) ? cnt[i] : 0;
  int s = v;
#pragma unroll
  for (int off = 1; off < 64; off <<= 1) {
    int t = __shfl_up(s, off);
    if (lane >= off) s += t;
  }
  if (lane == 63) wsum[wv] = s;
  __syncthreads();
  if (tid < 16) {
    int t = wsum[tid];
    int ss = t;
#pragma unroll
    for (int off = 1; off < 16; off <<= 1) {
      int u = __shfl_up(ss, off);
      if (tid >= off) ss += u;
    }
    wpre[tid] = ss - t;
  }
  __syncthreads();
  if (i < n) {
    rs[i] = s - v + wpre[wv];
    degf[i] = (float)(v > 0 ? v : 1);
  }
  if (tid == 1023) bsum[blockIdx.x] = wpre[15] + wsum[15];
}

__global__ void k_scan2(const int* __restrict__ bsum, int* __restrict__ boff,
                        int* __restrict__ rs_n, int nb) {
  int tid = threadIdx.x;
  int v = (tid < nb) ? bsum[tid] : 0;
  int s = v;
#pragma unroll
  for (int off = 1; off < 64; off <<= 1) {
    int t = __shfl_up(s, off);
    if (tid >= off) s += t;
  }
  if (tid < nb) boff[tid] = s - v;
  if (tid == 63) rs_n[0] = s;
}

__global__ void k_scan3(int* __restrict__ rs, const int* __restrict__ boff,
                        int* __restrict__ cursor, int n) {
  int i = blockIdx.x * blockDim.x + threadIdx.x;
  if (i < n) {
    int r = rs[i] + boff[i >> 10];
    rs[i] = r;
    cursor[i] = r;
  }
}

__global__ void k_scatter(const int* __restrict__ src, const int* __restrict__ dst,
                          int* __restrict__ cursor, int* __restrict__ csr, int E) {
  int i = blockIdx.x * blockDim.x + threadIdx.x;
  if (i < E) {
    int p = atomicAdd(&cursor[dst[i]], 1);
    csr[p] = src[i];
  }
}

// ---------------- fp32 -> interleaved hi|lo X row + dense hi Xh -------------
// X row (u32 view, 128 words): [0..63]=hi pairs, [64..127]=lo pairs
__global__ void k_split(const float* __restrict__ x, unsigned* __restrict__ X,
                        unsigned* __restrict__ Xh, long n2) {
  long g = (long)blockIdx.x * blockDim.x + threadIdx.x;
  if (g >= n2) return;
  float2 v = ((const float2*)x)[g];
  unsigned short hx = f2bf(v.x), hy = f2bf(v.y);
  unsigned short lx = f2bf(v.x - bf2f(hx)), ly = f2bf(v.y - bf2f(hy));
  long row = g >> 6, p = g & 63;
  unsigned hw = (unsigned)hx | ((unsigned)hy << 16);
  X[row * 128 + p] = hw;
  X[row * 128 + 64 + p] = (unsigned)lx | ((unsigned)ly << 16);
  Xh[row * 64 + p] = hw;
}

// ---------------- weight pack: fp32 [K=128][N=128] -> frag-order bf16 hi/lo --
// frag f = nt*4 + ks; lane l supplies B[k0 + 8*(l>>4) + r][nt*16 + (l&15)]
__global__ void k_packW(const float* __restrict__ W, unsigned short* __restrict__ hi,
                        unsigned short* __restrict__ lo, int nmat) {
  int gid = blockIdx.x * blockDim.x + threadIdx.x;
  if (gid >= nmat * 2048) return;
  int lane = gid & 63;
  int f = (gid >> 6) & 31;
  int mat = gid >> 11;
  int nt = f >> 2, ks = f & 3;
  int n = nt * 16 + (lane & 15);
  int k0 = ks * 32 + 8 * (lane >> 4);
  const float* Wm = W + (size_t)mat * 16384;
  size_t dst = (size_t)gid * 8;
#pragma unroll
  for (int r = 0; r < 8; ++r) {
    float w = Wm[(size_t)(k0 + r) * 128 + n];
    unsigned short h = f2bf(w);
    hi[dst + r] = h;
    lo[dst + r] = f2bf(w - bf2f(h));
  }
}

// ---------------- mean aggregation over dense bf16-hi rows ------------------
// One wave per dst node. Lane L: neighbor slot h=L>>4 (4 per load), 16 B
// chunk (L&15)*16 of the 256 B row. Main loop = 2 loads (8 edges, 2 KB in
// flight); masked 4-edge tail. Output: interleaved hi/lo row of B.
__global__ void k_aggr(const unsigned short* __restrict__ Xh,
                       const int* __restrict__ csr, const int* __restrict__ rs,
                       const float* __restrict__ degf,
                       unsigned short* __restrict__ B, int n) {
  int gid = blockIdx.x * blockDim.x + threadIdx.x;
  int wid = gid >> 6, lane = gid & 63;
  if (wid >= n) return;
  int s = rs[wid], e = rs[wid + 1];
  const int h = lane >> 4;         // neighbor slot (0..3)
  const int o16 = (lane & 15) * 8; // ushort offset within 256 B row
  float a0 = 0.f, a1 = 0.f, a2 = 0.f, a3 = 0.f;
  float a4 = 0.f, a5 = 0.f, a6 = 0.f, a7 = 0.f;
  int j = s;
  for (; j + 7 < e; j += 8) {
    int n0 = csr[j + h];
    int n1 = csr[j + 4 + h];
    uint4 v0 = *(const uint4*)(Xh + (size_t)n0 * 128 + o16);
    uint4 v1 = *(const uint4*)(Xh + (size_t)n1 * 128 + o16);
    a0 += lo16f(v0.x) + lo16f(v1.x);
    a1 += hi16f(v0.x) + hi16f(v1.x);
    a2 += lo16f(v0.y) + lo16f(v1.y);
    a3 += hi16f(v0.y) + hi16f(v1.y);
    a4 += lo16f(v0.z) + lo16f(v1.z);
    a5 += hi16f(v0.z) + hi16f(v1.z);
    a6 += lo16f(v0.w) + lo16f(v1.w);
    a7 += hi16f(v0.w) + hi16f(v1.w);
  }
  for (; j < e; j += 4) {
    int idx = j + h;
    bool ok = idx < e;
    int nn = ok ? csr[idx] : 0;
    uint4 v = *(const uint4*)(Xh + (size_t)nn * 128 + o16);
    float m = ok ? 1.f : 0.f;
    a0 += m * lo16f(v.x); a1 += m * hi16f(v.x);
    a2 += m * lo16f(v.y); a3 += m * hi16f(v.y);
    a4 += m * lo16f(v.z); a5 += m * hi16f(v.z);
    a6 += m * lo16f(v.w); a7 += m * hi16f(v.w);
  }
  // sum the 4 neighbor slots (xor 16 then 32)
  a0 += __shfl_xor(a0, 16); a1 += __shfl_xor(a1, 16);
  a2 += __shfl_xor(a2, 16); a3 += __shfl_xor(a3, 16);
  a4 += __shfl_xor(a4, 16); a5 += __shfl_xor(a5, 16);
  a6 += __shfl_xor(a6, 16); a7 += __shfl_xor(a7, 16);
  a0 += __shfl_xor(a0, 32); a1 += __shfl_xor(a1, 32);
  a2 += __shfl_xor(a2, 32); a3 += __shfl_xor(a3, 32);
  a4 += __shfl_xor(a4, 32); a5 += __shfl_xor(a5, 32);
  a6 += __shfl_xor(a6, 32); a7 += __shfl_xor(a7, 32);
  if (lane < 16) {
    float inv = 1.0f / degf[wid];
    float m0 = a0 * inv, m1 = a1 * inv, m2 = a2 * inv, m3 = a3 * inv;
    float m4 = a4 * inv, m5 = a5 * inv, m6 = a6 * inv, m7 = a7 * inv;
    unsigned short h0 = f2bf(m0), h1 = f2bf(m1), h2 = f2bf(m2), h3 = f2bf(m3);
    unsigned short h4 = f2bf(m4), h5 = f2bf(m5), h6 = f2bf(m6), h7 = f2bf(m7);
    uint4 oh, ol;
    oh.x = (unsigned)h0 | ((unsigned)h1 << 16);
    oh.y = (unsigned)h2 | ((unsigned)h3 << 16);
    oh.z = (unsigned)h4 | ((unsigned)h5 << 16);
    oh.w = (unsigned)h6 | ((unsigned)h7 << 16);
    ol.x = (unsigned)f2bf(m0 - bf2f(h0)) | ((unsigned)f2bf(m1 - bf2f(h1)) << 16);
    ol.y = (unsigned)f2bf(m2 - bf2f(h2)) | ((unsigned)f2bf(m3 - bf2f(h3)) << 16);
    ol.z = (unsigned)f2bf(m4 - bf2f(h4)) | ((unsigned)f2bf(m5 - bf2f(h5)) << 16);
    ol.w = (unsigned)f2bf(m6 - bf2f(h6)) | ((unsigned)f2bf(m7 - bf2f(h7)) << 16);
    *(uint4*)(B + (size_t)wid * 256 + o16) = oh;
    *(uint4*)(B + (size_t)wid * 256 + 128 + o16) = ol;
  }
}

// ---------------- MFMA GEMM, LDS-staged weights ------------------------------
// A inputs interleaved (stride 256 ushorts; lo at +128). 512 threads = 8
// waves; each wave owns 32 rows (2 row-sets of 16). Per phase: stage hi+lo
// frag-packed weights (64 KiB) to LDS, then 4 ks x 8 nt { 2 ds_read_b128 ->
// 6 MFMA }. EPI: 0 = relu + interleaved out (+ dense hi to OD if non-null);
// 1 = interleaved out (+OD); 2 = dense bf16 out (stride 128).
template <int NPHASE, int EPI>
__global__ __launch_bounds__(512, 2) void k_gemm(
    const unsigned short* __restrict__ A0, const unsigned short* __restrict__ A1,
    const unsigned short* __restrict__ W0h, const unsigned short* __restrict__ W0l,
    const unsigned short* __restrict__ W1h, const unsigned short* __restrict__ W1l,
    const float* __restrict__ bias, unsigned short* __restrict__ O,
    unsigned short* __restrict__ OD, int nrows) {
  __shared__ unsigned short smem[8 * 4096];  // hi: 16384, lo: 16384 ushorts
  unsigned short* smh = smem;
  unsigned short* sml = smem + 8 * 2048;

  const int tid = threadIdx.x;
  const int lane = tid & 63;
  const int wv = tid >> 6;
  const long row0 = ((long)blockIdx.x * 8 + wv) * 32;
  const bool active = row0 < nrows;
  const int kgrp = (lane >> 4) * 8;

  long arow[2];
#pragma unroll
  for (int rs = 0; rs < 2; ++rs) {
    long r = row0 + rs * 16 + (lane & 15);
    arow[rs] = (r < nrows) ? r : (long)(nrows - 1);
  }

  f32x4 zero = {0.f, 0.f, 0.f, 0.f};
  f32x4 acc[2][8];
#pragma unroll
  for (int rs = 0; rs < 2; ++rs)
#pragma unroll
    for (int t = 0; t < 8; ++t) acc[rs][t] = zero;

#pragma unroll
  for (int p = 0; p < NPHASE; ++p) {
    const unsigned short* A = p ? A1 : A0;
    const unsigned short* Wh = p ? W1h : W0h;
    const unsigned short* Wl_ = p ? W1l : W0l;
    if (p) __syncthreads();
    for (int t = tid; t < 8 * 256; t += 512) {
      ((uint4*)smh)[t] = ((const uint4*)Wh)[t];
      ((uint4*)sml)[t] = ((const uint4*)Wl_)[t];
    }
    __syncthreads();
    if (active) {
#pragma unroll
      for (int ks = 0; ks < 4; ++ks) {
        bf16x8 a_h[2], a_l[2];
#pragma unroll
        for (int rs = 0; rs < 2; ++rs) {
          a_h[rs] = *(const bf16x8*)(A + arow[rs] * 256 + ks * 32 + kgrp);
          a_l[rs] = *(const bf16x8*)(A + arow[rs] * 256 + 128 + ks * 32 + kgrp);
        }
#pragma unroll
        for (int nt = 0; nt < 8; ++nt) {
          const bf16x8 b_h = *(const bf16x8*)(smh + (nt * 4 + ks) * 512 + lane * 8);
          const bf16x8 b_l = *(const bf16x8*)(sml + (nt * 4 + ks) * 512 + lane * 8);
#pragma unroll
          for (int rs = 0; rs < 2; ++rs) {
            acc[rs][nt] = __builtin_amdgcn_mfma_f32_16x16x32_bf16(a_h[rs], b_h, acc[rs][nt], 0, 0, 0);
            acc[rs][nt] = __builtin_amdgcn_mfma_f32_16x16x32_bf16(a_l[rs], b_h, acc[rs][nt], 0, 0, 0);
            acc[rs][nt] = __builtin_amdgcn_mfma_f32_16x16x32_bf16(a_h[rs], b_l, acc[rs][nt], 0, 0, 0);
          }
        }
      }
    }
  }
  if (!active) return;

  const int c = lane & 15;
#pragma unroll
  for (int rs = 0; rs < 2; ++rs) {
    const long rbase = row0 + rs * 16 + (lane >> 4) * 4;
#pragma unroll
    for (int nt = 0; nt < 8; ++nt) {
      int col = nt * 16 + c;
      float bv = bias[col];
#pragma unroll
      for (int j = 0; j < 4; ++j) {
        long row = rbase + j;
        if (row >= nrows) continue;
        float val = acc[rs][nt][j] + bv;
        if (EPI == 0) val = fmaxf(val, 0.f);
        unsigned short h = f2bf(val);
        if (EPI == 2) {
          O[row * 128 + col] = h;
        } else {
          O[row * 256 + col] = h;
          O[row * 256 + 128 + col] = f2bf(val - bf2f(h));
          if (OD) OD[row * 128 + col] = h;
        }
      }
    }
  }
}

// ---------------- predict pair: y = relu(u[i]+v[j]) . qW2 + qb2 -------------
__global__ __launch_bounds__(256) void k_pair(
    const unsigned short* __restrict__ u, const unsigned short* __restrict__ v,
    const int* __restrict__ ps, const int* __restrict__ pd,
    const float* __restrict__ qW2, const float* __restrict__ qb2,
    float* __restrict__ out, int EP) {
  int gid = blockIdx.x * blockDim.x + threadIdx.x;
  long wid = gid >> 6;
  int lane = gid & 63;
  int sub = lane & 15, g = lane >> 4;
  long base = wid * 8;
  if (base >= EP) return;
  float4 q0 = *(const float4*)(qW2 + sub * 8);
  float4 q1 = *(const float4*)(qW2 + sub * 8 + 4);
  float qb = qb2[0];

  long p0 = base + g;
  long p1 = base + 4 + g;
  long c0 = (p0 < EP) ? p0 : (EP - 1);
  long c1 = (p1 < EP) ? p1 : (EP - 1);
  int i0 = ps[c0], j0 = pd[c0];
  int i1 = ps[c1], j1 = pd[c1];
  uint4 a0 = *(const uint4*)(u + (size_t)i0 * 128 + sub * 8);
  uint4 b0 = *(const uint4*)(v + (size_t)j0 * 128 + sub * 8);
  uint4 a1 = *(const uint4*)(u + (size_t)i1 * 128 + sub * 8);
  uint4 b1 = *(const uint4*)(v + (size_t)j1 * 128 + sub * 8);

  float s0, s1;
  {
    float t;
    t = fmaxf(lo16f(a0.x) + lo16f(b0.x), 0.f) * q0.x;
    t = fmaf(fmaxf(hi16f(a0.x) + hi16f(b0.x), 0.f), q0.y, t);
    t = fmaf(fmaxf(lo16f(a0.y) + lo16f(b0.y), 0.f), q0.z, t);
    t = fmaf(fmaxf(hi16f(a0.y) + hi16f(b0.y), 0.f), q0.w, t);
    t = fmaf(fmaxf(lo16f(a0.z) + lo16f(b0.z), 0.f), q1.x, t);
    t = fmaf(fmaxf(hi16f(a0.z) + hi16f(b0.z), 0.f), q1.y, t);
    t = fmaf(fmaxf(lo16f(a0.w) + lo16f(b0.w), 0.f), q1.z, t);
    t = fmaf(fmaxf(hi16f(a0.w) + hi16f(b0.w), 0.f), q1.w, t);
    s0 = t;
    t = fmaxf(lo16f(a1.x) + lo16f(b1.x), 0.f) * q0.x;
    t = fmaf(fmaxf(hi16f(a1.x) + hi16f(b1.x), 0.f), q0.y, t);
    t = fmaf(fmaxf(lo16f(a1.y) + lo16f(b1.y), 0.f), q0.z, t);
    t = fmaf(fmaxf(hi16f(a1.y) + hi16f(b1.y), 0.f), q0.w, t);
    t = fmaf(fmaxf(lo16f(a1.z) + lo16f(b1.z), 0.f), q1.x, t);
    t = fmaf(fmaxf(hi16f(a1.z) + hi16f(b1.z), 0.f), q1.y, t);
    t = fmaf(fmaxf(lo16f(a1.w) + lo16f(b1.w), 0.f), q1.z, t);
    t = fmaf(fmaxf(hi16f(a1.w) + hi16f(b1.w), 0.f), q1.w, t);
    s1 = t;
  }
#pragma unroll
  for (int m = 1; m < 16; m <<= 1) {
    s0 += __shfl_xor(s0, m);
    s1 += __shfl_xor(s1, m);
  }
  if (sub == 0) {
    if (p0 < EP) out[p0] = s0 + qb;
    if (p1 < EP) out[p1] = s1 + qb;
  }
}

extern "C" void kernel_launch(void* const* d_in, const int* in_sizes, int n_in,
                              void* d_out, int out_size, void* d_ws, size_t ws_size,
                              hipStream_t stream) {
  const float* x_in = (const float*)d_in[0];
  // d_in[1] edge_attr: dead
  const int* ei = (const int*)d_in[2];
  const int* pe = (const int*)d_in[3];
  const float* Wl = (const float*)d_in[4];
  const float* bl = (const float*)d_in[5];
  const float* Wr = (const float*)d_in[6];
  // d_in[7..10] edge-update weights: dead
  const float* pW1 = (const float*)d_in[11];
  const float* pb1 = (const float*)d_in[12];
  const float* pW2 = (const float*)d_in[13];
  const float* pb2 = (const float*)d_in[14];
  const float* qW1 = (const float*)d_in[15];
  const float* qb1 = (const float*)d_in[16];
  const float* qW2 = (const float*)d_in[17];
  const float* qb2 = (const float*)d_in[18];

  const int N = in_sizes[0] / 128;
  const int E = in_sizes[2] / 2;
  const int EP = in_sizes[3] / 2;
  const int* e_src = ei;
  const int* e_dst = ei + E;
  const int* p_src = pe;
  const int* p_dst = pe + EP;

  char* ws = (char*)d_ws;
  size_t off = 0;
  auto alloc = [&](size_t bytes) {
    void* p = ws + off;
    off += (bytes + 511) & ~(size_t)511;
    return p;
  };
  // X: interleaved [node][hi 128 | lo 128] bf16; Xh: dense bf16 hi gather table
  unsigned short* X = (unsigned short*)alloc((size_t)N * 256 * 2);   // 25.6 MB
  unsigned short* B = (unsigned short*)alloc((size_t)N * 256 * 2);   // 25.6 MB
  unsigned short* Xh = (unsigned short*)alloc((size_t)N * 128 * 2);  // 12.8 MB
  int* deg_i = (int*)alloc((size_t)N * 4);
  int* rs = (int*)alloc((size_t)(N + 1) * 4);
  int* cursor = (int*)alloc((size_t)N * 4);
  float* degf = (float*)alloc((size_t)N * 4);
  int* csr = (int*)alloc((size_t)E * 4);
  int* bsum = (int*)alloc(64 * 4);
  int* boff = (int*)alloc(64 * 4);
  unsigned short* Whi = (unsigned short*)alloc((size_t)10 * 16384 * 2);
  unsigned short* Wlo = (unsigned short*)alloc((size_t)10 * 16384 * 2);
  float* biasuv = (float*)alloc(256 * 4);

  const size_t MS = 16384;  // mat stride in ushorts
  const int nb = (N + 1023) / 1024;

  hipMemsetAsync(deg_i, 0, (size_t)N * 4, stream);
  hipMemcpyAsync(biasuv, qb1, 128 * 4, hipMemcpyDeviceToDevice, stream);
  hipMemsetAsync(biasuv + 128, 0, 128 * 4, stream);

  // pack weights (frag order, hi/lo split); mats 8,9 = qW1 top/bottom
  k_packW<<<(3 * 2048 + 255) / 256, 256, 0, stream>>>(Wl, Whi + 0 * MS, Wlo + 0 * MS, 3);
  k_packW<<<(3 * 2048 + 255) / 256, 256, 0, stream>>>(Wr, Whi + 3 * MS, Wlo + 3 * MS, 3);
  k_packW<<<(2048 + 255) / 256, 256, 0, stream>>>(pW1, Whi + 6 * MS, Wlo + 6 * MS, 1);
  k_packW<<<(2048 + 255) / 256, 256, 0, stream>>>(pW2, Whi + 7 * MS, Wlo + 7 * MS, 1);
  k_packW<<<(2 * 2048 + 255) / 256, 256, 0, stream>>>(qW1, Whi + 8 * MS, Wlo + 8 * MS, 2);

  // x -> interleaved hi|lo + dense hi
  long n2 = (long)N * 64;
  k_split<<<(int)((n2 + 255) / 256), 256, 0, stream>>>(x_in, (unsigned*)X,
                                                       (unsigned*)Xh, n2);

  // CSR (hierarchical scan)
  k_count<<<(E + 255) / 256, 256, 0, stream>>>(e_dst, deg_i, E);
  k_scan1<<<nb, 1024, 0, stream>>>(deg_i, rs, degf, bsum, N);
  k_scan2<<<1, 64, 0, stream>>>(bsum, boff, rs + N, nb);
  k_scan3<<<(N + 255) / 256, 256, 0, stream>>>(rs, boff, cursor, N);
  k_scatter<<<(E + 255) / 256, 256, 0, stream>>>(e_src, e_dst, cursor, csr, E);

  const int gmm = ((N + 31) / 32 + 7) / 8;  // 32 rows/wave, 8 waves/block
  const int agblocks = (N + 3) / 4;
  for (int l = 0; l < 3; ++l) {
    k_aggr<<<agblocks, 256, 0, stream>>>(Xh, csr, rs, degf, B, N);
    // x = relu(aggr@Wl + x@Wr + bl) -> X interleaved + Xh dense
    // (in-place safe: rows wave-owned; phase reads precede epilogue stores)
    k_gemm<2, 0><<<gmm, 512, 0, stream>>>(
        B, X, Whi + (size_t)l * MS, Wlo + (size_t)l * MS,
        Whi + (size_t)(3 + l) * MS, Wlo + (size_t)(3 + l) * MS,
        bl + (size_t)l * 128, X, Xh, N);
  }
  // h1 = relu(x@pW1+pb1) -> B
  k_gemm<1, 0><<<gmm, 512, 0, stream>>>(
      X, nullptr, Whi + 6 * MS, Wlo + 6 * MS, nullptr, nullptr, pb1, B, nullptr, N);
  // x2 = h1@pW2+pb2 -> X (in-place over x; B is the source)
  k_gemm<1, 1><<<gmm, 512, 0, stream>>>(
      B, nullptr, Whi + 7 * MS, Wlo + 7 * MS, nullptr, nullptr, pb2, X, nullptr, N);
  // u = x2@qW1t + qb1 ; v = x2@qW1b   (dense bf16, carved out of B's space)
  unsigned short* u = B;
  unsigned short* v = B + (size_t)N * 128;
  k_gemm<1, 2><<<gmm, 512, 0, stream>>>(
      X, nullptr, Whi + 8 * MS, Wlo + 8 * MS, nullptr, nullptr, biasuv, u, nullptr, N);
  k_gemm<1, 2><<<gmm, 512, 0, stream>>>(
      X, nullptr, Whi + 9 * MS, Wlo + 9 * MS, nullptr, nullptr, biasuv + 128, v,
      nullptr, N);
  // y = relu(u[i]+v[j]) . qW2 + qb2
  k_pair<<<(EP + 31) / 32, 256, 0, stream>>>(u, v, p_src, p_dst, qW2, qb2,
                                             (float*)d_out, EP);
}

// Round 8
// 331.412 us; speedup vs baseline: 2.9398x; 1.0438x over previous
//
#include <hip/hip_runtime.h>

// ---------------------------------------------------------------------------
// GNNStack — dead-code-eliminated (edge-update MLPs never reach the output).
// All matmuls on MFMA bf16 with hi/lo split precision (fp32-equivalent):
//   C = Ahi*Bhi + Alo*Bhi + Ahi*Blo   (AloBlo ~ 1.6e-5 relative, dropped)
// Node features: X interleaved [node][hi 128 | lo 128] bf16 (512 B row).
// Aggregation gathers the CONTIGUOUS hi half (256 B) of X directly — no
// separate dense copy needed. GEMM uses swapped MFMA operands
// (D[colquad][xrow]) so the epilogue writes packed uint2 (8 B) per nt-tile:
// coalesced, no partial-line write inflation. Weights LDS-staged per phase.
// ---------------------------------------------------------------------------

typedef __attribute__((ext_vector_type(8))) short bf16x8;
typedef __attribute__((ext_vector_type(4))) float f32x4;

__device__ __forceinline__ unsigned short f2bf(float x) {
  unsigned u = __float_as_uint(x);
  u += 0x7fffu + ((u >> 16) & 1u);
  return (unsigned short)(u >> 16);
}
__device__ __forceinline__ float bf2f(unsigned short h) {
  return __uint_as_float(((unsigned)h) << 16);
}
__device__ __forceinline__ float lo16f(unsigned u) { return __uint_as_float(u << 16); }
__device__ __forceinline__ float hi16f(unsigned u) { return __uint_as_float(u & 0xffff0000u); }

// ---------------- CSR build ----------------
__global__ void k_count(const int* __restrict__ dst, int* __restrict__ cnt, int E) {
  int i = blockIdx.x * blockDim.x + threadIdx.x;
  if (i < E) atomicAdd(&cnt[dst[i]], 1);
}

__global__ void k_scan1(const int* __restrict__ cnt, int* __restrict__ rs,
                        float* __restrict__ degf, int* __restrict__ bsum, int n) {
  __shared__ int wsum[16];
  __shared__ int wpre[16];
  const int tid = threadIdx.x;
  const int lane = tid & 63;
  const int wv = tid >> 6;
  int i = blockIdx.x * 1024 + tid;
  int v = (i < n) ? cnt[i] : 0;
  int s = v;
#pragma unroll
  for (int off = 1; off < 64; off <<= 1) {
    int t = __shfl_up(s, off);
    if (lane >= off) s += t;
  }
  if (lane == 63) wsum[wv] = s;
  __syncthreads();
  if (tid < 16) {
    int t = wsum[tid];
    int ss = t;
#pragma unroll
    for (int off = 1; off < 16; off <<= 1) {
      int u = __shfl_up(ss, off);
      if (tid >= off) ss += u;
    }
    wpre[tid] = ss - t;
  }
  __syncthreads();
  if (i < n) {
    rs[i] = s - v + wpre[wv];
    degf[i] = (float)(v > 0 ? v : 1);
  }
  if (tid == 1023) bsum[blockIdx.x] = wpre[15] + wsum[15];
}

__global__ void k_scan2(const int* __restrict__ bsum, int* __restrict__ boff,
                        int* __restrict__ rs_n, int nb) {
  int tid = threadIdx.x;
  int v = (tid < nb) ? bsum[tid] : 0;
  int s = v;
#pragma unroll
  for (int off = 1; off < 64; off <<= 1) {
    int t = __shfl_up(s, off);
    if (tid >= off) s += t;
  }
  if (tid < nb) boff[tid] = s - v;
  if (tid == 63) rs_n[0] = s;
}

__global__ void k_scan3(int* __restrict__ rs, const int* __restrict__ boff,
                        int* __restrict__ cursor, int n) {
  int i = blockIdx.x * blockDim.x + threadIdx.x;
  if (i < n) {
    int r = rs[i] + boff[i >> 10];
    rs[i] = r;
    cursor[i] = r;
  }
}

__global__ void k_scatter(const int* __restrict__ src, const int* __restrict__ dst,
                          int* __restrict__ cursor, int* __restrict__ csr, int E) {
  int i = blockIdx.x * blockDim.x + threadIdx.x;
  if (i < E) {
    int p = atomicAdd(&cursor[dst[i]], 1);
    csr[p] = src[i];
  }
}

// ---------------- fp32 -> interleaved hi|lo X row ----------------
// X row (u32 view, 128 words): [0..63]=hi pairs, [64..127]=lo pairs
__global__ void k_split(const float* __restrict__ x, unsigned* __restrict__ X,
                        long n2) {
  long g = (long)blockIdx.x * blockDim.x + threadIdx.x;
  if (g >= n2) return;
  float2 v = ((const float2*)x)[g];
  unsigned short hx = f2bf(v.x), hy = f2bf(v.y);
  unsigned short lx = f2bf(v.x - bf2f(hx)), ly = f2bf(v.y - bf2f(hy));
  long row = g >> 6, p = g & 63;
  X[row * 128 + p] = (unsigned)hx | ((unsigned)hy << 16);
  X[row * 128 + 64 + p] = (unsigned)lx | ((unsigned)ly << 16);
}

// ---------------- weight pack: fp32 [K=128][N=128] -> frag-order bf16 hi/lo --
// frag f = nt*4 + ks; lane l supplies B[k0 + 8*(l>>4) + r][nt*16 + (l&15)]
__global__ void k_packW(const float* __restrict__ W, unsigned short* __restrict__ hi,
                        unsigned short* __restrict__ lo, int nmat) {
  int gid = blockIdx.x * blockDim.x + threadIdx.x;
  if (gid >= nmat * 2048) return;
  int lane = gid & 63;
  int f = (gid >> 6) & 31;
  int mat = gid >> 11;
  int nt = f >> 2, ks = f & 3;
  int n = nt * 16 + (lane & 15);
  int k0 = ks * 32 + 8 * (lane >> 4);
  const float* Wm = W + (size_t)mat * 16384;
  size_t dst = (size_t)gid * 8;
#pragma unroll
  for (int r = 0; r < 8; ++r) {
    float w = Wm[(size_t)(k0 + r) * 128 + n];
    unsigned short h = f2bf(w);
    hi[dst + r] = h;
    lo[dst + r] = f2bf(w - bf2f(h));
  }
}

// ---------------- mean aggregation over X hi-halves -------------------------
// One wave per dst node. Lane L: neighbor slot h=L>>4 (4 per load), 16 B
// chunk (L&15)*16 of the 256 B hi half (row stride 512 B). Main loop = 2
// loads (8 edges, 2 KB in flight); masked 4-edge tail. Output: interleaved
// hi/lo row of B.
__global__ void k_aggr(const unsigned short* __restrict__ X,
                       const int* __restrict__ csr, const int* __restrict__ rs,
                       const float* __restrict__ degf,
                       unsigned short* __restrict__ B, int n) {
  int gid = blockIdx.x * blockDim.x + threadIdx.x;
  int wid = gid >> 6, lane = gid & 63;
  if (wid >= n) return;
  int s = rs[wid], e = rs[wid + 1];
  const int h = lane >> 4;         // neighbor slot (0..3)
  const int o16 = (lane & 15) * 8; // ushort offset within 256 B hi half
  float a0 = 0.f, a1 = 0.f, a2 = 0.f, a3 = 0.f;
  float a4 = 0.f, a5 = 0.f, a6 = 0.f, a7 = 0.f;
  int j = s;
  for (; j + 7 < e; j += 8) {
    int n0 = csr[j + h];
    int n1 = csr[j + 4 + h];
    uint4 v0 = *(const uint4*)(X + (size_t)n0 * 256 + o16);
    uint4 v1 = *(const uint4*)(X + (size_t)n1 * 256 + o16);
    a0 += lo16f(v0.x) + lo16f(v1.x);
    a1 += hi16f(v0.x) + hi16f(v1.x);
    a2 += lo16f(v0.y) + lo16f(v1.y);
    a3 += hi16f(v0.y) + hi16f(v1.y);
    a4 += lo16f(v0.z) + lo16f(v1.z);
    a5 += hi16f(v0.z) + hi16f(v1.z);
    a6 += lo16f(v0.w) + lo16f(v1.w);
    a7 += hi16f(v0.w) + hi16f(v1.w);
  }
  for (; j < e; j += 4) {
    int idx = j + h;
    bool ok = idx < e;
    int nn = ok ? csr[idx] : 0;
    uint4 v = *(const uint4*)(X + (size_t)nn * 256 + o16);
    float m = ok ? 1.f : 0.f;
    a0 += m * lo16f(v.x); a1 += m * hi16f(v.x);
    a2 += m * lo16f(v.y); a3 += m * hi16f(v.y);
    a4 += m * lo16f(v.z); a5 += m * hi16f(v.z);
    a6 += m * lo16f(v.w); a7 += m * hi16f(v.w);
  }
  // sum the 4 neighbor slots (xor 16 then 32)
  a0 += __shfl_xor(a0, 16); a1 += __shfl_xor(a1, 16);
  a2 += __shfl_xor(a2, 16); a3 += __shfl_xor(a3, 16);
  a4 += __shfl_xor(a4, 16); a5 += __shfl_xor(a5, 16);
  a6 += __shfl_xor(a6, 16); a7 += __shfl_xor(a7, 16);
  a0 += __shfl_xor(a0, 32); a1 += __shfl_xor(a1, 32);
  a2 += __shfl_xor(a2, 32); a3 += __shfl_xor(a3, 32);
  a4 += __shfl_xor(a4, 32); a5 += __shfl_xor(a5, 32);
  a6 += __shfl_xor(a6, 32); a7 += __shfl_xor(a7, 32);
  if (lane < 16) {
    float inv = 1.0f / degf[wid];
    float m0 = a0 * inv, m1 = a1 * inv, m2 = a2 * inv, m3 = a3 * inv;
    float m4 = a4 * inv, m5 = a5 * inv, m6 = a6 * inv, m7 = a7 * inv;
    unsigned short h0 = f2bf(m0), h1 = f2bf(m1), h2 = f2bf(m2), h3 = f2bf(m3);
    unsigned short h4 = f2bf(m4), h5 = f2bf(m5), h6 = f2bf(m6), h7 = f2bf(m7);
    uint4 oh, ol;
    oh.x = (unsigned)h0 | ((unsigned)h1 << 16);
    oh.y = (unsigned)h2 | ((unsigned)h3 << 16);
    oh.z = (unsigned)h4 | ((unsigned)h5 << 16);
    oh.w = (unsigned)h6 | ((unsigned)h7 << 16);
    ol.x = (unsigned)f2bf(m0 - bf2f(h0)) | ((unsigned)f2bf(m1 - bf2f(h1)) << 16);
    ol.y = (unsigned)f2bf(m2 - bf2f(h2)) | ((unsigned)f2bf(m3 - bf2f(h3)) << 16);
    ol.z = (unsigned)f2bf(m4 - bf2f(h4)) | ((unsigned)f2bf(m5 - bf2f(h5)) << 16);
    ol.w = (unsigned)f2bf(m6 - bf2f(h6)) | ((unsigned)f2bf(m7 - bf2f(h7)) << 16);
    *(uint4*)(B + (size_t)wid * 256 + o16) = oh;
    *(uint4*)(B + (size_t)wid * 256 + 128 + o16) = ol;
  }
}

// ---------------- MFMA GEMM, LDS-staged weights, swapped operands -----------
// mfma(w_frag, x_frag): D[m][n] with m = output col (quad per lane),
// n = x row (lane&15). Epilogue: each lane owns 4 consecutive output cols
// per nt tile -> packed uint2 stores (8 B), no partial-line inflation.
// A inputs interleaved (stride 256 ushorts; lo at +128). 512 threads = 8
// waves; each wave owns 32 rows (2 row-sets of 16). Per phase: stage hi+lo
// frag-packed weights (64 KiB) to LDS, then 4 ks x 8 nt { 2 ds_read_b128 ->
// 6 MFMA }. EPI: 0 = relu + interleaved out; 1 = interleaved out; 2 = dense
// bf16 out (stride 128).
template <int NPHASE, int EPI>
__global__ __launch_bounds__(512, 2) void k_gemm(
    const unsigned short* __restrict__ A0, const unsigned short* __restrict__ A1,
    const unsigned short* __restrict__ W0h, const unsigned short* __restrict__ W0l,
    const unsigned short* __restrict__ W1h, const unsigned short* __restrict__ W1l,
    const float* __restrict__ bias, unsigned short* __restrict__ O, int nrows) {
  __shared__ unsigned short smem[8 * 4096];  // hi: 16384, lo: 16384 ushorts
  unsigned short* smh = smem;
  unsigned short* sml = smem + 8 * 2048;

  const int tid = threadIdx.x;
  const int lane = tid & 63;
  const int wv = tid >> 6;
  const long row0 = ((long)blockIdx.x * 8 + wv) * 32;
  const bool active = row0 < nrows;
  const int kgrp = (lane >> 4) * 8;

  long arow[2];
#pragma unroll
  for (int rs = 0; rs < 2; ++rs) {
    long r = row0 + rs * 16 + (lane & 15);
    arow[rs] = (r < nrows) ? r : (long)(nrows - 1);
  }

  f32x4 zero = {0.f, 0.f, 0.f, 0.f};
  f32x4 acc[2][8];
#pragma unroll
  for (int rs = 0; rs < 2; ++rs)
#pragma unroll
    for (int t = 0; t < 8; ++t) acc[rs][t] = zero;

#pragma unroll
  for (int p = 0; p < NPHASE; ++p) {
    const unsigned short* A = p ? A1 : A0;
    const unsigned short* Wh = p ? W1h : W0h;
    const unsigned short* Wl_ = p ? W1l : W0l;
    if (p) __syncthreads();
    for (int t = tid; t < 8 * 256; t += 512) {
      ((uint4*)smh)[t] = ((const uint4*)Wh)[t];
      ((uint4*)sml)[t] = ((const uint4*)Wl_)[t];
    }
    __syncthreads();
    if (active) {
#pragma unroll
      for (int ks = 0; ks < 4; ++ks) {
        bf16x8 a_h[2], a_l[2];
#pragma unroll
        for (int rs = 0; rs < 2; ++rs) {
          a_h[rs] = *(const bf16x8*)(A + arow[rs] * 256 + ks * 32 + kgrp);
          a_l[rs] = *(const bf16x8*)(A + arow[rs] * 256 + 128 + ks * 32 + kgrp);
        }
#pragma unroll
        for (int nt = 0; nt < 8; ++nt) {
          const bf16x8 b_h = *(const bf16x8*)(smh + (nt * 4 + ks) * 512 + lane * 8);
          const bf16x8 b_l = *(const bf16x8*)(sml + (nt * 4 + ks) * 512 + lane * 8);
#pragma unroll
          for (int rs = 0; rs < 2; ++rs) {
            // swapped: W-frag as A-operand, x-frag as B-operand
            acc[rs][nt] = __builtin_amdgcn_mfma_f32_16x16x32_bf16(b_h, a_h[rs], acc[rs][nt], 0, 0, 0);
            acc[rs][nt] = __builtin_amdgcn_mfma_f32_16x16x32_bf16(b_h, a_l[rs], acc[rs][nt], 0, 0, 0);
            acc[rs][nt] = __builtin_amdgcn_mfma_f32_16x16x32_bf16(b_l, a_h[rs], acc[rs][nt], 0, 0, 0);
          }
        }
      }
    }
  }
  if (!active) return;

  // D layout: n (x row) = lane&15, m (output col within nt tile) =
  // (lane>>4)*4 + reg. Lane writes 4 consecutive cols as one uint2 per nt.
  const int cq = (lane >> 4) * 4;  // col quad base within 16-col tile
#pragma unroll
  for (int rs = 0; rs < 2; ++rs) {
    const long row = row0 + rs * 16 + (lane & 15);
    if (row >= nrows) continue;
#pragma unroll
    for (int nt = 0; nt < 8; ++nt) {
      const int col = nt * 16 + cq;
      float4 bv = *(const float4*)(bias + col);
      float v0 = acc[rs][nt][0] + bv.x;
      float v1 = acc[rs][nt][1] + bv.y;
      float v2 = acc[rs][nt][2] + bv.z;
      float v3 = acc[rs][nt][3] + bv.w;
      if (EPI == 0) {
        v0 = fmaxf(v0, 0.f); v1 = fmaxf(v1, 0.f);
        v2 = fmaxf(v2, 0.f); v3 = fmaxf(v3, 0.f);
      }
      unsigned short h0 = f2bf(v0), h1 = f2bf(v1), h2 = f2bf(v2), h3 = f2bf(v3);
      uint2 oh;
      oh.x = (unsigned)h0 | ((unsigned)h1 << 16);
      oh.y = (unsigned)h2 | ((unsigned)h3 << 16);
      if (EPI == 2) {
        *(uint2*)(O + row * 128 + col) = oh;
      } else {
        uint2 ol;
        ol.x = (unsigned)f2bf(v0 - bf2f(h0)) | ((unsigned)f2bf(v1 - bf2f(h1)) << 16);
        ol.y = (unsigned)f2bf(v2 - bf2f(h2)) | ((unsigned)f2bf(v3 - bf2f(h3)) << 16);
        *(uint2*)(O + row * 256 + col) = oh;
        *(uint2*)(O + row * 256 + 128 + col) = ol;
      }
    }
  }
}

// ---------------- predict pair: y = relu(u[i]+v[j]) . qW2 + qb2 -------------
__global__ __launch_bounds__(256) void k_pair(
    const unsigned short* __restrict__ u, const unsigned short* __restrict__ v,
    const int* __restrict__ ps, const int* __restrict__ pd,
    const float* __restrict__ qW2, const float* __restrict__ qb2,
    float* __restrict__ out, int EP) {
  int gid = blockIdx.x * blockDim.x + threadIdx.x;
  long wid = gid >> 6;
  int lane = gid & 63;
  int sub = lane & 15, g = lane >> 4;
  long base = wid * 8;
  if (base >= EP) return;
  float4 q0 = *(const float4*)(qW2 + sub * 8);
  float4 q1 = *(const float4*)(qW2 + sub * 8 + 4);
  float qb = qb2[0];

  long p0 = base + g;
  long p1 = base + 4 + g;
  long c0 = (p0 < EP) ? p0 : (EP - 1);
  long c1 = (p1 < EP) ? p1 : (EP - 1);
  int i0 = ps[c0], j0 = pd[c0];
  int i1 = ps[c1], j1 = pd[c1];
  uint4 a0 = *(const uint4*)(u + (size_t)i0 * 128 + sub * 8);
  uint4 b0 = *(const uint4*)(v + (size_t)j0 * 128 + sub * 8);
  uint4 a1 = *(const uint4*)(u + (size_t)i1 * 128 + sub * 8);
  uint4 b1 = *(const uint4*)(v + (size_t)j1 * 128 + sub * 8);

  float s0, s1;
  {
    float t;
    t = fmaxf(lo16f(a0.x) + lo16f(b0.x), 0.f) * q0.x;
    t = fmaf(fmaxf(hi16f(a0.x) + hi16f(b0.x), 0.f), q0.y, t);
    t = fmaf(fmaxf(lo16f(a0.y) + lo16f(b0.y), 0.f), q0.z, t);
    t = fmaf(fmaxf(hi16f(a0.y) + hi16f(b0.y), 0.f), q0.w, t);
    t = fmaf(fmaxf(lo16f(a0.z) + lo16f(b0.z), 0.f), q1.x, t);
    t = fmaf(fmaxf(hi16f(a0.z) + hi16f(b0.z), 0.f), q1.y, t);
    t = fmaf(fmaxf(lo16f(a0.w) + lo16f(b0.w), 0.f), q1.z, t);
    t = fmaf(fmaxf(hi16f(a0.w) + hi16f(b0.w), 0.f), q1.w, t);
    s0 = t;
    t = fmaxf(lo16f(a1.x) + lo16f(b1.x), 0.f) * q0.x;
    t = fmaf(fmaxf(hi16f(a1.x) + hi16f(b1.x), 0.f), q0.y, t);
    t = fmaf(fmaxf(lo16f(a1.y) + lo16f(b1.y), 0.f), q0.z, t);
    t = fmaf(fmaxf(hi16f(a1.y) + hi16f(b1.y), 0.f), q0.w, t);
    t = fmaf(fmaxf(lo16f(a1.z) + lo16f(b1.z), 0.f), q1.x, t);
    t = fmaf(fmaxf(hi16f(a1.z) + hi16f(b1.z), 0.f), q1.y, t);
    t = fmaf(fmaxf(lo16f(a1.w) + lo16f(b1.w), 0.f), q1.z, t);
    t = fmaf(fmaxf(hi16f(a1.w) + hi16f(b1.w), 0.f), q1.w, t);
    s1 = t;
  }
#pragma unroll
  for (int m = 1; m < 16; m <<= 1) {
    s0 += __shfl_xor(s0, m);
    s1 += __shfl_xor(s1, m);
  }
  if (sub == 0) {
    if (p0 < EP) out[p0] = s0 + qb;
    if (p1 < EP) out[p1] = s1 + qb;
  }
}

extern "C" void kernel_launch(void* const* d_in, const int* in_sizes, int n_in,
                              void* d_out, int out_size, void* d_ws, size_t ws_size,
                              hipStream_t stream) {
  const float* x_in = (const float*)d_in[0];
  // d_in[1] edge_attr: dead
  const int* ei = (const int*)d_in[2];
  const int* pe = (const int*)d_in[3];
  const float* Wl = (const float*)d_in[4];
  const float* bl = (const float*)d_in[5];
  const float* Wr = (const float*)d_in[6];
  // d_in[7..10] edge-update weights: dead
  const float* pW1 = (const float*)d_in[11];
  const float* pb1 = (const float*)d_in[12];
  const float* pW2 = (const float*)d_in[13];
  const float* pb2 = (const float*)d_in[14];
  const float* qW1 = (const float*)d_in[15];
  const float* qb1 = (const float*)d_in[16];
  const float* qW2 = (const float*)d_in[17];
  const float* qb2 = (const float*)d_in[18];

  const int N = in_sizes[0] / 128;
  const int E = in_sizes[2] / 2;
  const int EP = in_sizes[3] / 2;
  const int* e_src = ei;
  const int* e_dst = ei + E;
  const int* p_src = pe;
  const int* p_dst = pe + EP;

  char* ws = (char*)d_ws;
  size_t off = 0;
  auto alloc = [&](size_t bytes) {
    void* p = ws + off;
    off += (bytes + 511) & ~(size_t)511;
    return p;
  };
  // X, B: interleaved [node][hi 128 | lo 128] bf16 (512 B rows)
  unsigned short* X = (unsigned short*)alloc((size_t)N * 256 * 2);  // 25.6 MB
  unsigned short* B = (unsigned short*)alloc((size_t)N * 256 * 2);  // 25.6 MB
  int* deg_i = (int*)alloc((size_t)N * 4);
  int* rs = (int*)alloc((size_t)(N + 1) * 4);
  int* cursor = (int*)alloc((size_t)N * 4);
  float* degf = (float*)alloc((size_t)N * 4);
  int* csr = (int*)alloc((size_t)E * 4);
  int* bsum = (int*)alloc(64 * 4);
  int* boff = (int*)alloc(64 * 4);
  unsigned short* Whi = (unsigned short*)alloc((size_t)10 * 16384 * 2);
  unsigned short* Wlo = (unsigned short*)alloc((size_t)10 * 16384 * 2);
  float* biasuv = (float*)alloc(256 * 4);

  const size_t MS = 16384;  // mat stride in ushorts
  const int nb = (N + 1023) / 1024;

  hipMemsetAsync(deg_i, 0, (size_t)N * 4, stream);
  hipMemcpyAsync(biasuv, qb1, 128 * 4, hipMemcpyDeviceToDevice, stream);
  hipMemsetAsync(biasuv + 128, 0, 128 * 4, stream);

  // pack weights (frag order, hi/lo split); mats 8,9 = qW1 top/bottom
  k_packW<<<(3 * 2048 + 255) / 256, 256, 0, stream>>>(Wl, Whi + 0 * MS, Wlo + 0 * MS, 3);
  k_packW<<<(3 * 2048 + 255) / 256, 256, 0, stream>>>(Wr, Whi + 3 * MS, Wlo + 3 * MS, 3);
  k_packW<<<(2048 + 255) / 256, 256, 0, stream>>>(pW1, Whi + 6 * MS, Wlo + 6 * MS, 1);
  k_packW<<<(2048 + 255) / 256, 256, 0, stream>>>(pW2, Whi + 7 * MS, Wlo + 7 * MS, 1);
  k_packW<<<(2 * 2048 + 255) / 256, 256, 0, stream>>>(qW1, Whi + 8 * MS, Wlo + 8 * MS, 2);

  // x -> interleaved hi|lo
  long n2 = (long)N * 64;
  k_split<<<(int)((n2 + 255) / 256), 256, 0, stream>>>(x_in, (unsigned*)X, n2);

  // CSR (hierarchical scan)
  k_count<<<(E + 255) / 256, 256, 0, stream>>>(e_dst, deg_i, E);
  k_scan1<<<nb, 1024, 0, stream>>>(deg_i, rs, degf, bsum, N);
  k_scan2<<<1, 64, 0, stream>>>(bsum, boff, rs + N, nb);
  k_scan3<<<(N + 255) / 256, 256, 0, stream>>>(rs, boff, cursor, N);
  k_scatter<<<(E + 255) / 256, 256, 0, stream>>>(e_src, e_dst, cursor, csr, E);

  const int gmm = ((N + 31) / 32 + 7) / 8;  // 32 rows/wave, 8 waves/block
  const int agblocks = (N + 3) / 4;
  for (int l = 0; l < 3; ++l) {
    k_aggr<<<agblocks, 256, 0, stream>>>(X, csr, rs, degf, B, N);
    // x = relu(aggr@Wl + x@Wr + bl) -> X interleaved
    // (in-place safe: rows wave-owned; phase reads precede epilogue stores)
    k_gemm<2, 0><<<gmm, 512, 0, stream>>>(
        B, X, Whi + (size_t)l * MS, Wlo + (size_t)l * MS,
        Whi + (size_t)(3 + l) * MS, Wlo + (size_t)(3 + l) * MS,
        bl + (size_t)l * 128, X, N);
  }
  // h1 = relu(x@pW1+pb1) -> B
  k_gemm<1, 0><<<gmm, 512, 0, stream>>>(
      X, nullptr, Whi + 6 * MS, Wlo + 6 * MS, nullptr, nullptr, pb1, B, N);
  // x2 = h1@pW2+pb2 -> X (in-place over x; B is the source)
  k_gemm<1, 1><<<gmm, 512, 0, stream>>>(
      B, nullptr, Whi + 7 * MS, Wlo + 7 * MS, nullptr, nullptr, pb2, X, N);
  // u = x2@qW1t + qb1 ; v = x2@qW1b   (dense bf16, carved out of B's space)
  unsigned short* u = B;
  unsigned short* v = B + (size_t)N * 128;
  k_gemm<1, 2><<<gmm, 512, 0, stream>>>(
      X, nullptr, Whi + 8 * MS, Wlo + 8 * MS, nullptr, nullptr, biasuv, u, N);
  k_gemm<1, 2><<<gmm, 512, 0, stream>>>(
      X, nullptr, Whi + 9 * MS, Wlo + 9 * MS, nullptr, nullptr, biasuv + 128, v, N);
  // y = relu(u[i]+v[j]) . qW2 + qb2
  k_pair<<<(EP + 31) / 32, 256, 0, stream>>>(u, v, p_src, p_dst, qW2, qb2,
                                             (float*)d_out, EP);
}

// Round 9
// 329.775 us; speedup vs baseline: 2.9544x; 1.0050x over previous
//
#include <hip/hip_runtime.h>

// ---------------------------------------------------------------------------
// GNNStack — dead-code-eliminated (edge-update MLPs never reach the output).
// All matmuls on MFMA bf16 with hi/lo split precision (fp32-equivalent):
//   C = Ahi*Bhi + Alo*Bhi + Ahi*Blo   (AloBlo ~ 1.6e-5 relative, dropped)
// Node features: X interleaved [node][hi 128 | lo 128] bf16 (512 B row).
// Aggregation gathers the contiguous hi half (256 B) of X directly.
// GEMM: swapped MFMA operands (D[colquad][xrow] -> packed uint2 stores),
// 4-wave/256-thread blocks, 128 rows/block (391 blocks -> all CUs busy,
// 2 resident blocks/CU overlap staging with MFMA). u,v fused via NT=16.
// ---------------------------------------------------------------------------

typedef __attribute__((ext_vector_type(8))) short bf16x8;
typedef __attribute__((ext_vector_type(4))) float f32x4;

__device__ __forceinline__ unsigned short f2bf(float x) {
  unsigned u = __float_as_uint(x);
  u += 0x7fffu + ((u >> 16) & 1u);
  return (unsigned short)(u >> 16);
}
__device__ __forceinline__ float bf2f(unsigned short h) {
  return __uint_as_float(((unsigned)h) << 16);
}
__device__ __forceinline__ float lo16f(unsigned u) { return __uint_as_float(u << 16); }
__device__ __forceinline__ float hi16f(unsigned u) { return __uint_as_float(u & 0xffff0000u); }

// ---------------- CSR build ----------------
__global__ void k_count(const int* __restrict__ dst, int* __restrict__ cnt, int E) {
  int i = blockIdx.x * blockDim.x + threadIdx.x;
  if (i < E) atomicAdd(&cnt[dst[i]], 1);
}

__global__ void k_scan1(const int* __restrict__ cnt, int* __restrict__ rs,
                        float* __restrict__ degf, int* __restrict__ bsum, int n) {
  __shared__ int wsum[16];
  __shared__ int wpre[16];
  const int tid = threadIdx.x;
  const int lane = tid & 63;
  const int wv = tid >> 6;
  int i = blockIdx.x * 1024 + tid;
  int v = (i < n) ? cnt[i] : 0;
  int s = v;
#pragma unroll
  for (int off = 1; off < 64; off <<= 1) {
    int t = __shfl_up(s, off);
    if (lane >= off) s += t;
  }
  if (lane == 63) wsum[wv] = s;
  __syncthreads();
  if (tid < 16) {
    int t = wsum[tid];
    int ss = t;
#pragma unroll
    for (int off = 1; off < 16; off <<= 1) {
      int u = __shfl_up(ss, off);
      if (tid >= off) ss += u;
    }
    wpre[tid] = ss - t;
  }
  __syncthreads();
  if (i < n) {
    rs[i] = s - v + wpre[wv];
    degf[i] = (float)(v > 0 ? v : 1);
  }
  if (tid == 1023) bsum[blockIdx.x] = wpre[15] + wsum[15];
}

__global__ void k_scan2(const int* __restrict__ bsum, int* __restrict__ boff,
                        int* __restrict__ rs_n, int nb) {
  int tid = threadIdx.x;
  int v = (tid < nb) ? bsum[tid] : 0;
  int s = v;
#pragma unroll
  for (int off = 1; off < 64; off <<= 1) {
    int t = __shfl_up(s, off);
    if (tid >= off) s += t;
  }
  if (tid < nb) boff[tid] = s - v;
  if (tid == 63) rs_n[0] = s;
}

__global__ void k_scan3(int* __restrict__ rs, const int* __restrict__ boff,
                        int* __restrict__ cursor, int n) {
  int i = blockIdx.x * blockDim.x + threadIdx.x;
  if (i < n) {
    int r = rs[i] + boff[i >> 10];
    rs[i] = r;
    cursor[i] = r;
  }
}

__global__ void k_scatter(const int* __restrict__ src, const int* __restrict__ dst,
                          int* __restrict__ cursor, int* __restrict__ csr, int E) {
  int i = blockIdx.x * blockDim.x + threadIdx.x;
  if (i < E) {
    int p = atomicAdd(&cursor[dst[i]], 1);
    csr[p] = src[i];
  }
}

// ---------------- fp32 -> interleaved hi|lo X row ----------------
__global__ void k_split(const float* __restrict__ x, unsigned* __restrict__ X,
                        long n2) {
  long g = (long)blockIdx.x * blockDim.x + threadIdx.x;
  if (g >= n2) return;
  float2 v = ((const float2*)x)[g];
  unsigned short hx = f2bf(v.x), hy = f2bf(v.y);
  unsigned short lx = f2bf(v.x - bf2f(hx)), ly = f2bf(v.y - bf2f(hy));
  long row = g >> 6, p = g & 63;
  X[row * 128 + p] = (unsigned)hx | ((unsigned)hy << 16);
  X[row * 128 + 64 + p] = (unsigned)lx | ((unsigned)ly << 16);
}

// ---------------- weight pack: fp32 [K=128][N=128] -> frag-order bf16 hi/lo --
// frag f = nt*4 + ks; lane l supplies B[k0 + 8*(l>>4) + r][nt*16 + (l&15)]
__global__ void k_packW(const float* __restrict__ W, unsigned short* __restrict__ hi,
                        unsigned short* __restrict__ lo, int nmat) {
  int gid = blockIdx.x * blockDim.x + threadIdx.x;
  if (gid >= nmat * 2048) return;
  int lane = gid & 63;
  int f = (gid >> 6) & 31;
  int mat = gid >> 11;
  int nt = f >> 2, ks = f & 3;
  int n = nt * 16 + (lane & 15);
  int k0 = ks * 32 + 8 * (lane >> 4);
  const float* Wm = W + (size_t)mat * 16384;
  size_t dst = (size_t)gid * 8;
#pragma unroll
  for (int r = 0; r < 8; ++r) {
    float w = Wm[(size_t)(k0 + r) * 128 + n];
    unsigned short h = f2bf(w);
    hi[dst + r] = h;
    lo[dst + r] = f2bf(w - bf2f(h));
  }
}

// ---------------- mean aggregation over X hi-halves -------------------------
__global__ void k_aggr(const unsigned short* __restrict__ X,
                       const int* __restrict__ csr, const int* __restrict__ rs,
                       const float* __restrict__ degf,
                       unsigned short* __restrict__ B, int n) {
  int gid = blockIdx.x * blockDim.x + threadIdx.x;
  int wid = gid >> 6, lane = gid & 63;
  if (wid >= n) return;
  int s = rs[wid], e = rs[wid + 1];
  const int h = lane >> 4;         // neighbor slot (0..3)
  const int o16 = (lane & 15) * 8; // ushort offset within 256 B hi half
  float a0 = 0.f, a1 = 0.f, a2 = 0.f, a3 = 0.f;
  float a4 = 0.f, a5 = 0.f, a6 = 0.f, a7 = 0.f;
  int j = s;
  for (; j + 7 < e; j += 8) {
    int n0 = csr[j + h];
    int n1 = csr[j + 4 + h];
    uint4 v0 = *(const uint4*)(X + (size_t)n0 * 256 + o16);
    uint4 v1 = *(const uint4*)(X + (size_t)n1 * 256 + o16);
    a0 += lo16f(v0.x) + lo16f(v1.x);
    a1 += hi16f(v0.x) + hi16f(v1.x);
    a2 += lo16f(v0.y) + lo16f(v1.y);
    a3 += hi16f(v0.y) + hi16f(v1.y);
    a4 += lo16f(v0.z) + lo16f(v1.z);
    a5 += hi16f(v0.z) + hi16f(v1.z);
    a6 += lo16f(v0.w) + lo16f(v1.w);
    a7 += hi16f(v0.w) + hi16f(v1.w);
  }
  for (; j < e; j += 4) {
    int idx = j + h;
    bool ok = idx < e;
    int nn = ok ? csr[idx] : 0;
    uint4 v = *(const uint4*)(X + (size_t)nn * 256 + o16);
    float m = ok ? 1.f : 0.f;
    a0 += m * lo16f(v.x); a1 += m * hi16f(v.x);
    a2 += m * lo16f(v.y); a3 += m * hi16f(v.y);
    a4 += m * lo16f(v.z); a5 += m * hi16f(v.z);
    a6 += m * lo16f(v.w); a7 += m * hi16f(v.w);
  }
  a0 += __shfl_xor(a0, 16); a1 += __shfl_xor(a1, 16);
  a2 += __shfl_xor(a2, 16); a3 += __shfl_xor(a3, 16);
  a4 += __shfl_xor(a4, 16); a5 += __shfl_xor(a5, 16);
  a6 += __shfl_xor(a6, 16); a7 += __shfl_xor(a7, 16);
  a0 += __shfl_xor(a0, 32); a1 += __shfl_xor(a1, 32);
  a2 += __shfl_xor(a2, 32); a3 += __shfl_xor(a3, 32);
  a4 += __shfl_xor(a4, 32); a5 += __shfl_xor(a5, 32);
  a6 += __shfl_xor(a6, 32); a7 += __shfl_xor(a7, 32);
  if (lane < 16) {
    float inv = 1.0f / degf[wid];
    float m0 = a0 * inv, m1 = a1 * inv, m2 = a2 * inv, m3 = a3 * inv;
    float m4 = a4 * inv, m5 = a5 * inv, m6 = a6 * inv, m7 = a7 * inv;
    unsigned short h0 = f2bf(m0), h1 = f2bf(m1), h2 = f2bf(m2), h3 = f2bf(m3);
    unsigned short h4 = f2bf(m4), h5 = f2bf(m5), h6 = f2bf(m6), h7 = f2bf(m7);
    uint4 oh, ol;
    oh.x = (unsigned)h0 | ((unsigned)h1 << 16);
    oh.y = (unsigned)h2 | ((unsigned)h3 << 16);
    oh.z = (unsigned)h4 | ((unsigned)h5 << 16);
    oh.w = (unsigned)h6 | ((unsigned)h7 << 16);
    ol.x = (unsigned)f2bf(m0 - bf2f(h0)) | ((unsigned)f2bf(m1 - bf2f(h1)) << 16);
    ol.y = (unsigned)f2bf(m2 - bf2f(h2)) | ((unsigned)f2bf(m3 - bf2f(h3)) << 16);
    ol.z = (unsigned)f2bf(m4 - bf2f(h4)) | ((unsigned)f2bf(m5 - bf2f(h5)) << 16);
    ol.w = (unsigned)f2bf(m6 - bf2f(h6)) | ((unsigned)f2bf(m7 - bf2f(h7)) << 16);
    *(uint4*)(B + (size_t)wid * 256 + o16) = oh;
    *(uint4*)(B + (size_t)wid * 256 + 128 + o16) = ol;
  }
}

// ---------------- MFMA GEMM, LDS-staged weights, swapped operands -----------
// 256 threads = 4 waves; each wave owns 32 rows (2 row-sets of 16); 128
// rows/block -> 391 blocks (all CUs busy, 2 resident/CU at NT=8).
// mfma(w_frag, x_frag): D col quad per lane -> packed uint2 epilogue stores.
// NT=8: output 128 cols. NT=16: two weight mats packed contiguously, output
// 256 cols split across O (cols<128) and O2 (cols>=128) — fuses u,v.
// EPI: 0 = relu + interleaved out; 1 = interleaved out; 2 = dense bf16 out.
template <int NPHASE, int EPI, int NT>
__global__ __launch_bounds__(256) void k_gemm(
    const unsigned short* __restrict__ A0, const unsigned short* __restrict__ A1,
    const unsigned short* __restrict__ W0h, const unsigned short* __restrict__ W0l,
    const unsigned short* __restrict__ W1h, const unsigned short* __restrict__ W1l,
    const float* __restrict__ bias, unsigned short* __restrict__ O,
    unsigned short* __restrict__ O2, int nrows) {
  __shared__ unsigned short smem[NT * 4096];  // hi: NT*2048, lo: NT*2048
  unsigned short* smh = smem;
  unsigned short* sml = smem + NT * 2048;

  const int tid = threadIdx.x;
  const int lane = tid & 63;
  const int wv = tid >> 6;  // 0..3
  const long row0 = ((long)blockIdx.x * 4 + wv) * 32;
  const bool active = row0 < nrows;
  const int kgrp = (lane >> 4) * 8;

  long arow[2];
#pragma unroll
  for (int rs = 0; rs < 2; ++rs) {
    long r = row0 + rs * 16 + (lane & 15);
    arow[rs] = (r < nrows) ? r : (long)(nrows - 1);
  }

  f32x4 zero = {0.f, 0.f, 0.f, 0.f};
  f32x4 acc[2][NT];
#pragma unroll
  for (int rs = 0; rs < 2; ++rs)
#pragma unroll
    for (int t = 0; t < NT; ++t) acc[rs][t] = zero;

#pragma unroll
  for (int p = 0; p < NPHASE; ++p) {
    const unsigned short* A = p ? A1 : A0;
    const unsigned short* Wh = p ? W1h : W0h;
    const unsigned short* Wl_ = p ? W1l : W0l;
    if (p) __syncthreads();
    for (int t = tid; t < NT * 256; t += 256) {
      ((uint4*)smh)[t] = ((const uint4*)Wh)[t];
      ((uint4*)sml)[t] = ((const uint4*)Wl_)[t];
    }
    __syncthreads();
    if (active) {
#pragma unroll
      for (int ks = 0; ks < 4; ++ks) {
        bf16x8 a_h[2], a_l[2];
#pragma unroll
        for (int rs = 0; rs < 2; ++rs) {
          a_h[rs] = *(const bf16x8*)(A + arow[rs] * 256 + ks * 32 + kgrp);
          a_l[rs] = *(const bf16x8*)(A + arow[rs] * 256 + 128 + ks * 32 + kgrp);
        }
#pragma unroll
        for (int nt = 0; nt < NT; ++nt) {
          const bf16x8 b_h = *(const bf16x8*)(smh + (nt * 4 + ks) * 512 + lane * 8);
          const bf16x8 b_l = *(const bf16x8*)(sml + (nt * 4 + ks) * 512 + lane * 8);
#pragma unroll
          for (int rs = 0; rs < 2; ++rs) {
            acc[rs][nt] = __builtin_amdgcn_mfma_f32_16x16x32_bf16(b_h, a_h[rs], acc[rs][nt], 0, 0, 0);
            acc[rs][nt] = __builtin_amdgcn_mfma_f32_16x16x32_bf16(b_h, a_l[rs], acc[rs][nt], 0, 0, 0);
            acc[rs][nt] = __builtin_amdgcn_mfma_f32_16x16x32_bf16(b_l, a_h[rs], acc[rs][nt], 0, 0, 0);
          }
        }
      }
    }
  }
  if (!active) return;

  const int cq = (lane >> 4) * 4;  // col quad base within 16-col tile
#pragma unroll
  for (int rs = 0; rs < 2; ++rs) {
    const long row = row0 + rs * 16 + (lane & 15);
    if (row >= nrows) continue;
#pragma unroll
    for (int nt = 0; nt < NT; ++nt) {
      const int col = nt * 16 + cq;
      float4 bv = *(const float4*)(bias + col);
      float v0 = acc[rs][nt][0] + bv.x;
      float v1 = acc[rs][nt][1] + bv.y;
      float v2 = acc[rs][nt][2] + bv.z;
      float v3 = acc[rs][nt][3] + bv.w;
      if (EPI == 0) {
        v0 = fmaxf(v0, 0.f); v1 = fmaxf(v1, 0.f);
        v2 = fmaxf(v2, 0.f); v3 = fmaxf(v3, 0.f);
      }
      unsigned short h0 = f2bf(v0), h1 = f2bf(v1), h2 = f2bf(v2), h3 = f2bf(v3);
      uint2 oh;
      oh.x = (unsigned)h0 | ((unsigned)h1 << 16);
      oh.y = (unsigned)h2 | ((unsigned)h3 << 16);
      if (EPI == 2) {
        if (NT == 8 || col < 128)
          *(uint2*)(O + row * 128 + col) = oh;
        else
          *(uint2*)(O2 + row * 128 + (col - 128)) = oh;
      } else {
        uint2 ol;
        ol.x = (unsigned)f2bf(v0 - bf2f(h0)) | ((unsigned)f2bf(v1 - bf2f(h1)) << 16);
        ol.y = (unsigned)f2bf(v2 - bf2f(h2)) | ((unsigned)f2bf(v3 - bf2f(h3)) << 16);
        *(uint2*)(O + row * 256 + col) = oh;
        *(uint2*)(O + row * 256 + 128 + col) = ol;
      }
    }
  }
}

// ---------------- predict pair: y = relu(u[i]+v[j]) . qW2 + qb2 -------------
__global__ __launch_bounds__(256) void k_pair(
    const unsigned short* __restrict__ u, const unsigned short* __restrict__ v,
    const int* __restrict__ ps, const int* __restrict__ pd,
    const float* __restrict__ qW2, const float* __restrict__ qb2,
    float* __restrict__ out, int EP) {
  int gid = blockIdx.x * blockDim.x + threadIdx.x;
  long wid = gid >> 6;
  int lane = gid & 63;
  int sub = lane & 15, g = lane >> 4;
  long base = wid * 8;
  if (base >= EP) return;
  float4 q0 = *(const float4*)(qW2 + sub * 8);
  float4 q1 = *(const float4*)(qW2 + sub * 8 + 4);
  float qb = qb2[0];

  long p0 = base + g;
  long p1 = base + 4 + g;
  long c0 = (p0 < EP) ? p0 : (EP - 1);
  long c1 = (p1 < EP) ? p1 : (EP - 1);
  int i0 = ps[c0], j0 = pd[c0];
  int i1 = ps[c1], j1 = pd[c1];
  uint4 a0 = *(const uint4*)(u + (size_t)i0 * 128 + sub * 8);
  uint4 b0 = *(const uint4*)(v + (size_t)j0 * 128 + sub * 8);
  uint4 a1 = *(const uint4*)(u + (size_t)i1 * 128 + sub * 8);
  uint4 b1 = *(const uint4*)(v + (size_t)j1 * 128 + sub * 8);

  float s0, s1;
  {
    float t;
    t = fmaxf(lo16f(a0.x) + lo16f(b0.x), 0.f) * q0.x;
    t = fmaf(fmaxf(hi16f(a0.x) + hi16f(b0.x), 0.f), q0.y, t);
    t = fmaf(fmaxf(lo16f(a0.y) + lo16f(b0.y), 0.f), q0.z, t);
    t = fmaf(fmaxf(hi16f(a0.y) + hi16f(b0.y), 0.f), q0.w, t);
    t = fmaf(fmaxf(lo16f(a0.z) + lo16f(b0.z), 0.f), q1.x, t);
    t = fmaf(fmaxf(hi16f(a0.z) + hi16f(b0.z), 0.f), q1.y, t);
    t = fmaf(fmaxf(lo16f(a0.w) + lo16f(b0.w), 0.f), q1.z, t);
    t = fmaf(fmaxf(hi16f(a0.w) + hi16f(b0.w), 0.f), q1.w, t);
    s0 = t;
    t = fmaxf(lo16f(a1.x) + lo16f(b1.x), 0.f) * q0.x;
    t = fmaf(fmaxf(hi16f(a1.x) + hi16f(b1.x), 0.f), q0.y, t);
    t = fmaf(fmaxf(lo16f(a1.y) + lo16f(b1.y), 0.f), q0.z, t);
    t = fmaf(fmaxf(hi16f(a1.y) + hi16f(b1.y), 0.f), q0.w, t);
    t = fmaf(fmaxf(lo16f(a1.z) + lo16f(b1.z), 0.f), q1.x, t);
    t = fmaf(fmaxf(hi16f(a1.z) + hi16f(b1.z), 0.f), q1.y, t);
    t = fmaf(fmaxf(lo16f(a1.w) + lo16f(b1.w), 0.f), q1.z, t);
    t = fmaf(fmaxf(hi16f(a1.w) + hi16f(b1.w), 0.f), q1.w, t);
    s1 = t;
  }
#pragma unroll
  for (int m = 1; m < 16; m <<= 1) {
    s0 += __shfl_xor(s0, m);
    s1 += __shfl_xor(s1, m);
  }
  if (sub == 0) {
    if (p0 < EP) out[p0] = s0 + qb;
    if (p1 < EP) out[p1] = s1 + qb;
  }
}

extern "C" void kernel_launch(void* const* d_in, const int* in_sizes, int n_in,
                              void* d_out, int out_size, void* d_ws, size_t ws_size,
                              hipStream_t stream) {
  const float* x_in = (const float*)d_in[0];
  // d_in[1] edge_attr: dead
  const int* ei = (const int*)d_in[2];
  const int* pe = (const int*)d_in[3];
  const float* Wl = (const float*)d_in[4];
  const float* bl = (const float*)d_in[5];
  const float* Wr = (const float*)d_in[6];
  // d_in[7..10] edge-update weights: dead
  const float* pW1 = (const float*)d_in[11];
  const float* pb1 = (const float*)d_in[12];
  const float* pW2 = (const float*)d_in[13];
  const float* pb2 = (const float*)d_in[14];
  const float* qW1 = (const float*)d_in[15];
  const float* qb1 = (const float*)d_in[16];
  const float* qW2 = (const float*)d_in[17];
  const float* qb2 = (const float*)d_in[18];

  const int N = in_sizes[0] / 128;
  const int E = in_sizes[2] / 2;
  const int EP = in_sizes[3] / 2;
  const int* e_src = ei;
  const int* e_dst = ei + E;
  const int* p_src = pe;
  const int* p_dst = pe + EP;

  char* ws = (char*)d_ws;
  size_t off = 0;
  auto alloc = [&](size_t bytes) {
    void* p = ws + off;
    off += (bytes + 511) & ~(size_t)511;
    return p;
  };
  // X, B: interleaved [node][hi 128 | lo 128] bf16 (512 B rows)
  unsigned short* X = (unsigned short*)alloc((size_t)N * 256 * 2);  // 25.6 MB
  unsigned short* B = (unsigned short*)alloc((size_t)N * 256 * 2);  // 25.6 MB
  int* deg_i = (int*)alloc((size_t)N * 4);
  int* rs = (int*)alloc((size_t)(N + 1) * 4);
  int* cursor = (int*)alloc((size_t)N * 4);
  float* degf = (float*)alloc((size_t)N * 4);
  int* csr = (int*)alloc((size_t)E * 4);
  int* bsum = (int*)alloc(64 * 4);
  int* boff = (int*)alloc(64 * 4);
  unsigned short* Whi = (unsigned short*)alloc((size_t)10 * 16384 * 2);
  unsigned short* Wlo = (unsigned short*)alloc((size_t)10 * 16384 * 2);
  float* biasuv = (float*)alloc(256 * 4);

  const size_t MS = 16384;  // mat stride in ushorts
  const int nb = (N + 1023) / 1024;

  hipMemsetAsync(deg_i, 0, (size_t)N * 4, stream);
  hipMemcpyAsync(biasuv, qb1, 128 * 4, hipMemcpyDeviceToDevice, stream);
  hipMemsetAsync(biasuv + 128, 0, 128 * 4, stream);

  // pack weights (frag order, hi/lo split); mats 8,9 = qW1 top/bottom
  k_packW<<<(3 * 2048 + 255) / 256, 256, 0, stream>>>(Wl, Whi + 0 * MS, Wlo + 0 * MS, 3);
  k_packW<<<(3 * 2048 + 255) / 256, 256, 0, stream>>>(Wr, Whi + 3 * MS, Wlo + 3 * MS, 3);
  k_packW<<<(2048 + 255) / 256, 256, 0, stream>>>(pW1, Whi + 6 * MS, Wlo + 6 * MS, 1);
  k_packW<<<(2048 + 255) / 256, 256, 0, stream>>>(pW2, Whi + 7 * MS, Wlo + 7 * MS, 1);
  k_packW<<<(2 * 2048 + 255) / 256, 256, 0, stream>>>(qW1, Whi + 8 * MS, Wlo + 8 * MS, 2);

  // x -> interleaved hi|lo
  long n2 = (long)N * 64;
  k_split<<<(int)((n2 + 255) / 256), 256, 0, stream>>>(x_in, (unsigned*)X, n2);

  // CSR (hierarchical scan)
  k_count<<<(E + 255) / 256, 256, 0, stream>>>(e_dst, deg_i, E);
  k_scan1<<<nb, 1024, 0, stream>>>(deg_i, rs, degf, bsum, N);
  k_scan2<<<1, 64, 0, stream>>>(bsum, boff, rs + N, nb);
  k_scan3<<<(N + 255) / 256, 256, 0, stream>>>(rs, boff, cursor, N);
  k_scatter<<<(E + 255) / 256, 256, 0, stream>>>(e_src, e_dst, cursor, csr, E);

  const int gmm = (N + 127) / 128;  // 128 rows/block, 4 waves
  const int agblocks = (N + 3) / 4;
  for (int l = 0; l < 3; ++l) {
    k_aggr<<<agblocks, 256, 0, stream>>>(X, csr, rs, degf, B, N);
    // x = relu(aggr@Wl + x@Wr + bl) -> X interleaved
    // (in-place safe: rows wave-owned; phase reads precede epilogue stores)
    k_gemm<2, 0, 8><<<gmm, 256, 0, stream>>>(
        B, X, Whi + (size_t)l * MS, Wlo + (size_t)l * MS,
        Whi + (size_t)(3 + l) * MS, Wlo + (size_t)(3 + l) * MS,
        bl + (size_t)l * 128, X, nullptr, N);
  }
  // h1 = relu(x@pW1+pb1) -> B
  k_gemm<1, 0, 8><<<gmm, 256, 0, stream>>>(
      X, nullptr, Whi + 6 * MS, Wlo + 6 * MS, nullptr, nullptr, pb1, B, nullptr, N);
  // x2 = h1@pW2+pb2 -> X (in-place over x; B is the source)
  k_gemm<1, 1, 8><<<gmm, 256, 0, stream>>>(
      B, nullptr, Whi + 7 * MS, Wlo + 7 * MS, nullptr, nullptr, pb2, X, nullptr, N);
  // u = x2@qW1t + qb1 ; v = x2@qW1b  — ONE NT=16 dispatch (mats 8,9 adjacent)
  unsigned short* u = B;
  unsigned short* v = B + (size_t)N * 128;
  k_gemm<1, 2, 16><<<gmm, 256, 0, stream>>>(
      X, nullptr, Whi + 8 * MS, Wlo + 8 * MS, nullptr, nullptr, biasuv, u, v, N);
  // y = relu(u[i]+v[j]) . qW2 + qb2
  k_pair<<<(EP + 31) / 32, 256, 0, stream>>>(u, v, p_src, p_dst, qW2, qb2,
                                             (float*)d_out, EP);
}

// Round 10
// 316.075 us; speedup vs baseline: 3.0825x; 1.0433x over previous
//
#include <hip/hip_runtime.h>

// ---------------------------------------------------------------------------
// GNNStack — dead-code-eliminated (edge-update MLPs never reach the output).
// Matmuls on MFMA bf16, split precision where it matters:
//   X (node features): interleaved [node][hi 128 | lo 128] bf16 (512 B row)
//   B (aggregated mean): dense bf16 (256 B row) — its inputs are already
//     bf16-quantized, so the lo residual is below the error budget.
//   C = Ahi*Bhi (+ Alo*Bhi if A has lo) + Ahi*Blo, fp32 AGPR accum.
// GEMM: swapped MFMA operands (packed uint2 epilogue stores), 4-wave blocks,
// 128 rows/block (391 blocks, 64 KiB LDS -> 2 resident blocks/CU).
// ---------------------------------------------------------------------------

typedef __attribute__((ext_vector_type(8))) short bf16x8;
typedef __attribute__((ext_vector_type(4))) float f32x4;

__device__ __forceinline__ unsigned short f2bf(float x) {
  unsigned u = __float_as_uint(x);
  u += 0x7fffu + ((u >> 16) & 1u);
  return (unsigned short)(u >> 16);
}
__device__ __forceinline__ float bf2f(unsigned short h) {
  return __uint_as_float(((unsigned)h) << 16);
}
__device__ __forceinline__ float lo16f(unsigned u) { return __uint_as_float(u << 16); }
__device__ __forceinline__ float hi16f(unsigned u) { return __uint_as_float(u & 0xffff0000u); }

// ---------------- CSR build ----------------
__global__ void k_count(const int* __restrict__ dst, int* __restrict__ cnt, int E) {
  int i = blockIdx.x * blockDim.x + threadIdx.x;
  if (i < E) atomicAdd(&cnt[dst[i]], 1);
}

__global__ void k_scan1(const int* __restrict__ cnt, int* __restrict__ rs,
                        float* __restrict__ degf, int* __restrict__ bsum, int n) {
  __shared__ int wsum[16];
  __shared__ int wpre[16];
  const int tid = threadIdx.x;
  const int lane = tid & 63;
  const int wv = tid >> 6;
  int i = blockIdx.x * 1024 + tid;
  int v = (i < n) ? cnt[i] : 0;
  int s = v;
#pragma unroll
  for (int off = 1; off < 64; off <<= 1) {
    int t = __shfl_up(s, off);
    if (lane >= off) s += t;
  }
  if (lane == 63) wsum[wv] = s;
  __syncthreads();
  if (tid < 16) {
    int t = wsum[tid];
    int ss = t;
#pragma unroll
    for (int off = 1; off < 16; off <<= 1) {
      int u = __shfl_up(ss, off);
      if (tid >= off) ss += u;
    }
    wpre[tid] = ss - t;
  }
  __syncthreads();
  if (i < n) {
    rs[i] = s - v + wpre[wv];
    degf[i] = (float)(v > 0 ? v : 1);
  }
  if (tid == 1023) bsum[blockIdx.x] = wpre[15] + wsum[15];
}

__global__ void k_scan2(const int* __restrict__ bsum, int* __restrict__ boff,
                        int* __restrict__ rs_n, int nb) {
  int tid = threadIdx.x;
  int v = (tid < nb) ? bsum[tid] : 0;
  int s = v;
#pragma unroll
  for (int off = 1; off < 64; off <<= 1) {
    int t = __shfl_up(s, off);
    if (tid >= off) s += t;
  }
  if (tid < nb) boff[tid] = s - v;
  if (tid == 63) rs_n[0] = s;
}

__global__ void k_scan3(int* __restrict__ rs, const int* __restrict__ boff,
                        int* __restrict__ cursor, int n) {
  int i = blockIdx.x * blockDim.x + threadIdx.x;
  if (i < n) {
    int r = rs[i] + boff[i >> 10];
    rs[i] = r;
    cursor[i] = r;
  }
}

__global__ void k_scatter(const int* __restrict__ src, const int* __restrict__ dst,
                          int* __restrict__ cursor, int* __restrict__ csr, int E) {
  int i = blockIdx.x * blockDim.x + threadIdx.x;
  if (i < E) {
    int p = atomicAdd(&cursor[dst[i]], 1);
    csr[p] = src[i];
  }
}

// ---------------- fp32 -> interleaved hi|lo X row ----------------
__global__ void k_split(const float* __restrict__ x, unsigned* __restrict__ X,
                        long n2) {
  long g = (long)blockIdx.x * blockDim.x + threadIdx.x;
  if (g >= n2) return;
  float2 v = ((const float2*)x)[g];
  unsigned short hx = f2bf(v.x), hy = f2bf(v.y);
  unsigned short lx = f2bf(v.x - bf2f(hx)), ly = f2bf(v.y - bf2f(hy));
  long row = g >> 6, p = g & 63;
  X[row * 128 + p] = (unsigned)hx | ((unsigned)hy << 16);
  X[row * 128 + 64 + p] = (unsigned)lx | ((unsigned)ly << 16);
}

// ---------------- weight pack: fp32 [K=128][N=128] -> frag-order bf16 hi/lo --
// frag f = nt*4 + ks; lane l supplies B[k0 + 8*(l>>4) + r][nt*16 + (l&15)]
__global__ void k_packW(const float* __restrict__ W, unsigned short* __restrict__ hi,
                        unsigned short* __restrict__ lo, int nmat) {
  int gid = blockIdx.x * blockDim.x + threadIdx.x;
  if (gid >= nmat * 2048) return;
  int lane = gid & 63;
  int f = (gid >> 6) & 31;
  int mat = gid >> 11;
  int nt = f >> 2, ks = f & 3;
  int n = nt * 16 + (lane & 15);
  int k0 = ks * 32 + 8 * (lane >> 4);
  const float* Wm = W + (size_t)mat * 16384;
  size_t dst = (size_t)gid * 8;
#pragma unroll
  for (int r = 0; r < 8; ++r) {
    float w = Wm[(size_t)(k0 + r) * 128 + n];
    unsigned short h = f2bf(w);
    hi[dst + r] = h;
    lo[dst + r] = f2bf(w - bf2f(h));
  }
}

// ---------------- mean aggregation over X hi-halves -> dense bf16 B ---------
__global__ void k_aggr(const unsigned short* __restrict__ X,
                       const int* __restrict__ csr, const int* __restrict__ rs,
                       const float* __restrict__ degf,
                       unsigned short* __restrict__ Bd, int n) {
  int gid = blockIdx.x * blockDim.x + threadIdx.x;
  int wid = gid >> 6, lane = gid & 63;
  if (wid >= n) return;
  int s = rs[wid], e = rs[wid + 1];
  const int h = lane >> 4;         // neighbor slot (0..3)
  const int o16 = (lane & 15) * 8; // ushort offset within 256 B hi half
  float a0 = 0.f, a1 = 0.f, a2 = 0.f, a3 = 0.f;
  float a4 = 0.f, a5 = 0.f, a6 = 0.f, a7 = 0.f;
  int j = s;
  for (; j + 7 < e; j += 8) {
    int n0 = csr[j + h];
    int n1 = csr[j + 4 + h];
    uint4 v0 = *(const uint4*)(X + (size_t)n0 * 256 + o16);
    uint4 v1 = *(const uint4*)(X + (size_t)n1 * 256 + o16);
    a0 += lo16f(v0.x) + lo16f(v1.x);
    a1 += hi16f(v0.x) + hi16f(v1.x);
    a2 += lo16f(v0.y) + lo16f(v1.y);
    a3 += hi16f(v0.y) + hi16f(v1.y);
    a4 += lo16f(v0.z) + lo16f(v1.z);
    a5 += hi16f(v0.z) + hi16f(v1.z);
    a6 += lo16f(v0.w) + lo16f(v1.w);
    a7 += hi16f(v0.w) + hi16f(v1.w);
  }
  for (; j < e; j += 4) {
    int idx = j + h;
    bool ok = idx < e;
    int nn = ok ? csr[idx] : 0;
    uint4 v = *(const uint4*)(X + (size_t)nn * 256 + o16);
    float m = ok ? 1.f : 0.f;
    a0 += m * lo16f(v.x); a1 += m * hi16f(v.x);
    a2 += m * lo16f(v.y); a3 += m * hi16f(v.y);
    a4 += m * lo16f(v.z); a5 += m * hi16f(v.z);
    a6 += m * lo16f(v.w); a7 += m * hi16f(v.w);
  }
  a0 += __shfl_xor(a0, 16); a1 += __shfl_xor(a1, 16);
  a2 += __shfl_xor(a2, 16); a3 += __shfl_xor(a3, 16);
  a4 += __shfl_xor(a4, 16); a5 += __shfl_xor(a5, 16);
  a6 += __shfl_xor(a6, 16); a7 += __shfl_xor(a7, 16);
  a0 += __shfl_xor(a0, 32); a1 += __shfl_xor(a1, 32);
  a2 += __shfl_xor(a2, 32); a3 += __shfl_xor(a3, 32);
  a4 += __shfl_xor(a4, 32); a5 += __shfl_xor(a5, 32);
  a6 += __shfl_xor(a6, 32); a7 += __shfl_xor(a7, 32);
  if (lane < 16) {
    float inv = 1.0f / degf[wid];
    unsigned short h0 = f2bf(a0 * inv), h1 = f2bf(a1 * inv);
    unsigned short h2 = f2bf(a2 * inv), h3 = f2bf(a3 * inv);
    unsigned short h4 = f2bf(a4 * inv), h5 = f2bf(a5 * inv);
    unsigned short h6 = f2bf(a6 * inv), h7 = f2bf(a7 * inv);
    uint4 oh;
    oh.x = (unsigned)h0 | ((unsigned)h1 << 16);
    oh.y = (unsigned)h2 | ((unsigned)h3 << 16);
    oh.z = (unsigned)h4 | ((unsigned)h5 << 16);
    oh.w = (unsigned)h6 | ((unsigned)h7 << 16);
    *(uint4*)(Bd + (size_t)wid * 128 + o16) = oh;
  }
}

// ---------------- MFMA GEMM, LDS-staged weights, swapped operands -----------
// 256 threads = 4 waves; each wave owns 32 rows; 128 rows/block. NT=8,
// LDS 64 KiB -> 2 resident blocks/CU. mfma(w_frag, x_frag): lane owns a col
// quad -> packed uint2 epilogue stores.
// A0DENSE: phase-0 A is dense bf16 (stride 128, no lo part, 2 MFMAs).
// EPI: 0 = relu + interleaved out; 1 = interleaved out; 2 = dense bf16 out.
template <int NPHASE, int EPI, int A0DENSE>
__global__ __launch_bounds__(256) void k_gemm(
    const unsigned short* __restrict__ A0, const unsigned short* __restrict__ A1,
    const unsigned short* __restrict__ W0h, const unsigned short* __restrict__ W0l,
    const unsigned short* __restrict__ W1h, const unsigned short* __restrict__ W1l,
    const float* __restrict__ bias, unsigned short* __restrict__ O, int nrows) {
  __shared__ unsigned short smem[8 * 4096];  // hi: 16384, lo: 16384 ushorts
  unsigned short* smh = smem;
  unsigned short* sml = smem + 8 * 2048;

  const int tid = threadIdx.x;
  const int lane = tid & 63;
  const int wv = tid >> 6;  // 0..3
  const long row0 = ((long)blockIdx.x * 4 + wv) * 32;
  const bool active = row0 < nrows;
  const int kgrp = (lane >> 4) * 8;

  long arow[2];
#pragma unroll
  for (int rs = 0; rs < 2; ++rs) {
    long r = row0 + rs * 16 + (lane & 15);
    arow[rs] = (r < nrows) ? r : (long)(nrows - 1);
  }

  f32x4 zero = {0.f, 0.f, 0.f, 0.f};
  f32x4 acc[2][8];
#pragma unroll
  for (int rs = 0; rs < 2; ++rs)
#pragma unroll
    for (int t = 0; t < 8; ++t) acc[rs][t] = zero;

#pragma unroll
  for (int p = 0; p < NPHASE; ++p) {
    const bool dense = (p == 0) && A0DENSE;
    const unsigned short* A = p ? A1 : A0;
    const unsigned short* Wh = p ? W1h : W0h;
    const unsigned short* Wl_ = p ? W1l : W0l;
    if (p) __syncthreads();
    for (int t = tid; t < 8 * 256; t += 256) {
      ((uint4*)smh)[t] = ((const uint4*)Wh)[t];
      ((uint4*)sml)[t] = ((const uint4*)Wl_)[t];
    }
    __syncthreads();
    if (active) {
#pragma unroll
      for (int ks = 0; ks < 4; ++ks) {
        bf16x8 a_h[2], a_l[2];
#pragma unroll
        for (int rs = 0; rs < 2; ++rs) {
          if (dense) {
            a_h[rs] = *(const bf16x8*)(A + arow[rs] * 128 + ks * 32 + kgrp);
          } else {
            a_h[rs] = *(const bf16x8*)(A + arow[rs] * 256 + ks * 32 + kgrp);
            a_l[rs] = *(const bf16x8*)(A + arow[rs] * 256 + 128 + ks * 32 + kgrp);
          }
        }
#pragma unroll
        for (int nt = 0; nt < 8; ++nt) {
          const bf16x8 b_h = *(const bf16x8*)(smh + (nt * 4 + ks) * 512 + lane * 8);
          const bf16x8 b_l = *(const bf16x8*)(sml + (nt * 4 + ks) * 512 + lane * 8);
#pragma unroll
          for (int rs = 0; rs < 2; ++rs) {
            acc[rs][nt] = __builtin_amdgcn_mfma_f32_16x16x32_bf16(b_h, a_h[rs], acc[rs][nt], 0, 0, 0);
            if (!dense)
              acc[rs][nt] = __builtin_amdgcn_mfma_f32_16x16x32_bf16(b_h, a_l[rs], acc[rs][nt], 0, 0, 0);
            acc[rs][nt] = __builtin_amdgcn_mfma_f32_16x16x32_bf16(b_l, a_h[rs], acc[rs][nt], 0, 0, 0);
          }
        }
      }
    }
  }
  if (!active) return;

  const int cq = (lane >> 4) * 4;  // col quad base within 16-col tile
#pragma unroll
  for (int rs = 0; rs < 2; ++rs) {
    const long row = row0 + rs * 16 + (lane & 15);
    if (row >= nrows) continue;
#pragma unroll
    for (int nt = 0; nt < 8; ++nt) {
      const int col = nt * 16 + cq;
      float4 bv = *(const float4*)(bias + col);
      float v0 = acc[rs][nt][0] + bv.x;
      float v1 = acc[rs][nt][1] + bv.y;
      float v2 = acc[rs][nt][2] + bv.z;
      float v3 = acc[rs][nt][3] + bv.w;
      if (EPI == 0) {
        v0 = fmaxf(v0, 0.f); v1 = fmaxf(v1, 0.f);
        v2 = fmaxf(v2, 0.f); v3 = fmaxf(v3, 0.f);
      }
      unsigned short h0 = f2bf(v0), h1 = f2bf(v1), h2 = f2bf(v2), h3 = f2bf(v3);
      uint2 oh;
      oh.x = (unsigned)h0 | ((unsigned)h1 << 16);
      oh.y = (unsigned)h2 | ((unsigned)h3 << 16);
      if (EPI == 2) {
        *(uint2*)(O + row * 128 + col) = oh;
      } else {
        uint2 ol;
        ol.x = (unsigned)f2bf(v0 - bf2f(h0)) | ((unsigned)f2bf(v1 - bf2f(h1)) << 16);
        ol.y = (unsigned)f2bf(v2 - bf2f(h2)) | ((unsigned)f2bf(v3 - bf2f(h3)) << 16);
        *(uint2*)(O + row * 256 + col) = oh;
        *(uint2*)(O + row * 256 + 128 + col) = ol;
      }
    }
  }
}

// ---------------- predict pair: y = relu(u[i]+v[j]) . qW2 + qb2 -------------
__global__ __launch_bounds__(256) void k_pair(
    const unsigned short* __restrict__ u, const unsigned short* __restrict__ v,
    const int* __restrict__ ps, const int* __restrict__ pd,
    const float* __restrict__ qW2, const float* __restrict__ qb2,
    float* __restrict__ out, int EP) {
  int gid = blockIdx.x * blockDim.x + threadIdx.x;
  long wid = gid >> 6;
  int lane = gid & 63;
  int sub = lane & 15, g = lane >> 4;
  long base = wid * 8;
  if (base >= EP) return;
  float4 q0 = *(const float4*)(qW2 + sub * 8);
  float4 q1 = *(const float4*)(qW2 + sub * 8 + 4);
  float qb = qb2[0];

  long p0 = base + g;
  long p1 = base + 4 + g;
  long c0 = (p0 < EP) ? p0 : (EP - 1);
  long c1 = (p1 < EP) ? p1 : (EP - 1);
  int i0 = ps[c0], j0 = pd[c0];
  int i1 = ps[c1], j1 = pd[c1];
  uint4 a0 = *(const uint4*)(u + (size_t)i0 * 128 + sub * 8);
  uint4 b0 = *(const uint4*)(v + (size_t)j0 * 128 + sub * 8);
  uint4 a1 = *(const uint4*)(u + (size_t)i1 * 128 + sub * 8);
  uint4 b1 = *(const uint4*)(v + (size_t)j1 * 128 + sub * 8);

  float s0, s1;
  {
    float t;
    t = fmaxf(lo16f(a0.x) + lo16f(b0.x), 0.f) * q0.x;
    t = fmaf(fmaxf(hi16f(a0.x) + hi16f(b0.x), 0.f), q0.y, t);
    t = fmaf(fmaxf(lo16f(a0.y) + lo16f(b0.y), 0.f), q0.z, t);
    t = fmaf(fmaxf(hi16f(a0.y) + hi16f(b0.y), 0.f), q0.w, t);
    t = fmaf(fmaxf(lo16f(a0.z) + lo16f(b0.z), 0.f), q1.x, t);
    t = fmaf(fmaxf(hi16f(a0.z) + hi16f(b0.z), 0.f), q1.y, t);
    t = fmaf(fmaxf(lo16f(a0.w) + lo16f(b0.w), 0.f), q1.z, t);
    t = fmaf(fmaxf(hi16f(a0.w) + hi16f(b0.w), 0.f), q1.w, t);
    s0 = t;
    t = fmaxf(lo16f(a1.x) + lo16f(b1.x), 0.f) * q0.x;
    t = fmaf(fmaxf(hi16f(a1.x) + hi16f(b1.x), 0.f), q0.y, t);
    t = fmaf(fmaxf(lo16f(a1.y) + lo16f(b1.y), 0.f), q0.z, t);
    t = fmaf(fmaxf(hi16f(a1.y) + hi16f(b1.y), 0.f), q0.w, t);
    t = fmaf(fmaxf(lo16f(a1.z) + lo16f(b1.z), 0.f), q1.x, t);
    t = fmaf(fmaxf(hi16f(a1.z) + hi16f(b1.z), 0.f), q1.y, t);
    t = fmaf(fmaxf(lo16f(a1.w) + lo16f(b1.w), 0.f), q1.z, t);
    t = fmaf(fmaxf(hi16f(a1.w) + hi16f(b1.w), 0.f), q1.w, t);
    s1 = t;
  }
#pragma unroll
  for (int m = 1; m < 16; m <<= 1) {
    s0 += __shfl_xor(s0, m);
    s1 += __shfl_xor(s1, m);
  }
  if (sub == 0) {
    if (p0 < EP) out[p0] = s0 + qb;
    if (p1 < EP) out[p1] = s1 + qb;
  }
}

extern "C" void kernel_launch(void* const* d_in, const int* in_sizes, int n_in,
                              void* d_out, int out_size, void* d_ws, size_t ws_size,
                              hipStream_t stream) {
  const float* x_in = (const float*)d_in[0];
  // d_in[1] edge_attr: dead
  const int* ei = (const int*)d_in[2];
  const int* pe = (const int*)d_in[3];
  const float* Wl = (const float*)d_in[4];
  const float* bl = (const float*)d_in[5];
  const float* Wr = (const float*)d_in[6];
  // d_in[7..10] edge-update weights: dead
  const float* pW1 = (const float*)d_in[11];
  const float* pb1 = (const float*)d_in[12];
  const float* pW2 = (const float*)d_in[13];
  const float* pb2 = (const float*)d_in[14];
  const float* qW1 = (const float*)d_in[15];
  const float* qb1 = (const float*)d_in[16];
  const float* qW2 = (const float*)d_in[17];
  const float* qb2 = (const float*)d_in[18];

  const int N = in_sizes[0] / 128;
  const int E = in_sizes[2] / 2;
  const int EP = in_sizes[3] / 2;
  const int* e_src = ei;
  const int* e_dst = ei + E;
  const int* p_src = pe;
  const int* p_dst = pe + EP;

  char* ws = (char*)d_ws;
  size_t off = 0;
  auto alloc = [&](size_t bytes) {
    void* p = ws + off;
    off += (bytes + 511) & ~(size_t)511;
    return p;
  };
  // X: interleaved [node][hi|lo] (512 B rows). B: scratch — holds the dense
  // bf16 aggregated mean (256 B rows), later the interleaved h1, then u|v.
  unsigned short* X = (unsigned short*)alloc((size_t)N * 256 * 2);  // 25.6 MB
  unsigned short* B = (unsigned short*)alloc((size_t)N * 256 * 2);  // 25.6 MB
  int* deg_i = (int*)alloc((size_t)N * 4);
  int* rs = (int*)alloc((size_t)(N + 1) * 4);
  int* cursor = (int*)alloc((size_t)N * 4);
  float* degf = (float*)alloc((size_t)N * 4);
  int* csr = (int*)alloc((size_t)E * 4);
  int* bsum = (int*)alloc(64 * 4);
  int* boff = (int*)alloc(64 * 4);
  unsigned short* Whi = (unsigned short*)alloc((size_t)10 * 16384 * 2);
  unsigned short* Wlo = (unsigned short*)alloc((size_t)10 * 16384 * 2);
  float* biasuv = (float*)alloc(256 * 4);

  const size_t MS = 16384;  // mat stride in ushorts
  const int nb = (N + 1023) / 1024;

  hipMemsetAsync(deg_i, 0, (size_t)N * 4, stream);
  hipMemcpyAsync(biasuv, qb1, 128 * 4, hipMemcpyDeviceToDevice, stream);
  hipMemsetAsync(biasuv + 128, 0, 128 * 4, stream);

  // pack weights (frag order, hi/lo split); mats 8,9 = qW1 top/bottom
  k_packW<<<(3 * 2048 + 255) / 256, 256, 0, stream>>>(Wl, Whi + 0 * MS, Wlo + 0 * MS, 3);
  k_packW<<<(3 * 2048 + 255) / 256, 256, 0, stream>>>(Wr, Whi + 3 * MS, Wlo + 3 * MS, 3);
  k_packW<<<(2048 + 255) / 256, 256, 0, stream>>>(pW1, Whi + 6 * MS, Wlo + 6 * MS, 1);
  k_packW<<<(2048 + 255) / 256, 256, 0, stream>>>(pW2, Whi + 7 * MS, Wlo + 7 * MS, 1);
  k_packW<<<(2 * 2048 + 255) / 256, 256, 0, stream>>>(qW1, Whi + 8 * MS, Wlo + 8 * MS, 2);

  // x -> interleaved hi|lo
  long n2 = (long)N * 64;
  k_split<<<(int)((n2 + 255) / 256), 256, 0, stream>>>(x_in, (unsigned*)X, n2);

  // CSR (hierarchical scan)
  k_count<<<(E + 255) / 256, 256, 0, stream>>>(e_dst, deg_i, E);
  k_scan1<<<nb, 1024, 0, stream>>>(deg_i, rs, degf, bsum, N);
  k_scan2<<<1, 64, 0, stream>>>(bsum, boff, rs + N, nb);
  k_scan3<<<(N + 255) / 256, 256, 0, stream>>>(rs, boff, cursor, N);
  k_scatter<<<(E + 255) / 256, 256, 0, stream>>>(e_src, e_dst, cursor, csr, E);

  const int gmm = (N + 127) / 128;  // 128 rows/block, 4 waves
  const int agblocks = (N + 3) / 4;
  for (int l = 0; l < 3; ++l) {
    k_aggr<<<agblocks, 256, 0, stream>>>(X, csr, rs, degf, B, N);
    // x = relu(aggr@Wl + x@Wr + bl) -> X interleaved; aggr (B) is dense bf16
    // (in-place safe: rows wave-owned; phase reads precede epilogue stores)
    k_gemm<2, 0, 1><<<gmm, 256, 0, stream>>>(
        B, X, Whi + (size_t)l * MS, Wlo + (size_t)l * MS,
        Whi + (size_t)(3 + l) * MS, Wlo + (size_t)(3 + l) * MS,
        bl + (size_t)l * 128, X, N);
  }
  // h1 = relu(x@pW1+pb1) -> B (interleaved)
  k_gemm<1, 0, 0><<<gmm, 256, 0, stream>>>(
      X, nullptr, Whi + 6 * MS, Wlo + 6 * MS, nullptr, nullptr, pb1, B, N);
  // x2 = h1@pW2+pb2 -> X (in-place over x; B is the source)
  k_gemm<1, 1, 0><<<gmm, 256, 0, stream>>>(
      B, nullptr, Whi + 7 * MS, Wlo + 7 * MS, nullptr, nullptr, pb2, X, N);
  // u = x2@qW1t + qb1 ; v = x2@qW1b  (two NT=8 dispatches, 64 KiB LDS each)
  unsigned short* u = B;
  unsigned short* v = B + (size_t)N * 128;
  k_gemm<1, 2, 0><<<gmm, 256, 0, stream>>>(
      X, nullptr, Whi + 8 * MS, Wlo + 8 * MS, nullptr, nullptr, biasuv, u, N);
  k_gemm<1, 2, 0><<<gmm, 256, 0, stream>>>(
      X, nullptr, Whi + 9 * MS, Wlo + 9 * MS, nullptr, nullptr, biasuv + 128, v, N);
  // y = relu(u[i]+v[j]) . qW2 + qb2
  k_pair<<<(EP + 31) / 32, 256, 0, stream>>>(u, v, p_src, p_dst, qW2, qb2,
                                             (float*)d_out, EP);
}